// Round 1
// baseline (1748.492 us; speedup 1.0000x reference)
//
#include <hip/hip_runtime.h>
#include <hip/hip_bf16.h>
#include <cstdint>

#define G 8
#define M 1024
#define H 256
#define HEADS 8
#define FFND 1024
#define NE 131072
#define NN (G*M)          // 8192
#define HD 32             // H/HEADS

typedef unsigned long long u64;
typedef uint8_t u8;

// ---------------- degree / dinv ----------------
__global__ void k_deg(const int* __restrict__ dst, int* __restrict__ deg) {
  int e = blockIdx.x * 256 + threadIdx.x;
  if (e < NE) atomicAdd(&deg[dst[e]], 1);
}

__global__ void k_dinv(const int* __restrict__ deg, float* __restrict__ dinv) {
  int i = blockIdx.x * 256 + threadIdx.x;
  if (i < NN) dinv[i] = rsqrtf((float)(deg[i] + 1));   // +1 self loop
}

// ---------------- generic SGEMM: C[N,O] = A[N,K] @ W[O,K]^T + bias, opt GELU ----------------
template<int ACT>
__global__ __launch_bounds__(256) void k_gemm(const float* __restrict__ A,
                                              const float* __restrict__ W,
                                              const float* __restrict__ bias,
                                              float* __restrict__ C,
                                              int K, int O) {
  __shared__ float As[64][17];
  __shared__ float Ws[64][17];
  const int tid = threadIdx.x;
  const int tx = tid & 15, ty = tid >> 4;
  const int m0 = blockIdx.y * 64, n0 = blockIdx.x * 64;
  const int lr = tid >> 2, lc = (tid & 3) * 4;
  float c[4][4] = {};
  for (int k0 = 0; k0 < K; k0 += 16) {
    float4 av = *reinterpret_cast<const float4*>(&A[(size_t)(m0 + lr) * K + k0 + lc]);
    float4 wv = *reinterpret_cast<const float4*>(&W[(size_t)(n0 + lr) * K + k0 + lc]);
    As[lr][lc+0] = av.x; As[lr][lc+1] = av.y; As[lr][lc+2] = av.z; As[lr][lc+3] = av.w;
    Ws[lr][lc+0] = wv.x; Ws[lr][lc+1] = wv.y; Ws[lr][lc+2] = wv.z; Ws[lr][lc+3] = wv.w;
    __syncthreads();
    #pragma unroll
    for (int kk = 0; kk < 16; ++kk) {
      float a[4], b[4];
      #pragma unroll
      for (int i = 0; i < 4; ++i) a[i] = As[ty*4 + i][kk];
      #pragma unroll
      for (int j = 0; j < 4; ++j) b[j] = Ws[tx*4 + j][kk];
      #pragma unroll
      for (int i = 0; i < 4; ++i)
        #pragma unroll
        for (int j = 0; j < 4; ++j) c[i][j] += a[i] * b[j];
    }
    __syncthreads();
  }
  #pragma unroll
  for (int i = 0; i < 4; ++i) {
    int row = m0 + ty*4 + i;
    #pragma unroll
    for (int j = 0; j < 4; ++j) {
      int col = n0 + tx*4 + j;
      float v = c[i][j] + (bias ? bias[col] : 0.0f);
      if (ACT == 1) v = 0.5f * v * (1.0f + erff(v * 0.70710678118654752f));
      C[(size_t)row * O + col] = v;
    }
  }
}

// ---------------- GCN scatter: agg[dst] += dinv[src]*xw[src] ----------------
__global__ void k_scatter(const int* __restrict__ srcv, const int* __restrict__ dstv,
                          const float* __restrict__ dinv, const float* __restrict__ xw,
                          float* __restrict__ agg) {
  int t = blockIdx.x * 256 + threadIdx.x;   // NE*64 threads
  int e = t >> 6, c = (t & 63) * 4;
  int s = srcv[e], d = dstv[e];
  float sc = dinv[s];
  float4 v = *reinterpret_cast<const float4*>(&xw[(size_t)s * H + c]);
  float* o = &agg[(size_t)d * H + c];
  atomicAdd(o + 0, sc * v.x); atomicAdd(o + 1, sc * v.y);
  atomicAdd(o + 2, sc * v.z); atomicAdd(o + 3, sc * v.w);
}

__global__ void k_xlocal(const float* __restrict__ xw, const float* __restrict__ agg,
                         const float* __restrict__ dinv, const float* __restrict__ gcn_b,
                         float* __restrict__ xloc) {
  int t = blockIdx.x * 256 + threadIdx.x;   // NN*64 threads
  int n = t >> 6, c = (t & 63) * 4;
  float di = dinv[n];
  float4 a = *reinterpret_cast<const float4*>(&agg[(size_t)n * H + c]);
  float4 w = *reinterpret_cast<const float4*>(&xw[(size_t)n * H + c]);
  float4 b = *reinterpret_cast<const float4*>(&gcn_b[c]);
  float4 o;
  o.x = di * a.x + di * di * w.x + b.x;
  o.y = di * a.y + di * di * w.y + b.y;
  o.z = di * a.z + di * di * w.z + b.z;
  o.w = di * a.w + di * di * w.w + b.w;
  *reinterpret_cast<float4*>(&xloc[(size_t)n * H + c]) = o;
}

// ---------------- adjacency bitset ----------------
__global__ void k_adj(const int* __restrict__ srcv, const int* __restrict__ dstv,
                      u64* __restrict__ adj) {
  int e = blockIdx.x * 256 + threadIdx.x;
  if (e >= NE) return;
  int s = srcv[e], d = dstv[e];
  if (s == d) return;
  int g = s >> 10, ls = s & 1023, ld = d & 1023;
  atomicOr(&adj[((size_t)((g << 10) | ls)) * 16 + (ld >> 6)], 1ull << (ld & 63));
  atomicOr(&adj[((size_t)((g << 10) | ld)) * 16 + (ls >> 6)], 1ull << (ls & 63));
}

// ---------------- BFS (capped at 5) : one wave per source ----------------
__global__ __launch_bounds__(64) void k_bfs(const u64* __restrict__ adj, u8* __restrict__ dist) {
  int src = blockIdx.x;            // 0..NN-1
  int g = src >> 10, q = src & 1023;
  const u64* A = adj + (size_t)g * M * 16;
  u8* drow = dist + (size_t)src * M;
  __shared__ u64 cur[16], vis[16], part[64];
  int t = threadIdx.x;
  int4 six; six.x = six.y = six.z = six.w = 0x06060606;
  reinterpret_cast<int4*>(drow)[t] = six;                 // fill with 6
  if (t < 16) { vis[t] = 0; cur[t] = 0; }
  __syncthreads();
  if (t == 0) {
    drow[q] = 0;
    cur[q >> 6] = 1ull << (q & 63);
    vis[q >> 6] = 1ull << (q & 63);
  }
  __syncthreads();
  const int w = t & 15, grp = t >> 4;
  for (int l = 1; l <= 5; ++l) {
    u64 acc = 0;
    for (int j = grp * 256; j < grp * 256 + 256; ++j) {
      if (cur[j >> 6] & (1ull << (j & 63))) acc |= A[(size_t)j * 16 + w];
    }
    part[t] = acc;
    __syncthreads();
    if (t < 16) {
      u64 nxt = part[t] | part[16 + t] | part[32 + t] | part[48 + t];
      u64 newly = nxt & ~vis[t];
      vis[t] |= newly;
      cur[t] = newly;
      u64 b = newly;
      while (b) {
        int k = __ffsll(b) - 1;
        b &= b - 1;
        drow[t * 64 + k] = (u8)l;
      }
    }
    __syncthreads();
    bool nz = (t < 16) && (cur[t] != 0);
    if (__ballot(nz) == 0) break;
  }
}

// ---------------- flash attention with SPD bias ----------------
__global__ __launch_bounds__(256) void k_attn(const float* __restrict__ qkvb,
                                              const u8* __restrict__ dist,
                                              const float* __restrict__ emb,
                                              float* __restrict__ attno) {
  __shared__ __align__(16) float Ks[64][32];
  __shared__ __align__(16) float Vs[64][32];
  __shared__ float semb[8];
  const int g = blockIdx.z, head = blockIdx.y, t = threadIdx.x;
  const int qrow = blockIdx.x * 256 + t;
  if (t < 7) semb[t] = emb[t];
  float q[32];
  const float* qp = &qkvb[((size_t)(g * M + qrow)) * 768 + head * 32];
  #pragma unroll
  for (int c = 0; c < 8; ++c) {
    float4 v = *reinterpret_cast<const float4*>(qp + c * 4);
    q[c*4+0] = v.x * 0.17677669529663687f; q[c*4+1] = v.y * 0.17677669529663687f;
    q[c*4+2] = v.z * 0.17677669529663687f; q[c*4+3] = v.w * 0.17677669529663687f;
  }
  const u8* drow = &dist[((size_t)(g * M + qrow)) * M];
  float m = -3.0e38f, l = 0.0f, acc[32] = {};
  for (int kt = 0; kt < 16; ++kt) {
    #pragma unroll
    for (int i = 0; i < 2; ++i) {
      int f = t * 2 + i, r = f >> 3, c4 = (f & 7) * 4;
      const float* kp = &qkvb[((size_t)(g * M + kt * 64 + r)) * 768 + 256 + head * 32 + c4];
      const float* vp = &qkvb[((size_t)(g * M + kt * 64 + r)) * 768 + 512 + head * 32 + c4];
      float4 kv = *reinterpret_cast<const float4*>(kp);
      float4 vv = *reinterpret_cast<const float4*>(vp);
      Ks[r][c4+0] = kv.x; Ks[r][c4+1] = kv.y; Ks[r][c4+2] = kv.z; Ks[r][c4+3] = kv.w;
      Vs[r][c4+0] = vv.x; Vs[r][c4+1] = vv.y; Vs[r][c4+2] = vv.z; Vs[r][c4+3] = vv.w;
    }
    __syncthreads();
    for (int kk = 0; kk < 64; ++kk) {
      float s = 0.0f;
      #pragma unroll
      for (int c = 0; c < 8; ++c) {
        float4 kv = *reinterpret_cast<const float4*>(&Ks[kk][c*4]);
        s += q[c*4+0]*kv.x + q[c*4+1]*kv.y + q[c*4+2]*kv.z + q[c*4+3]*kv.w;
      }
      s += semb[drow[kt * 64 + kk]];
      if (s <= m) {
        float p = __expf(s - m);
        l += p;
        #pragma unroll
        for (int c = 0; c < 8; ++c) {
          float4 vv = *reinterpret_cast<const float4*>(&Vs[kk][c*4]);
          acc[c*4+0] += p * vv.x; acc[c*4+1] += p * vv.y;
          acc[c*4+2] += p * vv.z; acc[c*4+3] += p * vv.w;
        }
      } else {
        float corr = __expf(m - s);
        m = s;
        l = l * corr + 1.0f;
        #pragma unroll
        for (int c = 0; c < 8; ++c) {
          float4 vv = *reinterpret_cast<const float4*>(&Vs[kk][c*4]);
          acc[c*4+0] = acc[c*4+0]*corr + vv.x; acc[c*4+1] = acc[c*4+1]*corr + vv.y;
          acc[c*4+2] = acc[c*4+2]*corr + vv.z; acc[c*4+3] = acc[c*4+3]*corr + vv.w;
        }
      }
    }
    __syncthreads();
  }
  float inv = 1.0f / l;
  float* op = &attno[((size_t)(g * M + qrow)) * H + head * 32];
  #pragma unroll
  for (int c = 0; c < 8; ++c) {
    float4 o;
    o.x = acc[c*4+0]*inv; o.y = acc[c*4+1]*inv; o.z = acc[c*4+2]*inv; o.w = acc[c*4+3]*inv;
    *reinterpret_cast<float4*>(op + c * 4) = o;
  }
}

// ---------------- fused add(2|3) + LayerNorm ----------------
__global__ __launch_bounds__(256) void k_ln(const float* __restrict__ a, const float* __restrict__ b,
                                            const float* __restrict__ c3,
                                            const float* __restrict__ gam, const float* __restrict__ bet,
                                            float* __restrict__ out) {
  int row = blockIdx.x, t = threadIdx.x;
  size_t idx = (size_t)row * H + t;
  float v = a[idx] + b[idx];
  if (c3) v += c3[idx];
  float s = v, s2 = v * v;
  #pragma unroll
  for (int off = 32; off >= 1; off >>= 1) {
    s  += __shfl_down(s, off);
    s2 += __shfl_down(s2, off);
  }
  __shared__ float rs[4], rq[4], smean, srstd;
  int wv = t >> 6, ln = t & 63;
  if (ln == 0) { rs[wv] = s; rq[wv] = s2; }
  __syncthreads();
  if (t == 0) {
    float S = rs[0]+rs[1]+rs[2]+rs[3], Q = rq[0]+rq[1]+rq[2]+rq[3];
    float mean = S / (float)H;
    float var = Q / (float)H - mean * mean;
    smean = mean; srstd = rsqrtf(var + 1e-5f);
  }
  __syncthreads();
  out[idx] = (v - smean) * srstd * gam[t] + bet[t];
}

// ---------------- launch ----------------
extern "C" void kernel_launch(void* const* d_in, const int* in_sizes, int n_in,
                              void* d_out, int out_size, void* d_ws, size_t ws_size,
                              hipStream_t stream) {
  const float* x      = (const float*)d_in[0];
  const float* gcn_w  = (const float*)d_in[1];
  const float* gcn_b  = (const float*)d_in[2];
  const float* qkv_w  = (const float*)d_in[3];
  const float* qkv_b  = (const float*)d_in[4];
  const float* proj_w = (const float*)d_in[5];
  const float* proj_b = (const float*)d_in[6];
  const float* ln1_g  = (const float*)d_in[7];
  const float* ln1_b  = (const float*)d_in[8];
  const float* ln2_g  = (const float*)d_in[9];
  const float* ln2_b  = (const float*)d_in[10];
  const float* ffn1_w = (const float*)d_in[11];
  const float* ffn1_b = (const float*)d_in[12];
  const float* ffn2_w = (const float*)d_in[13];
  const float* ffn2_b = (const float*)d_in[14];
  const float* bias_e = (const float*)d_in[15];
  const float* oln1_g = (const float*)d_in[16];
  const float* oln1_b = (const float*)d_in[17];
  const float* oln2_g = (const float*)d_in[18];
  const float* oln2_b = (const float*)d_in[19];
  const float* offn1_w= (const float*)d_in[20];
  const float* offn1_b= (const float*)d_in[21];
  const float* offn2_w= (const float*)d_in[22];
  const float* offn2_b= (const float*)d_in[23];
  const int*   eidx   = (const int*)d_in[24];
  const int* esrc = eidx;
  const int* edst = eidx + NE;

  char* w = (char*)d_ws;
  size_t off = 0;
  auto alloc = [&](size_t bytes) { void* p = w + off; off += (bytes + 255) & ~255ull; return p; };
  const size_t SZ_NH = (size_t)NN * H * 4;
  float* xw   = (float*)alloc(SZ_NH);
  float* agg  = (float*)alloc(SZ_NH);
  float* xloc = (float*)alloc(SZ_NH);
  float* dinv = (float*)alloc((size_t)NN * 4);
  int*   deg  = (int*)  alloc((size_t)NN * 4);
  u64*   adj  = (u64*)  alloc((size_t)G * M * 16 * 8);
  u8*    dist = (u8*)   alloc((size_t)G * M * M);      // 8 MiB
  float* qkvb = (float*)alloc((size_t)NN * 768 * 4);   // 24 MiB (contiguous after dist)
  float* h1   = (float*)alloc(SZ_NH);
  float* f2   = (float*)alloc(SZ_NH);
  float* h2   = (float*)alloc(SZ_NH);
  float* y    = (float*)alloc(SZ_NH);
  float* mid  = (float*)dist;       // 32 MiB alias over dist+qkvb (dead after attention)
  float* attno = agg;               // agg dead after k_xlocal
  float* projo = xw;                // xw dead after k_xlocal
  float* outp  = (float*)d_out;

  hipMemsetAsync(deg, 0, (size_t)NN * 4, stream);
  hipMemsetAsync(agg, 0, SZ_NH, stream);
  hipMemsetAsync(adj, 0, (size_t)G * M * 16 * 8, stream);

  // --- GCN local path ---
  k_deg<<<(NE + 255) / 256, 256, 0, stream>>>(edst, deg);
  k_dinv<<<NN / 256, 256, 0, stream>>>(deg, dinv);
  k_gemm<0><<<dim3(H / 64, NN / 64), 256, 0, stream>>>(x, gcn_w, nullptr, xw, H, H);
  k_scatter<<<NE * 64 / 256, 256, 0, stream>>>(esrc, edst, dinv, xw, agg);
  k_xlocal<<<NN * 64 / 256, 256, 0, stream>>>(xw, agg, dinv, gcn_b, xloc);

  // --- SPD distances ---
  k_adj<<<(NE + 255) / 256, 256, 0, stream>>>(esrc, edst, adj);
  k_bfs<<<NN, 64, 0, stream>>>(adj, dist);

  // --- Graphormer encoder ---
  k_gemm<0><<<dim3(768 / 64, NN / 64), 256, 0, stream>>>(x, qkv_w, qkv_b, qkvb, H, 768);
  k_attn<<<dim3(M / 256, HEADS, G), 256, 0, stream>>>(qkvb, dist, bias_e, attno);
  k_gemm<0><<<dim3(H / 64, NN / 64), 256, 0, stream>>>(attno, proj_w, proj_b, projo, H, H);
  k_ln<<<NN, 256, 0, stream>>>(x, projo, nullptr, ln1_g, ln1_b, h1);
  k_gemm<1><<<dim3(FFND / 64, NN / 64), 256, 0, stream>>>(h1, ffn1_w, ffn1_b, mid, H, FFND);
  k_gemm<0><<<dim3(H / 64, NN / 64), 256, 0, stream>>>(mid, ffn2_w, ffn2_b, f2, FFND, H);
  k_ln<<<NN, 256, 0, stream>>>(h1, f2, nullptr, ln2_g, ln2_b, h2);

  // --- GPS combine + outer FFN ---
  k_ln<<<NN, 256, 0, stream>>>(x, xloc, h2, oln1_g, oln1_b, y);
  k_gemm<1><<<dim3(FFND / 64, NN / 64), 256, 0, stream>>>(y, offn1_w, offn1_b, mid, H, FFND);
  k_gemm<0><<<dim3(H / 64, NN / 64), 256, 0, stream>>>(mid, offn2_w, offn2_b, f2, FFND, H);
  k_ln<<<NN, 256, 0, stream>>>(y, f2, nullptr, oln2_g, oln2_b, outp);
}

// Round 2
// 898.768 us; speedup vs baseline: 1.9454x; 1.9454x over previous
//
#include <hip/hip_runtime.h>
#include <hip/hip_bf16.h>
#include <cstdint>

#define G 8
#define M 1024
#define H 256
#define HEADS 8
#define FFND 1024
#define NE 131072
#define NN (G*M)          // 8192
#define HD 32             // H/HEADS

typedef unsigned long long u64;
typedef uint8_t u8;
typedef unsigned short ushort_t;
typedef __attribute__((ext_vector_type(8))) short bf16x8;
typedef __attribute__((ext_vector_type(4))) float f32x4;

__device__ __forceinline__ short f2b(float v) {
  __hip_bfloat16 h = __float2bfloat16(v);
  return *reinterpret_cast<short*>(&h);
}
__device__ __forceinline__ float b2f(unsigned int u) {
  union { float f; unsigned int i; } v; v.i = u << 16; return v.f;
}

typedef __attribute__((address_space(1))) const void gvoid;
typedef __attribute__((address_space(3))) void lvoid;
__device__ __forceinline__ void gload16(const void* g, void* l) {
  __builtin_amdgcn_global_load_lds((gvoid*)g, (lvoid*)l, 16, 0, 0);
}

// ---------------- degree / dinv ----------------
__global__ void k_deg(const int* __restrict__ dst, int* __restrict__ deg) {
  int e = blockIdx.x * 256 + threadIdx.x;
  if (e < NE) atomicAdd(&deg[dst[e]], 1);
}

__global__ void k_dinv(const int* __restrict__ deg, float* __restrict__ dinv) {
  int i = blockIdx.x * 256 + threadIdx.x;
  if (i < NN) dinv[i] = rsqrtf((float)(deg[i] + 1));   // +1 self loop
}

// ---------------- exclusive prefix sum of deg (NN=8192, one block) ----------------
__global__ __launch_bounds__(1024) void k_scan(const int* __restrict__ deg, int* __restrict__ starts) {
  __shared__ int tmp[1024];
  int t = threadIdx.x;
  int base = t * 8;
  int v[8]; int s = 0;
  #pragma unroll
  for (int i = 0; i < 8; ++i) { v[i] = deg[base + i]; s += v[i]; }
  tmp[t] = s;
  __syncthreads();
  for (int off = 1; off < 1024; off <<= 1) {
    int x = (t >= off) ? tmp[t - off] : 0;
    __syncthreads();
    tmp[t] += x;
    __syncthreads();
  }
  int ex = (t == 0) ? 0 : tmp[t - 1];
  #pragma unroll
  for (int i = 0; i < 8; ++i) { starts[base + i] = ex; ex += v[i]; }
}

// ---------------- CSR fill ----------------
__global__ void k_fill(const int* __restrict__ srcv, const int* __restrict__ dstv,
                       const int* __restrict__ starts, int* __restrict__ cursor,
                       int* __restrict__ csr) {
  int e = blockIdx.x * 256 + threadIdx.x;
  if (e >= NE) return;
  int d = dstv[e];
  int pos = atomicAdd(&cursor[d], 1);
  csr[starts[d] + pos] = srcv[e];
}

// ---------------- CSR gather (fuses xlocal epilogue) ----------------
__global__ __launch_bounds__(256) void k_gather(const int* __restrict__ csr,
    const int* __restrict__ starts, const int* __restrict__ deg,
    const float* __restrict__ dinv, const float* __restrict__ xw,
    const float* __restrict__ gcn_b, float* __restrict__ xloc) {
  int d = blockIdx.x, t = threadIdx.x;
  int s0 = starts[d], cnt = deg[d];
  float acc = 0.f;
  for (int j = 0; j < cnt; ++j) {
    int s = csr[s0 + j];
    acc += dinv[s] * xw[(size_t)s * H + t];
  }
  float di = dinv[d];
  float self = xw[(size_t)d * H + t];
  xloc[(size_t)d * H + t] = di * acc + di * di * self + gcn_b[t];
}

// ---------------- fp32 -> bf16 converts ----------------
__global__ void k_cvt(const float* __restrict__ in, ushort_t* __restrict__ out, int n4) {
  int i = blockIdx.x * 256 + threadIdx.x;
  if (i >= n4) return;
  float4 v = reinterpret_cast<const float4*>(in)[i];
  unsigned int lo = (unsigned int)(ushort_t)f2b(v.x) | ((unsigned int)(ushort_t)f2b(v.y) << 16);
  unsigned int hi = (unsigned int)(ushort_t)f2b(v.z) | ((unsigned int)(ushort_t)f2b(v.w) << 16);
  reinterpret_cast<uint2*>(out)[i] = make_uint2(lo, hi);
}

#define WB_GCN   0
#define WB_QKV   65536
#define WB_PROJ  262144
#define WB_FFN1  327680
#define WB_FFN2  589824
#define WB_OFFN1 851968
#define WB_OFFN2 1114112
#define WB_TOTAL 1376256

__global__ void k_cvtw(const float* p0, const float* p1, const float* p2,
                       const float* p3, const float* p4, const float* p5,
                       const float* p6, ushort_t* __restrict__ out) {
  int i = blockIdx.x * 256 + threadIdx.x;
  if (i >= WB_TOTAL) return;
  const float* src; int off;
  if (i < WB_QKV)        { src = p0; off = i; }
  else if (i < WB_PROJ)  { src = p1; off = i - WB_QKV; }
  else if (i < WB_FFN1)  { src = p2; off = i - WB_PROJ; }
  else if (i < WB_FFN2)  { src = p3; off = i - WB_FFN1; }
  else if (i < WB_OFFN1) { src = p4; off = i - WB_FFN2; }
  else if (i < WB_OFFN2) { src = p5; off = i - WB_OFFN1; }
  else                   { src = p6; off = i - WB_OFFN2; }
  out[i] = (ushort_t)f2b(src[off]);
}

// ---------------- bf16 MFMA GEMM: C[NI,O] = A[NI,K] @ W[O,K]^T + bias ----------------
// BM=128, BN=64, BK=64; 4 waves as 2x2; per wave 4x2 frags of 16x16.
// LDS linear, global source pre-swizzled (byte16-slot ^= row&7), reads XOR-swizzled.
template<int ACT, int OBF>
__global__ __launch_bounds__(256) void k_mgemm(const short* __restrict__ A,
                                               const short* __restrict__ W,
                                               const float* __restrict__ bias,
                                               float* __restrict__ Cf,
                                               short* __restrict__ Cb,
                                               int K, int O) {
  __shared__ __attribute__((aligned(16))) short As[128 * 64];
  __shared__ __attribute__((aligned(16))) short Ws[64 * 64];
  const int tid = threadIdx.x;
  const int lane = tid & 63, wbase = tid & 192;   // wbase = wid*64
  const int wid = tid >> 6;
  const int wm = wid >> 1, wn = wid & 1;
  const int m0 = blockIdx.y * 128, n0 = blockIdx.x * 64;
  f32x4 acc[4][2];
  #pragma unroll
  for (int i = 0; i < 4; ++i)
    #pragma unroll
    for (int j = 0; j < 2; ++j)
      acc[i][j] = (f32x4){0.f, 0.f, 0.f, 0.f};

  for (int k0 = 0; k0 < K; k0 += 64) {
    #pragma unroll
    for (int c = 0; c < 4; ++c) {           // A tile: 128x64 bf16 = 16KB
      int chunk = c * 256 + tid;
      int row = chunk >> 3, ks = chunk & 7;
      int srcks = ks ^ (row & 7);
      gload16(A + (size_t)(m0 + row) * K + k0 + srcks * 8,
              (char*)As + (c * 256 + wbase) * 16);
    }
    #pragma unroll
    for (int c = 0; c < 2; ++c) {           // W tile: 64x64 bf16 = 8KB
      int chunk = c * 256 + tid;
      int row = chunk >> 3, ks = chunk & 7;
      int srcks = ks ^ (row & 7);
      gload16(W + (size_t)(n0 + row) * K + k0 + srcks * 8,
              (char*)Ws + (c * 256 + wbase) * 16);
    }
    __syncthreads();
    #pragma unroll
    for (int kk = 0; kk < 2; ++kk) {
      const int d = kk * 4 + (lane >> 4);
      bf16x8 b[2];
      #pragma unroll
      for (int fn = 0; fn < 2; ++fn) {
        int r = wn * 32 + fn * 16 + (lane & 15);
        b[fn] = *reinterpret_cast<const bf16x8*>((const char*)Ws + r * 128 + ((d ^ (r & 7)) * 16));
      }
      #pragma unroll
      for (int fm = 0; fm < 4; ++fm) {
        int r = wm * 64 + fm * 16 + (lane & 15);
        bf16x8 a = *reinterpret_cast<const bf16x8*>((const char*)As + r * 128 + ((d ^ (r & 7)) * 16));
        acc[fm][0] = __builtin_amdgcn_mfma_f32_16x16x32_bf16(a, b[0], acc[fm][0], 0, 0, 0);
        acc[fm][1] = __builtin_amdgcn_mfma_f32_16x16x32_bf16(a, b[1], acc[fm][1], 0, 0, 0);
      }
    }
    __syncthreads();
  }
  #pragma unroll
  for (int fm = 0; fm < 4; ++fm)
    #pragma unroll
    for (int fn = 0; fn < 2; ++fn)
      #pragma unroll
      for (int rg = 0; rg < 4; ++rg) {
        int r = m0 + wm * 64 + fm * 16 + (lane >> 4) * 4 + rg;
        int cc = n0 + wn * 32 + fn * 16 + (lane & 15);
        float v = acc[fm][fn][rg] + (bias ? bias[cc] : 0.f);
        if (ACT == 1) v = 0.5f * v * (1.0f + erff(v * 0.70710678118654752f));
        if (OBF) Cb[(size_t)r * O + cc] = f2b(v);
        else     Cf[(size_t)r * O + cc] = v;
      }
}

// ---------------- adjacency bitset ----------------
__global__ void k_adj(const int* __restrict__ srcv, const int* __restrict__ dstv,
                      u64* __restrict__ adj) {
  int e = blockIdx.x * 256 + threadIdx.x;
  if (e >= NE) return;
  int s = srcv[e], d = dstv[e];
  if (s == d) return;
  int g = s >> 10, ls = s & 1023, ld = d & 1023;
  atomicOr(&adj[((size_t)((g << 10) | ls)) * 16 + (ld >> 6)], 1ull << (ld & 63));
  atomicOr(&adj[((size_t)((g << 10) | ld)) * 16 + (ls >> 6)], 1ull << (ls & 63));
}

// ---------------- BFS (capped at 5) : one wave per source ----------------
__global__ __launch_bounds__(64) void k_bfs(const u64* __restrict__ adj, u8* __restrict__ dist) {
  int src = blockIdx.x;
  int g = src >> 10, q = src & 1023;
  const u64* A = adj + (size_t)g * M * 16;
  u8* drow = dist + (size_t)src * M;
  __shared__ u64 cur[16], vis[16], part[64];
  int t = threadIdx.x;
  int4 six; six.x = six.y = six.z = six.w = 0x06060606;
  reinterpret_cast<int4*>(drow)[t] = six;
  if (t < 16) { vis[t] = 0; cur[t] = 0; }
  __syncthreads();
  if (t == 0) {
    drow[q] = 0;
    cur[q >> 6] = 1ull << (q & 63);
    vis[q >> 6] = 1ull << (q & 63);
  }
  __syncthreads();
  const int w = t & 15, grp = t >> 4;
  for (int l = 1; l <= 5; ++l) {
    u64 acc = 0;
    for (int j = grp * 256; j < grp * 256 + 256; ++j) {
      if (cur[j >> 6] & (1ull << (j & 63))) acc |= A[(size_t)j * 16 + w];
    }
    part[t] = acc;
    __syncthreads();
    if (t < 16) {
      u64 nxt = part[t] | part[16 + t] | part[32 + t] | part[48 + t];
      u64 newly = nxt & ~vis[t];
      vis[t] |= newly;
      cur[t] = newly;
      u64 b = newly;
      while (b) {
        int k = __ffsll(b) - 1;
        b &= b - 1;
        drow[t * 64 + k] = (u8)l;
      }
    }
    __syncthreads();
    bool nz = (t < 16) && (cur[t] != 0);
    if (__ballot(nz) == 0) break;
  }
}

// ---------------- flash attention with SPD bias (bf16 qkv in, bf16 out) ----------------
__global__ __launch_bounds__(256) void k_attn(const ushort_t* __restrict__ qkv,
                                              const u8* __restrict__ dist,
                                              const float* __restrict__ emb,
                                              short* __restrict__ attno) {
  __shared__ __attribute__((aligned(16))) float Ks[64][32];
  __shared__ __attribute__((aligned(16))) float Vs[64][32];
  __shared__ float semb[8];
  const int g = blockIdx.z, head = blockIdx.y, t = threadIdx.x;
  const int qrow = blockIdx.x * 256 + t;
  if (t < 7) semb[t] = emb[t];
  float q[32];
  const ushort_t* qp = qkv + ((size_t)(g * M + qrow)) * 768 + head * 32;
  const float SC = 0.17677669529663687f;
  #pragma unroll
  for (int c = 0; c < 4; ++c) {
    uint4 raw = reinterpret_cast<const uint4*>(qp)[c];
    q[c*8+0] = b2f(raw.x & 0xffff) * SC; q[c*8+1] = b2f(raw.x >> 16) * SC;
    q[c*8+2] = b2f(raw.y & 0xffff) * SC; q[c*8+3] = b2f(raw.y >> 16) * SC;
    q[c*8+4] = b2f(raw.z & 0xffff) * SC; q[c*8+5] = b2f(raw.z >> 16) * SC;
    q[c*8+6] = b2f(raw.w & 0xffff) * SC; q[c*8+7] = b2f(raw.w >> 16) * SC;
  }
  const u8* drow = &dist[((size_t)(g * M + qrow)) * M];
  float m = -3.0e38f, l = 0.0f, acc[32] = {};
  for (int kt = 0; kt < 16; ++kt) {
    {
      int r = t >> 2, c8 = (t & 3) * 8;
      const ushort_t* kp = qkv + ((size_t)(g * M + kt * 64 + r)) * 768 + 256 + head * 32 + c8;
      const ushort_t* vp = qkv + ((size_t)(g * M + kt * 64 + r)) * 768 + 512 + head * 32 + c8;
      uint4 kraw = *reinterpret_cast<const uint4*>(kp);
      uint4 vraw = *reinterpret_cast<const uint4*>(vp);
      Ks[r][c8+0] = b2f(kraw.x & 0xffff); Ks[r][c8+1] = b2f(kraw.x >> 16);
      Ks[r][c8+2] = b2f(kraw.y & 0xffff); Ks[r][c8+3] = b2f(kraw.y >> 16);
      Ks[r][c8+4] = b2f(kraw.z & 0xffff); Ks[r][c8+5] = b2f(kraw.z >> 16);
      Ks[r][c8+6] = b2f(kraw.w & 0xffff); Ks[r][c8+7] = b2f(kraw.w >> 16);
      Vs[r][c8+0] = b2f(vraw.x & 0xffff); Vs[r][c8+1] = b2f(vraw.x >> 16);
      Vs[r][c8+2] = b2f(vraw.y & 0xffff); Vs[r][c8+3] = b2f(vraw.y >> 16);
      Vs[r][c8+4] = b2f(vraw.z & 0xffff); Vs[r][c8+5] = b2f(vraw.z >> 16);
      Vs[r][c8+6] = b2f(vraw.w & 0xffff); Vs[r][c8+7] = b2f(vraw.w >> 16);
    }
    __syncthreads();
    for (int kk = 0; kk < 64; ++kk) {
      float s = 0.0f;
      #pragma unroll
      for (int c = 0; c < 8; ++c) {
        float4 kv = *reinterpret_cast<const float4*>(&Ks[kk][c*4]);
        s += q[c*4+0]*kv.x + q[c*4+1]*kv.y + q[c*4+2]*kv.z + q[c*4+3]*kv.w;
      }
      s += semb[drow[kt * 64 + kk]];
      if (s <= m) {
        float p = __expf(s - m);
        l += p;
        #pragma unroll
        for (int c = 0; c < 8; ++c) {
          float4 vv = *reinterpret_cast<const float4*>(&Vs[kk][c*4]);
          acc[c*4+0] += p * vv.x; acc[c*4+1] += p * vv.y;
          acc[c*4+2] += p * vv.z; acc[c*4+3] += p * vv.w;
        }
      } else {
        float corr = __expf(m - s);
        m = s;
        l = l * corr + 1.0f;
        #pragma unroll
        for (int c = 0; c < 8; ++c) {
          float4 vv = *reinterpret_cast<const float4*>(&Vs[kk][c*4]);
          acc[c*4+0] = acc[c*4+0]*corr + vv.x; acc[c*4+1] = acc[c*4+1]*corr + vv.y;
          acc[c*4+2] = acc[c*4+2]*corr + vv.z; acc[c*4+3] = acc[c*4+3]*corr + vv.w;
        }
      }
    }
    __syncthreads();
  }
  float inv = 1.0f / l;
  unsigned int* op = reinterpret_cast<unsigned int*>(attno + ((size_t)(g * M + qrow)) * H + head * 32);
  #pragma unroll
  for (int c = 0; c < 16; ++c) {
    unsigned int lo = (unsigned int)(ushort_t)f2b(acc[2*c] * inv);
    unsigned int hi = (unsigned int)(ushort_t)f2b(acc[2*c+1] * inv);
    op[c] = lo | (hi << 16);
  }
}

// ---------------- fused add(2|3) + LayerNorm (+optional bf16 copy) ----------------
__global__ __launch_bounds__(256) void k_ln(const float* __restrict__ a, const float* __restrict__ b,
                                            const float* __restrict__ c3,
                                            const float* __restrict__ gam, const float* __restrict__ bet,
                                            float* __restrict__ out, ushort_t* __restrict__ outb) {
  int row = blockIdx.x, t = threadIdx.x;
  size_t idx = (size_t)row * H + t;
  float v = a[idx] + b[idx];
  if (c3) v += c3[idx];
  float s = v, s2 = v * v;
  #pragma unroll
  for (int off = 32; off >= 1; off >>= 1) {
    s  += __shfl_down(s, off);
    s2 += __shfl_down(s2, off);
  }
  __shared__ float rs[4], rq[4], smean, srstd;
  int wv = t >> 6, ln = t & 63;
  if (ln == 0) { rs[wv] = s; rq[wv] = s2; }
  __syncthreads();
  if (t == 0) {
    float S = rs[0]+rs[1]+rs[2]+rs[3], Q = rq[0]+rq[1]+rq[2]+rq[3];
    float mean = S / (float)H;
    float var = Q / (float)H - mean * mean;
    smean = mean; srstd = rsqrtf(var + 1e-5f);
  }
  __syncthreads();
  float r = (v - smean) * srstd * gam[t] + bet[t];
  out[idx] = r;
  if (outb) outb[idx] = (ushort_t)f2b(r);
}

// ---------------- launch ----------------
extern "C" void kernel_launch(void* const* d_in, const int* in_sizes, int n_in,
                              void* d_out, int out_size, void* d_ws, size_t ws_size,
                              hipStream_t stream) {
  const float* x      = (const float*)d_in[0];
  const float* gcn_w  = (const float*)d_in[1];
  const float* gcn_b  = (const float*)d_in[2];
  const float* qkv_w  = (const float*)d_in[3];
  const float* qkv_b  = (const float*)d_in[4];
  const float* proj_w = (const float*)d_in[5];
  const float* proj_b = (const float*)d_in[6];
  const float* ln1_g  = (const float*)d_in[7];
  const float* ln1_b  = (const float*)d_in[8];
  const float* ln2_g  = (const float*)d_in[9];
  const float* ln2_b  = (const float*)d_in[10];
  const float* ffn1_w = (const float*)d_in[11];
  const float* ffn1_b = (const float*)d_in[12];
  const float* ffn2_w = (const float*)d_in[13];
  const float* ffn2_b = (const float*)d_in[14];
  const float* bias_e = (const float*)d_in[15];
  const float* oln1_g = (const float*)d_in[16];
  const float* oln1_b = (const float*)d_in[17];
  const float* oln2_g = (const float*)d_in[18];
  const float* oln2_b = (const float*)d_in[19];
  const float* offn1_w= (const float*)d_in[20];
  const float* offn1_b= (const float*)d_in[21];
  const float* offn2_w= (const float*)d_in[22];
  const float* offn2_b= (const float*)d_in[23];
  const int*   eidx   = (const int*)d_in[24];
  const int* esrc = eidx;
  const int* edst = eidx + NE;

  char* wsp = (char*)d_ws;
  size_t off = 0;
  auto alloc = [&](size_t bytes) { void* p = wsp + off; off += (bytes + 255) & ~255ull; return p; };
  const size_t SZ_NH = (size_t)NN * H * 4;
  ushort_t* x_bf  = (ushort_t*)alloc((size_t)NN * H * 2);         // 4MB
  ushort_t* w_bf  = (ushort_t*)alloc((size_t)WB_TOTAL * 2);       // 2.75MB
  float* xw   = (float*)alloc(SZ_NH);                             // 8MB
  float* xloc = (float*)alloc(SZ_NH);                             // 8MB
  float* dinv = (float*)alloc((size_t)NN * 4);
  int*   deg  = (int*)  alloc((size_t)NN * 4);
  int* cursor = (int*)  alloc((size_t)NN * 4);
  int* starts = (int*)  alloc((size_t)NN * 4);
  int*   csr  = (int*)  alloc((size_t)NE * 4);                    // 0.5MB
  u64*   adj  = (u64*)  alloc((size_t)G * M * 16 * 8);            // 1MB
  u8*    dist = (u8*)   alloc((size_t)G * M * M);                 // 8MB
  ushort_t* qkvb = (ushort_t*)alloc((size_t)NN * 768 * 2);        // 12MB (right after dist)
  float* h1   = (float*)alloc(SZ_NH);                             // 8MB
  ushort_t* h1_bf = (ushort_t*)alloc((size_t)NN * H * 2);         // 4MB
  float* f2   = (float*)alloc(SZ_NH);                             // 8MB
  float* h2   = (float*)alloc(SZ_NH);                             // 8MB
  float* y    = (float*)alloc(SZ_NH);                             // 8MB

  ushort_t* attno = x_bf;                  // x_bf dead after qkv gemm
  float* projo = xw;                       // xw dead after gather
  ushort_t* mid = (ushort_t*)dist;         // dist+qkvb (20MB) dead after attn; mid=16MB
  ushort_t* y_bf = h1_bf;                  // h1_bf dead after ffn1
  float* outp = (float*)d_out;

  ushort_t* gcn_wb  = w_bf + WB_GCN;
  ushort_t* qkv_wb  = w_bf + WB_QKV;
  ushort_t* proj_wb = w_bf + WB_PROJ;
  ushort_t* ffn1_wb = w_bf + WB_FFN1;
  ushort_t* ffn2_wb = w_bf + WB_FFN2;
  ushort_t* offn1_wb= w_bf + WB_OFFN1;
  ushort_t* offn2_wb= w_bf + WB_OFFN2;

  hipMemsetAsync(deg, 0, (size_t)NN * 4, stream);
  hipMemsetAsync(cursor, 0, (size_t)NN * 4, stream);
  hipMemsetAsync(adj, 0, (size_t)G * M * 16 * 8, stream);

  // conversions
  k_cvt<<<(NN * H / 4 + 255) / 256, 256, 0, stream>>>(x, x_bf, NN * H / 4);
  k_cvtw<<<(WB_TOTAL + 255) / 256, 256, 0, stream>>>(gcn_w, qkv_w, proj_w, ffn1_w,
                                                     ffn2_w, offn1_w, offn2_w, w_bf);

  // --- GCN local path (CSR gather, no float atomics) ---
  k_deg<<<(NE + 255) / 256, 256, 0, stream>>>(edst, deg);
  k_dinv<<<NN / 256, 256, 0, stream>>>(deg, dinv);
  k_scan<<<1, 1024, 0, stream>>>(deg, starts);
  k_fill<<<(NE + 255) / 256, 256, 0, stream>>>(esrc, edst, starts, cursor, csr);
  k_mgemm<0,0><<<dim3(H / 64, NN / 128), 256, 0, stream>>>(
      (const short*)x_bf, (const short*)gcn_wb, nullptr, xw, nullptr, H, H);
  k_gather<<<NN, 256, 0, stream>>>(csr, starts, deg, dinv, xw, gcn_b, xloc);

  // --- SPD distances ---
  k_adj<<<(NE + 255) / 256, 256, 0, stream>>>(esrc, edst, adj);
  k_bfs<<<NN, 64, 0, stream>>>(adj, dist);

  // --- Graphormer encoder ---
  k_mgemm<0,1><<<dim3(768 / 64, NN / 128), 256, 0, stream>>>(
      (const short*)x_bf, (const short*)qkv_wb, qkv_b, nullptr, (short*)qkvb, H, 768);
  k_attn<<<dim3(M / 256, HEADS, G), 256, 0, stream>>>(qkvb, dist, bias_e, (short*)attno);
  k_mgemm<0,0><<<dim3(H / 64, NN / 128), 256, 0, stream>>>(
      (const short*)attno, (const short*)proj_wb, proj_b, projo, nullptr, H, H);
  k_ln<<<NN, 256, 0, stream>>>(x, projo, nullptr, ln1_g, ln1_b, h1, h1_bf);
  k_mgemm<1,1><<<dim3(FFND / 64, NN / 128), 256, 0, stream>>>(
      (const short*)h1_bf, (const short*)ffn1_wb, ffn1_b, nullptr, (short*)mid, H, FFND);
  k_mgemm<0,0><<<dim3(H / 64, NN / 128), 256, 0, stream>>>(
      (const short*)mid, (const short*)ffn2_wb, ffn2_b, f2, nullptr, FFND, H);
  k_ln<<<NN, 256, 0, stream>>>(h1, f2, nullptr, ln2_g, ln2_b, h2, nullptr);

  // --- GPS combine + outer FFN ---
  k_ln<<<NN, 256, 0, stream>>>(x, xloc, h2, oln1_g, oln1_b, y, y_bf);
  k_mgemm<1,1><<<dim3(FFND / 64, NN / 128), 256, 0, stream>>>(
      (const short*)y_bf, (const short*)offn1_wb, offn1_b, nullptr, (short*)mid, H, FFND);
  k_mgemm<0,0><<<dim3(H / 64, NN / 128), 256, 0, stream>>>(
      (const short*)mid, (const short*)offn2_wb, offn2_b, f2, nullptr, FFND, H);
  k_ln<<<NN, 256, 0, stream>>>(y, f2, nullptr, oln2_g, oln2_b, outp, nullptr);
}

// Round 3
// 722.311 us; speedup vs baseline: 2.4207x; 1.2443x over previous
//
#include <hip/hip_runtime.h>
#include <hip/hip_bf16.h>
#include <cstdint>

#define G 8
#define M 1024
#define H 256
#define HEADS 8
#define FFND 1024
#define NE 131072
#define NN (G*M)          // 8192
#define HD 32             // H/HEADS
#define NSP 4             // attention K-splits
#define RIDX_N (G*HEADS*M)  // 65536

typedef unsigned long long u64;
typedef uint8_t u8;
typedef unsigned short ushort_t;
typedef __attribute__((ext_vector_type(8))) short bf16x8;
typedef __attribute__((ext_vector_type(4))) float f32x4;

__device__ __forceinline__ short f2b(float v) {
  __hip_bfloat16 h = __float2bfloat16(v);
  return *reinterpret_cast<short*>(&h);
}
__device__ __forceinline__ float b2f(unsigned int u) {
  union { float f; unsigned int i; } v; v.i = u << 16; return v.f;
}

typedef __attribute__((address_space(1))) const void gvoid;
typedef __attribute__((address_space(3))) void lvoid;
__device__ __forceinline__ void gload16(const void* g, void* l) {
  __builtin_amdgcn_global_load_lds((gvoid*)g, (lvoid*)l, 16, 0, 0);
}

// ---------------- degree kernels ----------------
__global__ void k_deg(const int* __restrict__ dst, int* __restrict__ deg) {
  int e = blockIdx.x * 256 + threadIdx.x;
  if (e < NE) atomicAdd(&deg[dst[e]], 1);
}

__global__ void k_deg2(const int* __restrict__ srcv, const int* __restrict__ dstv,
                       int* __restrict__ deg2) {
  int e = blockIdx.x * 256 + threadIdx.x;
  if (e >= NE) return;
  int a = srcv[e], b = dstv[e];
  if (a != b) { atomicAdd(&deg2[a], 1); atomicAdd(&deg2[b], 1); }
}

__global__ void k_dinv(const int* __restrict__ deg, float* __restrict__ dinv) {
  int i = blockIdx.x * 256 + threadIdx.x;
  if (i < NN) dinv[i] = rsqrtf((float)(deg[i] + 1));   // +1 self loop
}

// ---------------- exclusive prefix sum (NN=8192, one block) ----------------
__global__ __launch_bounds__(1024) void k_scan(const int* __restrict__ deg, int* __restrict__ starts) {
  __shared__ int tmp[1024];
  int t = threadIdx.x;
  int base = t * 8;
  int v[8]; int s = 0;
  #pragma unroll
  for (int i = 0; i < 8; ++i) { v[i] = deg[base + i]; s += v[i]; }
  tmp[t] = s;
  __syncthreads();
  for (int off = 1; off < 1024; off <<= 1) {
    int x = (t >= off) ? tmp[t - off] : 0;
    __syncthreads();
    tmp[t] += x;
    __syncthreads();
  }
  int ex = (t == 0) ? 0 : tmp[t - 1];
  #pragma unroll
  for (int i = 0; i < 8; ++i) { starts[base + i] = ex; ex += v[i]; }
}

// ---------------- CSR fills ----------------
__global__ void k_fill(const int* __restrict__ srcv, const int* __restrict__ dstv,
                       const int* __restrict__ starts, int* __restrict__ cursor,
                       int* __restrict__ csr) {
  int e = blockIdx.x * 256 + threadIdx.x;
  if (e >= NE) return;
  int d = dstv[e];
  int pos = atomicAdd(&cursor[d], 1);
  csr[starts[d] + pos] = srcv[e];
}

__global__ void k_fill2(const int* __restrict__ srcv, const int* __restrict__ dstv,
                        const int* __restrict__ starts2, int* __restrict__ cur2,
                        int* __restrict__ nbr) {
  int e = blockIdx.x * 256 + threadIdx.x;
  if (e >= NE) return;
  int a = srcv[e], b = dstv[e];
  if (a == b) return;
  int p = atomicAdd(&cur2[a], 1); nbr[starts2[a] + p] = b;
  p = atomicAdd(&cur2[b], 1);     nbr[starts2[b] + p] = a;
}

// ---------------- CSR gather (GCN, fuses xlocal epilogue) ----------------
__global__ __launch_bounds__(256) void k_gather(const int* __restrict__ csr,
    const int* __restrict__ starts, const int* __restrict__ deg,
    const float* __restrict__ dinv, const float* __restrict__ xw,
    const float* __restrict__ gcn_b, float* __restrict__ xloc) {
  int d = blockIdx.x, t = threadIdx.x;
  int s0 = starts[d], cnt = deg[d];
  float acc = 0.f;
  for (int j = 0; j < cnt; ++j) {
    int s = csr[s0 + j];
    acc += dinv[s] * xw[(size_t)s * H + t];
  }
  float di = dinv[d];
  float self = xw[(size_t)d * H + t];
  xloc[(size_t)d * H + t] = di * acc + di * di * self + gcn_b[t];
}

// ---------------- SPD: level-synchronous bitset propagation ----------------
__global__ void k_rinit(u64* __restrict__ R0) {
  int idx = blockIdx.x * 256 + threadIdx.x;       // NN*16
  int i = idx >> 4, w = idx & 15;
  int il = i & 1023;
  R0[idx] = (w == (il >> 6)) ? (1ull << (il & 63)) : 0ull;
}

__global__ void k_spd(const u64* __restrict__ prev, u64* __restrict__ cur,
                      const int* __restrict__ starts2, const int* __restrict__ deg2,
                      const int* __restrict__ nbr) {
  int idx = blockIdx.x * 256 + threadIdx.x;       // NN*16
  int i = idx >> 4, w = idx & 15;
  u64 acc = prev[idx];
  int s0 = starts2[i], cnt = deg2[i];
  for (int e = 0; e < cnt; ++e)
    acc |= prev[(size_t)nbr[s0 + e] * 16 + w];
  cur[idx] = acc;
}

// decode: dist byte = first level whose bitset contains the bit (monotone R1..R5)
__global__ void k_dist(const u64* __restrict__ R, u8* __restrict__ dist) {
  int idx = blockIdx.x * 256 + threadIdx.x;       // NN*256 (u32 granules)
  int i = idx >> 8, c = idx & 255;
  int w = c >> 4;
  const u64* p = R + (size_t)NN * 16 + (size_t)i * 16 + w;   // level 1
  u64 r1 = p[0];
  u64 r2 = p[(size_t)NN * 16];
  u64 r3 = p[(size_t)NN * 32];
  u64 r4 = p[(size_t)NN * 48];
  u64 r5 = p[(size_t)NN * 64];
  int il = i & 1023;
  unsigned int out = 0;
  #pragma unroll
  for (int j = 0; j < 4; ++j) {
    int kbit = (c & 15) * 4 + j;
    u64 msk = 1ull << kbit;
    int dd = 6 - (int)((r1 & msk) != 0) - (int)((r2 & msk) != 0) - (int)((r3 & msk) != 0)
               - (int)((r4 & msk) != 0) - (int)((r5 & msk) != 0);
    if (il == c * 4 + j) dd = 0;
    out |= (unsigned int)dd << (8 * j);
  }
  reinterpret_cast<unsigned int*>(dist)[idx] = out;
}

// ---------------- fp32 -> bf16 converts ----------------
__global__ void k_cvt(const float* __restrict__ in, ushort_t* __restrict__ out, int n4) {
  int i = blockIdx.x * 256 + threadIdx.x;
  if (i >= n4) return;
  float4 v = reinterpret_cast<const float4*>(in)[i];
  unsigned int lo = (unsigned int)(ushort_t)f2b(v.x) | ((unsigned int)(ushort_t)f2b(v.y) << 16);
  unsigned int hi = (unsigned int)(ushort_t)f2b(v.z) | ((unsigned int)(ushort_t)f2b(v.w) << 16);
  reinterpret_cast<uint2*>(out)[i] = make_uint2(lo, hi);
}

#define WB_GCN   0
#define WB_QKV   65536
#define WB_PROJ  262144
#define WB_FFN1  327680
#define WB_FFN2  589824
#define WB_OFFN1 851968
#define WB_OFFN2 1114112
#define WB_TOTAL 1376256

__global__ void k_cvtw(const float* p0, const float* p1, const float* p2,
                       const float* p3, const float* p4, const float* p5,
                       const float* p6, ushort_t* __restrict__ out) {
  int i = blockIdx.x * 256 + threadIdx.x;
  if (i >= WB_TOTAL) return;
  const float* src; int off;
  if (i < WB_QKV)        { src = p0; off = i; }
  else if (i < WB_PROJ)  { src = p1; off = i - WB_QKV; }
  else if (i < WB_FFN1)  { src = p2; off = i - WB_PROJ; }
  else if (i < WB_FFN2)  { src = p3; off = i - WB_FFN1; }
  else if (i < WB_OFFN1) { src = p4; off = i - WB_FFN2; }
  else if (i < WB_OFFN2) { src = p5; off = i - WB_OFFN1; }
  else                   { src = p6; off = i - WB_OFFN2; }
  out[i] = (ushort_t)f2b(src[off]);
}

// ---------------- bf16 MFMA GEMM: C[NI,O] = A[NI,K] @ W[O,K]^T + bias ----------------
template<int ACT, int OBF>
__global__ __launch_bounds__(256) void k_mgemm(const short* __restrict__ A,
                                               const short* __restrict__ W,
                                               const float* __restrict__ bias,
                                               float* __restrict__ Cf,
                                               short* __restrict__ Cb,
                                               int K, int O) {
  __shared__ __attribute__((aligned(16))) short As[128 * 64];
  __shared__ __attribute__((aligned(16))) short Ws[64 * 64];
  const int tid = threadIdx.x;
  const int lane = tid & 63, wbase = tid & 192;
  const int wid = tid >> 6;
  const int wm = wid >> 1, wn = wid & 1;
  const int m0 = blockIdx.y * 128, n0 = blockIdx.x * 64;
  f32x4 acc[4][2];
  #pragma unroll
  for (int i = 0; i < 4; ++i)
    #pragma unroll
    for (int j = 0; j < 2; ++j)
      acc[i][j] = (f32x4){0.f, 0.f, 0.f, 0.f};

  for (int k0 = 0; k0 < K; k0 += 64) {
    #pragma unroll
    for (int c = 0; c < 4; ++c) {
      int chunk = c * 256 + tid;
      int row = chunk >> 3, ks = chunk & 7;
      int srcks = ks ^ (row & 7);
      gload16(A + (size_t)(m0 + row) * K + k0 + srcks * 8,
              (char*)As + (c * 256 + wbase) * 16);
    }
    #pragma unroll
    for (int c = 0; c < 2; ++c) {
      int chunk = c * 256 + tid;
      int row = chunk >> 3, ks = chunk & 7;
      int srcks = ks ^ (row & 7);
      gload16(W + (size_t)(n0 + row) * K + k0 + srcks * 8,
              (char*)Ws + (c * 256 + wbase) * 16);
    }
    __syncthreads();
    #pragma unroll
    for (int kk = 0; kk < 2; ++kk) {
      const int d = kk * 4 + (lane >> 4);
      bf16x8 b[2];
      #pragma unroll
      for (int fn = 0; fn < 2; ++fn) {
        int r = wn * 32 + fn * 16 + (lane & 15);
        b[fn] = *reinterpret_cast<const bf16x8*>((const char*)Ws + r * 128 + ((d ^ (r & 7)) * 16));
      }
      #pragma unroll
      for (int fm = 0; fm < 4; ++fm) {
        int r = wm * 64 + fm * 16 + (lane & 15);
        bf16x8 a = *reinterpret_cast<const bf16x8*>((const char*)As + r * 128 + ((d ^ (r & 7)) * 16));
        acc[fm][0] = __builtin_amdgcn_mfma_f32_16x16x32_bf16(a, b[0], acc[fm][0], 0, 0, 0);
        acc[fm][1] = __builtin_amdgcn_mfma_f32_16x16x32_bf16(a, b[1], acc[fm][1], 0, 0, 0);
      }
    }
    __syncthreads();
  }
  #pragma unroll
  for (int fm = 0; fm < 4; ++fm)
    #pragma unroll
    for (int fn = 0; fn < 2; ++fn)
      #pragma unroll
      for (int rg = 0; rg < 4; ++rg) {
        int r = m0 + wm * 64 + fm * 16 + (lane >> 4) * 4 + rg;
        int cc = n0 + wn * 32 + fn * 16 + (lane & 15);
        float v = acc[fm][fn][rg] + (bias ? bias[cc] : 0.f);
        if (ACT == 1) v = 0.5f * v * (1.0f + erff(v * 0.70710678118654752f));
        if (OBF) Cb[(size_t)r * O + cc] = f2b(v);
        else     Cf[(size_t)r * O + cc] = v;
      }
}

// ---------------- flash attention, 4-way K-split, writes partials ----------------
// LDS slot swizzle: float4-slot(r, c) = r*8 + (c ^ (r&7)); row reads are uniform.
__global__ __launch_bounds__(256) void k_attn(const ushort_t* __restrict__ qkv,
                                              const u8* __restrict__ dist,
                                              const float* __restrict__ emb,
                                              float* __restrict__ pm,
                                              float* __restrict__ pl,
                                              float* __restrict__ pacc) {
  __shared__ __attribute__((aligned(16))) float Ks[64 * 32];
  __shared__ __attribute__((aligned(16))) float Vs[64 * 32];
  __shared__ float semb[8];
  const int g = blockIdx.z, head = blockIdx.y, t = threadIdx.x;
  const int qc = blockIdx.x & 3, sp = blockIdx.x >> 2;
  const int qrow = qc * 256 + t;
  const int kbase = sp * 256;
  if (t < 7) semb[t] = emb[t];
  float q[32];
  const ushort_t* qp = qkv + ((size_t)(g * M + qrow)) * 768 + head * 32;
  const float SC = 0.17677669529663687f;
  #pragma unroll
  for (int c = 0; c < 4; ++c) {
    uint4 raw = reinterpret_cast<const uint4*>(qp)[c];
    q[c*8+0] = b2f(raw.x & 0xffff) * SC; q[c*8+1] = b2f(raw.x >> 16) * SC;
    q[c*8+2] = b2f(raw.y & 0xffff) * SC; q[c*8+3] = b2f(raw.y >> 16) * SC;
    q[c*8+4] = b2f(raw.z & 0xffff) * SC; q[c*8+5] = b2f(raw.z >> 16) * SC;
    q[c*8+6] = b2f(raw.w & 0xffff) * SC; q[c*8+7] = b2f(raw.w >> 16) * SC;
  }
  const u8* drow = dist + ((size_t)(g * M + qrow)) * M + kbase;
  float m = -3.0e38f, l = 0.0f, acc[32] = {};
  for (int kt = 0; kt < 4; ++kt) {
    {
      int r = t >> 2, c8 = t & 3;      // row r, 8-float group c8
      const ushort_t* kp = qkv + ((size_t)(g * M + kbase + kt * 64 + r)) * 768 + 256 + head * 32 + c8 * 8;
      const ushort_t* vp = kp + 256;
      uint4 kraw = *reinterpret_cast<const uint4*>(kp);
      uint4 vraw = *reinterpret_cast<const uint4*>(vp);
      int sw = r & 7;
      float4* kd0 = reinterpret_cast<float4*>(Ks) + (r * 8 + ((2 * c8) ^ sw));
      float4* kd1 = reinterpret_cast<float4*>(Ks) + (r * 8 + ((2 * c8 + 1) ^ sw));
      float4* vd0 = reinterpret_cast<float4*>(Vs) + (r * 8 + ((2 * c8) ^ sw));
      float4* vd1 = reinterpret_cast<float4*>(Vs) + (r * 8 + ((2 * c8 + 1) ^ sw));
      *kd0 = make_float4(b2f(kraw.x & 0xffff), b2f(kraw.x >> 16), b2f(kraw.y & 0xffff), b2f(kraw.y >> 16));
      *kd1 = make_float4(b2f(kraw.z & 0xffff), b2f(kraw.z >> 16), b2f(kraw.w & 0xffff), b2f(kraw.w >> 16));
      *vd0 = make_float4(b2f(vraw.x & 0xffff), b2f(vraw.x >> 16), b2f(vraw.y & 0xffff), b2f(vraw.y >> 16));
      *vd1 = make_float4(b2f(vraw.z & 0xffff), b2f(vraw.z >> 16), b2f(vraw.w & 0xffff), b2f(vraw.w >> 16));
    }
    __syncthreads();
    for (int kk = 0; kk < 64; ++kk) {
      const int ksw = kk & 7;
      const float4* krow = reinterpret_cast<const float4*>(Ks) + kk * 8;
      float s = 0.0f;
      #pragma unroll
      for (int c = 0; c < 8; ++c) {
        float4 kv = krow[c ^ ksw];
        s += q[c*4+0]*kv.x + q[c*4+1]*kv.y + q[c*4+2]*kv.z + q[c*4+3]*kv.w;
      }
      s += semb[drow[kt * 64 + kk]];
      const float4* vrow = reinterpret_cast<const float4*>(Vs) + kk * 8;
      if (s <= m) {
        float p = __expf(s - m);
        l += p;
        #pragma unroll
        for (int c = 0; c < 8; ++c) {
          float4 vv = vrow[c ^ ksw];
          acc[c*4+0] += p * vv.x; acc[c*4+1] += p * vv.y;
          acc[c*4+2] += p * vv.z; acc[c*4+3] += p * vv.w;
        }
      } else {
        float corr = __expf(m - s);
        m = s;
        l = l * corr + 1.0f;
        #pragma unroll
        for (int c = 0; c < 8; ++c) {
          float4 vv = vrow[c ^ ksw];
          acc[c*4+0] = acc[c*4+0]*corr + vv.x; acc[c*4+1] = acc[c*4+1]*corr + vv.y;
          acc[c*4+2] = acc[c*4+2]*corr + vv.z; acc[c*4+3] = acc[c*4+3]*corr + vv.w;
        }
      }
    }
    __syncthreads();
  }
  int ridx = ((g * HEADS + head) << 10) + qrow;
  pm[sp * RIDX_N + ridx] = m;
  pl[sp * RIDX_N + ridx] = l;
  float* pa = pacc + ((size_t)(sp * RIDX_N) + ridx) * 32;
  #pragma unroll
  for (int c = 0; c < 8; ++c)
    reinterpret_cast<float4*>(pa)[c] = make_float4(acc[c*4+0], acc[c*4+1], acc[c*4+2], acc[c*4+3]);
}

// ---------------- combine partials -> bf16 attn output ----------------
__global__ __launch_bounds__(256) void k_comb(const float* __restrict__ pm,
                                              const float* __restrict__ pl,
                                              const float* __restrict__ pacc,
                                              short* __restrict__ attno) {
  int ridx = blockIdx.x * 256 + threadIdx.x;     // RIDX_N
  float mg = -3.0e38f;
  #pragma unroll
  for (int sp = 0; sp < NSP; ++sp) mg = fmaxf(mg, pm[sp * RIDX_N + ridx]);
  float lt = 0.f;
  float o[32] = {};
  #pragma unroll
  for (int sp = 0; sp < NSP; ++sp) {
    float wgt = __expf(pm[sp * RIDX_N + ridx] - mg);
    lt += wgt * pl[sp * RIDX_N + ridx];
    const float4* pa = reinterpret_cast<const float4*>(pacc + ((size_t)(sp * RIDX_N) + ridx) * 32);
    #pragma unroll
    for (int c = 0; c < 8; ++c) {
      float4 v = pa[c];
      o[c*4+0] += wgt * v.x; o[c*4+1] += wgt * v.y;
      o[c*4+2] += wgt * v.z; o[c*4+3] += wgt * v.w;
    }
  }
  float inv = 1.0f / lt;
  int qq = ridx & 1023, hh = (ridx >> 10) & 7, gg = ridx >> 13;
  unsigned int* op = reinterpret_cast<unsigned int*>(attno + ((size_t)(gg * M + qq)) * H + hh * 32);
  #pragma unroll
  for (int c = 0; c < 16; ++c) {
    unsigned int lo = (unsigned int)(ushort_t)f2b(o[2*c] * inv);
    unsigned int hi = (unsigned int)(ushort_t)f2b(o[2*c+1] * inv);
    op[c] = lo | (hi << 16);
  }
}

// ---------------- fused add(2|3) + LayerNorm (+optional bf16 copy) ----------------
__global__ __launch_bounds__(256) void k_ln(const float* __restrict__ a, const float* __restrict__ b,
                                            const float* __restrict__ c3,
                                            const float* __restrict__ gam, const float* __restrict__ bet,
                                            float* __restrict__ out, ushort_t* __restrict__ outb) {
  int row = blockIdx.x, t = threadIdx.x;
  size_t idx = (size_t)row * H + t;
  float v = a[idx] + b[idx];
  if (c3) v += c3[idx];
  float s = v, s2 = v * v;
  #pragma unroll
  for (int off = 32; off >= 1; off >>= 1) {
    s  += __shfl_down(s, off);
    s2 += __shfl_down(s2, off);
  }
  __shared__ float rs[4], rq[4], smean, srstd;
  int wv = t >> 6, ln = t & 63;
  if (ln == 0) { rs[wv] = s; rq[wv] = s2; }
  __syncthreads();
  if (t == 0) {
    float S = rs[0]+rs[1]+rs[2]+rs[3], Q = rq[0]+rq[1]+rq[2]+rq[3];
    float mean = S / (float)H;
    float var = Q / (float)H - mean * mean;
    smean = mean; srstd = rsqrtf(var + 1e-5f);
  }
  __syncthreads();
  float r = (v - smean) * srstd * gam[t] + bet[t];
  out[idx] = r;
  if (outb) outb[idx] = (ushort_t)f2b(r);
}

// ---------------- launch ----------------
extern "C" void kernel_launch(void* const* d_in, const int* in_sizes, int n_in,
                              void* d_out, int out_size, void* d_ws, size_t ws_size,
                              hipStream_t stream) {
  const float* x      = (const float*)d_in[0];
  const float* gcn_w  = (const float*)d_in[1];
  const float* gcn_b  = (const float*)d_in[2];
  const float* qkv_w  = (const float*)d_in[3];
  const float* qkv_b  = (const float*)d_in[4];
  const float* proj_w = (const float*)d_in[5];
  const float* proj_b = (const float*)d_in[6];
  const float* ln1_g  = (const float*)d_in[7];
  const float* ln1_b  = (const float*)d_in[8];
  const float* ln2_g  = (const float*)d_in[9];
  const float* ln2_b  = (const float*)d_in[10];
  const float* ffn1_w = (const float*)d_in[11];
  const float* ffn1_b = (const float*)d_in[12];
  const float* ffn2_w = (const float*)d_in[13];
  const float* ffn2_b = (const float*)d_in[14];
  const float* bias_e = (const float*)d_in[15];
  const float* oln1_g = (const float*)d_in[16];
  const float* oln1_b = (const float*)d_in[17];
  const float* oln2_g = (const float*)d_in[18];
  const float* oln2_b = (const float*)d_in[19];
  const float* offn1_w= (const float*)d_in[20];
  const float* offn1_b= (const float*)d_in[21];
  const float* offn2_w= (const float*)d_in[22];
  const float* offn2_b= (const float*)d_in[23];
  const int*   eidx   = (const int*)d_in[24];
  const int* esrc = eidx;
  const int* edst = eidx + NE;

  char* wsp = (char*)d_ws;
  size_t off = 0;
  auto alloc = [&](size_t bytes) { void* p = wsp + off; off += (bytes + 255) & ~255ull; return p; };
  const size_t SZ_NH = (size_t)NN * H * 4;
  ushort_t* x_bf  = (ushort_t*)alloc((size_t)NN * H * 2);         // 4MB
  ushort_t* w_bf  = (ushort_t*)alloc((size_t)WB_TOTAL * 2);       // 2.75MB
  float* xw   = (float*)alloc(SZ_NH);                             // 8MB
  float* xloc = (float*)alloc(SZ_NH);                             // 8MB
  float* dinv = (float*)alloc((size_t)NN * 4);
  int*   deg  = (int*)  alloc((size_t)NN * 4);                    // ┐ contiguous
  int* cursor = (int*)  alloc((size_t)NN * 4);                    // │ zeroed
  int*  deg2  = (int*)  alloc((size_t)NN * 4);                    // │ together
  int* cursor2= (int*)  alloc((size_t)NN * 4);                    // ┘
  int* starts = (int*)  alloc((size_t)NN * 4);
  int* starts2= (int*)  alloc((size_t)NN * 4);
  int*   csr  = (int*)  alloc((size_t)NE * 4);                    // 0.5MB
  int*   nbr  = (int*)  alloc((size_t)2 * NE * 4);                // 1MB
  u64*   Rbuf = (u64*)  alloc((size_t)6 * NN * 16 * 8);           // 6MB (levels 0..5)
  u8*    dist = (u8*)   alloc((size_t)NN * M);                    // 8MB
  ushort_t* qkvb = (ushort_t*)alloc((size_t)NN * 768 * 2);        // 12MB
  float* h1   = (float*)alloc(SZ_NH);                             // 8MB ┐
  ushort_t* h1_bf = (ushort_t*)alloc((size_t)NN * H * 2);         // 4MB │ attn partials
  float* f2   = (float*)alloc(SZ_NH);                             // 8MB │ alias (35.5MB,
  float* h2   = (float*)alloc(SZ_NH);                             // 8MB │ dead during attn)
  float* y    = (float*)alloc(SZ_NH);                             // 8MB ┘

  ushort_t* attno = x_bf;                  // x_bf dead after qkv gemm
  float* projo = xw;                       // xw dead after gather
  ushort_t* mid = (ushort_t*)dist;         // dist+qkvb (20MB) dead after attn
  ushort_t* y_bf = h1_bf;                  // h1_bf dead after ffn1
  float* outp = (float*)d_out;

  // attention partials over h1..y region (written only after k_comb)
  float* pm   = h1;                                 // NSP*RIDX_N = 1MB
  float* pl   = h1 + (size_t)NSP * RIDX_N;          // 1MB
  float* pacc = h1 + (size_t)2 * NSP * RIDX_N;      // 33.5MB

  ushort_t* gcn_wb  = w_bf + WB_GCN;
  ushort_t* qkv_wb  = w_bf + WB_QKV;
  ushort_t* proj_wb = w_bf + WB_PROJ;
  ushort_t* ffn1_wb = w_bf + WB_FFN1;
  ushort_t* ffn2_wb = w_bf + WB_FFN2;
  ushort_t* offn1_wb= w_bf + WB_OFFN1;
  ushort_t* offn2_wb= w_bf + WB_OFFN2;

  hipMemsetAsync(deg, 0, (size_t)4 * NN * 4, stream);   // deg,cursor,deg2,cursor2

  // conversions
  k_cvt<<<(NN * H / 4 + 255) / 256, 256, 0, stream>>>(x, x_bf, NN * H / 4);
  k_cvtw<<<(WB_TOTAL + 255) / 256, 256, 0, stream>>>(gcn_w, qkv_w, proj_w, ffn1_w,
                                                     ffn2_w, offn1_w, offn2_w, w_bf);

  // --- degrees & CSRs ---
  k_deg<<<(NE + 255) / 256, 256, 0, stream>>>(edst, deg);
  k_deg2<<<(NE + 255) / 256, 256, 0, stream>>>(esrc, edst, deg2);
  k_dinv<<<NN / 256, 256, 0, stream>>>(deg, dinv);
  k_scan<<<1, 1024, 0, stream>>>(deg, starts);
  k_scan<<<1, 1024, 0, stream>>>(deg2, starts2);
  k_fill<<<(NE + 255) / 256, 256, 0, stream>>>(esrc, edst, starts, cursor, csr);
  k_fill2<<<(NE + 255) / 256, 256, 0, stream>>>(esrc, edst, starts2, cursor2, nbr);

  // --- GCN local path ---
  k_mgemm<0,0><<<dim3(H / 64, NN / 128), 256, 0, stream>>>(
      (const short*)x_bf, (const short*)gcn_wb, nullptr, xw, nullptr, H, H);
  k_gather<<<NN, 256, 0, stream>>>(csr, starts, deg, dinv, xw, gcn_b, xloc);

  // --- SPD distances (level-synchronous bitset propagation) ---
  k_rinit<<<NN * 16 / 256, 256, 0, stream>>>(Rbuf);
  for (int l = 1; l <= 5; ++l)
    k_spd<<<NN * 16 / 256, 256, 0, stream>>>(Rbuf + (size_t)(l - 1) * NN * 16,
                                             Rbuf + (size_t)l * NN * 16,
                                             starts2, deg2, nbr);
  k_dist<<<NN * 256 / 256, 256, 0, stream>>>(Rbuf, dist);

  // --- Graphormer encoder ---
  k_mgemm<0,1><<<dim3(768 / 64, NN / 128), 256, 0, stream>>>(
      (const short*)x_bf, (const short*)qkv_wb, qkv_b, nullptr, (short*)qkvb, H, 768);
  k_attn<<<dim3(4 * NSP, HEADS, G), 256, 0, stream>>>(qkvb, dist, bias_e, pm, pl, pacc);
  k_comb<<<RIDX_N / 256, 256, 0, stream>>>(pm, pl, pacc, (short*)attno);
  k_mgemm<0,0><<<dim3(H / 64, NN / 128), 256, 0, stream>>>(
      (const short*)attno, (const short*)proj_wb, proj_b, projo, nullptr, H, H);
  k_ln<<<NN, 256, 0, stream>>>(x, projo, nullptr, ln1_g, ln1_b, h1, h1_bf);
  k_mgemm<1,1><<<dim3(FFND / 64, NN / 128), 256, 0, stream>>>(
      (const short*)h1_bf, (const short*)ffn1_wb, ffn1_b, nullptr, (short*)mid, H, FFND);
  k_mgemm<0,0><<<dim3(H / 64, NN / 128), 256, 0, stream>>>(
      (const short*)mid, (const short*)ffn2_wb, ffn2_b, f2, nullptr, FFND, H);
  k_ln<<<NN, 256, 0, stream>>>(h1, f2, nullptr, ln2_g, ln2_b, h2, nullptr);

  // --- GPS combine + outer FFN ---
  k_ln<<<NN, 256, 0, stream>>>(x, xloc, h2, oln1_g, oln1_b, y, y_bf);
  k_mgemm<1,1><<<dim3(FFND / 64, NN / 128), 256, 0, stream>>>(
      (const short*)y_bf, (const short*)offn1_wb, offn1_b, nullptr, (short*)mid, H, FFND);
  k_mgemm<0,0><<<dim3(H / 64, NN / 128), 256, 0, stream>>>(
      (const short*)mid, (const short*)offn2_wb, offn2_b, f2, nullptr, FFND, H);
  k_ln<<<NN, 256, 0, stream>>>(y, f2, nullptr, oln2_g, oln2_b, outp, nullptr);
}

// Round 4
// 512.383 us; speedup vs baseline: 3.4125x; 1.4097x over previous
//
#include <hip/hip_runtime.h>
#include <hip/hip_bf16.h>
#include <cstdint>

#define G 8
#define M 1024
#define H 256
#define HEADS 8
#define FFND 1024
#define NE 131072
#define NN (G*M)          // 8192
#define HD 32             // H/HEADS

typedef unsigned long long u64;
typedef uint8_t u8;
typedef unsigned short ushort_t;
typedef __attribute__((ext_vector_type(8))) short bf16x8;
typedef __attribute__((ext_vector_type(4))) float f32x4;

__device__ __forceinline__ short f2b(float v) {
  __hip_bfloat16 h = __float2bfloat16(v);
  return *reinterpret_cast<short*>(&h);
}
__device__ __forceinline__ float b2f(unsigned int u) {
  union { float f; unsigned int i; } v; v.i = u << 16; return v.f;
}

typedef __attribute__((address_space(1))) const void gvoid;
typedef __attribute__((address_space(3))) void lvoid;
__device__ __forceinline__ void gload16(const void* g, void* l) {
  __builtin_amdgcn_global_load_lds((gvoid*)g, (lvoid*)l, 16, 0, 0);
}

// ---------------- degree kernels ----------------
__global__ void k_deg(const int* __restrict__ dst, int* __restrict__ deg) {
  int e = blockIdx.x * 256 + threadIdx.x;
  if (e < NE) atomicAdd(&deg[dst[e]], 1);
}

__global__ void k_deg2(const int* __restrict__ srcv, const int* __restrict__ dstv,
                       int* __restrict__ deg2) {
  int e = blockIdx.x * 256 + threadIdx.x;
  if (e >= NE) return;
  int a = srcv[e], b = dstv[e];
  if (a != b) { atomicAdd(&deg2[a], 1); atomicAdd(&deg2[b], 1); }
}

__global__ void k_dinv(const int* __restrict__ deg, float* __restrict__ dinv) {
  int i = blockIdx.x * 256 + threadIdx.x;
  if (i < NN) dinv[i] = rsqrtf((float)(deg[i] + 1));   // +1 self loop
}

// ---------------- exclusive prefix sum (NN=8192, one block) ----------------
__global__ __launch_bounds__(1024) void k_scan(const int* __restrict__ deg, int* __restrict__ starts) {
  __shared__ int tmp[1024];
  int t = threadIdx.x;
  int base = t * 8;
  int v[8]; int s = 0;
  #pragma unroll
  for (int i = 0; i < 8; ++i) { v[i] = deg[base + i]; s += v[i]; }
  tmp[t] = s;
  __syncthreads();
  for (int off = 1; off < 1024; off <<= 1) {
    int x = (t >= off) ? tmp[t - off] : 0;
    __syncthreads();
    tmp[t] += x;
    __syncthreads();
  }
  int ex = (t == 0) ? 0 : tmp[t - 1];
  #pragma unroll
  for (int i = 0; i < 8; ++i) { starts[base + i] = ex; ex += v[i]; }
}

// ---------------- CSR fills ----------------
__global__ void k_fill(const int* __restrict__ srcv, const int* __restrict__ dstv,
                       const int* __restrict__ starts, int* __restrict__ cursor,
                       int* __restrict__ csr) {
  int e = blockIdx.x * 256 + threadIdx.x;
  if (e >= NE) return;
  int d = dstv[e];
  int pos = atomicAdd(&cursor[d], 1);
  csr[starts[d] + pos] = srcv[e];
}

__global__ void k_fill2(const int* __restrict__ srcv, const int* __restrict__ dstv,
                        const int* __restrict__ starts2, int* __restrict__ cur2,
                        int* __restrict__ nbr) {
  int e = blockIdx.x * 256 + threadIdx.x;
  if (e >= NE) return;
  int a = srcv[e], b = dstv[e];
  if (a == b) return;
  int p = atomicAdd(&cur2[a], 1); nbr[starts2[a] + p] = b;
  p = atomicAdd(&cur2[b], 1);     nbr[starts2[b] + p] = a;
}

// ---------------- CSR gather (GCN, fuses xlocal epilogue) ----------------
__global__ __launch_bounds__(256) void k_gather(const int* __restrict__ csr,
    const int* __restrict__ starts, const int* __restrict__ deg,
    const float* __restrict__ dinv, const float* __restrict__ xw,
    const float* __restrict__ gcn_b, float* __restrict__ xloc) {
  int d = blockIdx.x, t = threadIdx.x;
  int s0 = starts[d], cnt = deg[d];
  float acc = 0.f;
  for (int j = 0; j < cnt; ++j) {
    int s = csr[s0 + j];
    acc += dinv[s] * xw[(size_t)s * H + t];
  }
  float di = dinv[d];
  float self = xw[(size_t)d * H + t];
  xloc[(size_t)d * H + t] = di * acc + di * di * self + gcn_b[t];
}

// ---------------- SPD: level-synchronous bitset propagation ----------------
__global__ void k_rinit(u64* __restrict__ R0) {
  int idx = blockIdx.x * 256 + threadIdx.x;       // NN*16
  int i = idx >> 4, w = idx & 15;
  int il = i & 1023;
  R0[idx] = (w == (il >> 6)) ? (1ull << (il & 63)) : 0ull;
}

__global__ void k_spd(const u64* __restrict__ prev, u64* __restrict__ cur,
                      const int* __restrict__ starts2, const int* __restrict__ deg2,
                      const int* __restrict__ nbr) {
  int idx = blockIdx.x * 256 + threadIdx.x;       // NN*16
  int i = idx >> 4, w = idx & 15;
  u64 acc = prev[idx];
  int s0 = starts2[i], cnt = deg2[i];
  for (int e = 0; e < cnt; ++e)
    acc |= prev[(size_t)nbr[s0 + e] * 16 + w];
  cur[idx] = acc;
}

// decode: dist byte = first level whose bitset contains the bit (monotone R1..R5)
__global__ void k_dist(const u64* __restrict__ R, u8* __restrict__ dist) {
  int idx = blockIdx.x * 256 + threadIdx.x;       // NN*256 (u32 granules)
  int i = idx >> 8, c = idx & 255;
  int w = c >> 4;
  const u64* p = R + (size_t)NN * 16 + (size_t)i * 16 + w;   // level 1
  u64 r1 = p[0];
  u64 r2 = p[(size_t)NN * 16];
  u64 r3 = p[(size_t)NN * 32];
  u64 r4 = p[(size_t)NN * 48];
  u64 r5 = p[(size_t)NN * 64];
  int il = i & 1023;
  unsigned int out = 0;
  #pragma unroll
  for (int j = 0; j < 4; ++j) {
    int kbit = (c & 15) * 4 + j;
    u64 msk = 1ull << kbit;
    int dd = 6 - (int)((r1 & msk) != 0) - (int)((r2 & msk) != 0) - (int)((r3 & msk) != 0)
               - (int)((r4 & msk) != 0) - (int)((r5 & msk) != 0);
    if (il == c * 4 + j) dd = 0;
    out |= (unsigned int)dd << (8 * j);
  }
  reinterpret_cast<unsigned int*>(dist)[idx] = out;
}

// ---------------- fp32 -> bf16 converts ----------------
__global__ void k_cvt(const float* __restrict__ in, ushort_t* __restrict__ out, int n4) {
  int i = blockIdx.x * 256 + threadIdx.x;
  if (i >= n4) return;
  float4 v = reinterpret_cast<const float4*>(in)[i];
  unsigned int lo = (unsigned int)(ushort_t)f2b(v.x) | ((unsigned int)(ushort_t)f2b(v.y) << 16);
  unsigned int hi = (unsigned int)(ushort_t)f2b(v.z) | ((unsigned int)(ushort_t)f2b(v.w) << 16);
  reinterpret_cast<uint2*>(out)[i] = make_uint2(lo, hi);
}

#define WB_GCN   0
#define WB_QKV   65536
#define WB_PROJ  262144
#define WB_FFN1  327680
#define WB_FFN2  589824
#define WB_OFFN1 851968
#define WB_OFFN2 1114112
#define WB_TOTAL 1376256

__global__ void k_cvtw(const float* p0, const float* p1, const float* p2,
                       const float* p3, const float* p4, const float* p5,
                       const float* p6, ushort_t* __restrict__ out) {
  int i = blockIdx.x * 256 + threadIdx.x;
  if (i >= WB_TOTAL) return;
  const float* src; int off;
  if (i < WB_QKV)        { src = p0; off = i; }
  else if (i < WB_PROJ)  { src = p1; off = i - WB_QKV; }
  else if (i < WB_FFN1)  { src = p2; off = i - WB_PROJ; }
  else if (i < WB_FFN2)  { src = p3; off = i - WB_FFN1; }
  else if (i < WB_OFFN1) { src = p4; off = i - WB_FFN2; }
  else if (i < WB_OFFN2) { src = p5; off = i - WB_OFFN1; }
  else                   { src = p6; off = i - WB_OFFN2; }
  out[i] = (ushort_t)f2b(src[off]);
}

// ---------------- bf16 MFMA GEMM: C[NI,O] = A[NI,K] @ W[O,K]^T + bias ----------------
template<int ACT, int OBF>
__global__ __launch_bounds__(256) void k_mgemm(const short* __restrict__ A,
                                               const short* __restrict__ W,
                                               const float* __restrict__ bias,
                                               float* __restrict__ Cf,
                                               short* __restrict__ Cb,
                                               int K, int O) {
  __shared__ __attribute__((aligned(16))) short As[128 * 64];
  __shared__ __attribute__((aligned(16))) short Ws[64 * 64];
  const int tid = threadIdx.x;
  const int lane = tid & 63, wbase = tid & 192;
  const int wid = tid >> 6;
  const int wm = wid >> 1, wn = wid & 1;
  const int m0 = blockIdx.y * 128, n0 = blockIdx.x * 64;
  f32x4 acc[4][2];
  #pragma unroll
  for (int i = 0; i < 4; ++i)
    #pragma unroll
    for (int j = 0; j < 2; ++j)
      acc[i][j] = (f32x4){0.f, 0.f, 0.f, 0.f};

  for (int k0 = 0; k0 < K; k0 += 64) {
    #pragma unroll
    for (int c = 0; c < 4; ++c) {
      int chunk = c * 256 + tid;
      int row = chunk >> 3, ks = chunk & 7;
      int srcks = ks ^ (row & 7);
      gload16(A + (size_t)(m0 + row) * K + k0 + srcks * 8,
              (char*)As + (c * 256 + wbase) * 16);
    }
    #pragma unroll
    for (int c = 0; c < 2; ++c) {
      int chunk = c * 256 + tid;
      int row = chunk >> 3, ks = chunk & 7;
      int srcks = ks ^ (row & 7);
      gload16(W + (size_t)(n0 + row) * K + k0 + srcks * 8,
              (char*)Ws + (c * 256 + wbase) * 16);
    }
    __syncthreads();
    #pragma unroll
    for (int kk = 0; kk < 2; ++kk) {
      const int d = kk * 4 + (lane >> 4);
      bf16x8 b[2];
      #pragma unroll
      for (int fn = 0; fn < 2; ++fn) {
        int r = wn * 32 + fn * 16 + (lane & 15);
        b[fn] = *reinterpret_cast<const bf16x8*>((const char*)Ws + r * 128 + ((d ^ (r & 7)) * 16));
      }
      #pragma unroll
      for (int fm = 0; fm < 4; ++fm) {
        int r = wm * 64 + fm * 16 + (lane & 15);
        bf16x8 a = *reinterpret_cast<const bf16x8*>((const char*)As + r * 128 + ((d ^ (r & 7)) * 16));
        acc[fm][0] = __builtin_amdgcn_mfma_f32_16x16x32_bf16(a, b[0], acc[fm][0], 0, 0, 0);
        acc[fm][1] = __builtin_amdgcn_mfma_f32_16x16x32_bf16(a, b[1], acc[fm][1], 0, 0, 0);
      }
    }
    __syncthreads();
  }
  #pragma unroll
  for (int fm = 0; fm < 4; ++fm)
    #pragma unroll
    for (int fn = 0; fn < 2; ++fn)
      #pragma unroll
      for (int rg = 0; rg < 4; ++rg) {
        int r = m0 + wm * 64 + fm * 16 + (lane >> 4) * 4 + rg;
        int cc = n0 + wn * 32 + fn * 16 + (lane & 15);
        float v = acc[fm][fn][rg] + (bias ? bias[cc] : 0.f);
        if (ACT == 1) v = 0.5f * v * (1.0f + erff(v * 0.70710678118654752f));
        if (OBF) Cb[(size_t)r * O + cc] = f2b(v);
        else     Cf[(size_t)r * O + cc] = v;
      }
}

// ---------------- MFMA flash attention with SPD bias ----------------
// Per block: (g, head, 64 q-rows). 4 waves, wave w owns q rows w*16..w*16+15.
// Loop over 16 key tiles of 64. HD=32 = one mfma_f32_16x16x32_bf16 K-depth.
__global__ __launch_bounds__(256) void k_attn(const ushort_t* __restrict__ qkv,
                                              const u8* __restrict__ dist,
                                              const float* __restrict__ emb,
                                              short* __restrict__ attno) {
  __shared__ __attribute__((aligned(16))) char KsB[64 * 80];    // K rows: [key][32 bf16], stride 80B
  __shared__ __attribute__((aligned(16))) char VtB[32 * 144];   // V^T: [d][64 keys bf16], stride 144B, chunk^=(d&7)
  __shared__ __attribute__((aligned(16))) char PB[4 * 16 * 144];// per-wave P: [q][64 keys bf16], stride 144B, chunk^=(q&7)
  __shared__ __attribute__((aligned(16))) u8 Ds[64 * 80];       // dist tile [q][key], stride 80
  __shared__ float semb[8];
  const int g = blockIdx.z, head = blockIdx.y;
  const int q0 = blockIdx.x * 64;
  const int t = threadIdx.x, lane = t & 63, wid = t >> 6;
  const int lg = lane >> 4, lr = lane & 15;
  if (t < 7) semb[t] = emb[t];
  const size_t nodebase = (size_t)(g * M) * 768;
  const float SC = 0.17677669529663687f;   // HD^-0.5

  // Q fragment (A layout): lane holds Q[q = wid*16 + lr][k = lg*8 .. +7]
  bf16x8 qfrag = *reinterpret_cast<const bf16x8*>(
      qkv + nodebase + (size_t)(q0 + wid * 16 + lr) * 768 + head * 32 + lg * 8);

  f32x4 o0 = {0.f, 0.f, 0.f, 0.f}, o1 = {0.f, 0.f, 0.f, 0.f};
  float mrun[4] = {-3e38f, -3e38f, -3e38f, -3e38f};
  float lrun[4] = {0.f, 0.f, 0.f, 0.f};
  char* pb = PB + wid * (16 * 144);

  for (int kt = 0; kt < 16; ++kt) {
    // ---- stage K (B layout direct), V (transposed), dist tile ----
    {
      int srow = t >> 2, sc = t & 3;
      const size_t kn = nodebase + (size_t)(kt * 64 + srow) * 768 + head * 32;
      uint4 kv = *reinterpret_cast<const uint4*>(qkv + kn + 256 + sc * 8);
      *reinterpret_cast<uint4*>(KsB + srow * 80 + sc * 16) = kv;
      uint4 vv = *reinterpret_cast<const uint4*>(qkv + kn + 512 + sc * 8);
      unsigned int vw[4] = {vv.x, vv.y, vv.z, vv.w};
      #pragma unroll
      for (int p = 0; p < 4; ++p) {
        #pragma unroll
        for (int hl = 0; hl < 2; ++hl) {
          int d = sc * 8 + p * 2 + hl;
          ushort_t val = (ushort_t)(hl ? (vw[p] >> 16) : (vw[p] & 0xffff));
          *reinterpret_cast<ushort_t*>(VtB + d * 144 + (((srow >> 3) ^ (d & 7)) * 16) + (srow & 7) * 2) = val;
        }
      }
      uint4 dv = *reinterpret_cast<const uint4*>(dist + (size_t)(g * M + q0 + srow) * M + kt * 64 + sc * 16);
      *reinterpret_cast<uint4*>(Ds + srow * 80 + sc * 16) = dv;
    }
    __syncthreads();

    // ---- scores: 4 MFMAs (fn = 16-key subtiles) ----
    f32x4 s[4];
    #pragma unroll
    for (int fn = 0; fn < 4; ++fn) {
      bf16x8 b = *reinterpret_cast<const bf16x8*>(KsB + (fn * 16 + lr) * 80 + lg * 16);
      s[fn] = __builtin_amdgcn_mfma_f32_16x16x32_bf16(qfrag, b, (f32x4){0.f,0.f,0.f,0.f}, 0, 0, 0);
    }
    // bias + scale (D layout: row q = wid*16 + 4*lg + rg, col key = fn*16 + lr)
    const int qD = wid * 16 + 4 * lg;
    #pragma unroll
    for (int fn = 0; fn < 4; ++fn)
      #pragma unroll
      for (int rg = 0; rg < 4; ++rg)
        s[fn][rg] = s[fn][rg] * SC + semb[Ds[(qD + rg) * 80 + fn * 16 + lr]];

    // ---- online softmax (row spread over 16 lanes of same lg group) ----
    #pragma unroll
    for (int rg = 0; rg < 4; ++rg) {
      float v = fmaxf(fmaxf(s[0][rg], s[1][rg]), fmaxf(s[2][rg], s[3][rg]));
      v = fmaxf(v, __shfl_xor(v, 1));
      v = fmaxf(v, __shfl_xor(v, 2));
      v = fmaxf(v, __shfl_xor(v, 4));
      v = fmaxf(v, __shfl_xor(v, 8));
      float mnew = fmaxf(mrun[rg], v);
      float corr = __expf(mrun[rg] - mnew);
      mrun[rg] = mnew;
      #pragma unroll
      for (int fn = 0; fn < 4; ++fn) s[fn][rg] = __expf(s[fn][rg] - mnew);
      float rs = s[0][rg] + s[1][rg] + s[2][rg] + s[3][rg];
      rs += __shfl_xor(rs, 1);
      rs += __shfl_xor(rs, 2);
      rs += __shfl_xor(rs, 4);
      rs += __shfl_xor(rs, 8);
      lrun[rg] = lrun[rg] * corr + rs;
      o0[rg] *= corr;
      o1[rg] *= corr;
    }

    // ---- P -> per-wave LDS (bf16, A-frag friendly layout) ----
    #pragma unroll
    for (int fn = 0; fn < 4; ++fn)
      #pragma unroll
      for (int rg = 0; rg < 4; ++rg) {
        int qq = 4 * lg + rg, key = fn * 16 + lr;
        *reinterpret_cast<ushort_t*>(pb + qq * 144 + (((key >> 3) ^ (qq & 7)) * 16) + (key & 7) * 2) =
            (ushort_t)f2b(s[fn][rg]);
      }

    // ---- PV: 4 MFMAs (2 key-halves x 2 d-halves) ----
    #pragma unroll
    for (int kh = 0; kh < 2; ++kh) {
      int ch = ((kh * 4 + lg) ^ (lr & 7)) * 16;
      bf16x8 a  = *reinterpret_cast<const bf16x8*>(pb + lr * 144 + ch);
      bf16x8 b0 = *reinterpret_cast<const bf16x8*>(VtB + lr * 144 + ch);
      bf16x8 b1 = *reinterpret_cast<const bf16x8*>(VtB + (16 + lr) * 144 + ch);
      o0 = __builtin_amdgcn_mfma_f32_16x16x32_bf16(a, b0, o0, 0, 0, 0);
      o1 = __builtin_amdgcn_mfma_f32_16x16x32_bf16(a, b1, o1, 0, 0, 0);
    }
    __syncthreads();
  }

  // ---- output: O[q][d] bf16, q = q0+wid*16+4*lg+rg, d = lr / 16+lr ----
  #pragma unroll
  for (int rg = 0; rg < 4; ++rg) {
    float inv = 1.0f / lrun[rg];
    size_t qn = (size_t)(g * M + q0 + wid * 16 + 4 * lg + rg);
    attno[qn * H + head * 32 + lr]      = f2b(o0[rg] * inv);
    attno[qn * H + head * 32 + 16 + lr] = f2b(o1[rg] * inv);
  }
}

// ---------------- fused add(2|3) + LayerNorm (+optional bf16 copy) ----------------
__global__ __launch_bounds__(256) void k_ln(const float* __restrict__ a, const float* __restrict__ b,
                                            const float* __restrict__ c3,
                                            const float* __restrict__ gam, const float* __restrict__ bet,
                                            float* __restrict__ out, ushort_t* __restrict__ outb) {
  int row = blockIdx.x, t = threadIdx.x;
  size_t idx = (size_t)row * H + t;
  float v = a[idx] + b[idx];
  if (c3) v += c3[idx];
  float s = v, s2 = v * v;
  #pragma unroll
  for (int off = 32; off >= 1; off >>= 1) {
    s  += __shfl_down(s, off);
    s2 += __shfl_down(s2, off);
  }
  __shared__ float rs[4], rq[4], smean, srstd;
  int wv = t >> 6, ln = t & 63;
  if (ln == 0) { rs[wv] = s; rq[wv] = s2; }
  __syncthreads();
  if (t == 0) {
    float S = rs[0]+rs[1]+rs[2]+rs[3], Q = rq[0]+rq[1]+rq[2]+rq[3];
    float mean = S / (float)H;
    float var = Q / (float)H - mean * mean;
    smean = mean; srstd = rsqrtf(var + 1e-5f);
  }
  __syncthreads();
  float r = (v - smean) * srstd * gam[t] + bet[t];
  out[idx] = r;
  if (outb) outb[idx] = (ushort_t)f2b(r);
}

// ---------------- launch ----------------
extern "C" void kernel_launch(void* const* d_in, const int* in_sizes, int n_in,
                              void* d_out, int out_size, void* d_ws, size_t ws_size,
                              hipStream_t stream) {
  const float* x      = (const float*)d_in[0];
  const float* gcn_w  = (const float*)d_in[1];
  const float* gcn_b  = (const float*)d_in[2];
  const float* qkv_w  = (const float*)d_in[3];
  const float* qkv_b  = (const float*)d_in[4];
  const float* proj_w = (const float*)d_in[5];
  const float* proj_b = (const float*)d_in[6];
  const float* ln1_g  = (const float*)d_in[7];
  const float* ln1_b  = (const float*)d_in[8];
  const float* ln2_g  = (const float*)d_in[9];
  const float* ln2_b  = (const float*)d_in[10];
  const float* ffn1_w = (const float*)d_in[11];
  const float* ffn1_b = (const float*)d_in[12];
  const float* ffn2_w = (const float*)d_in[13];
  const float* ffn2_b = (const float*)d_in[14];
  const float* bias_e = (const float*)d_in[15];
  const float* oln1_g = (const float*)d_in[16];
  const float* oln1_b = (const float*)d_in[17];
  const float* oln2_g = (const float*)d_in[18];
  const float* oln2_b = (const float*)d_in[19];
  const float* offn1_w= (const float*)d_in[20];
  const float* offn1_b= (const float*)d_in[21];
  const float* offn2_w= (const float*)d_in[22];
  const float* offn2_b= (const float*)d_in[23];
  const int*   eidx   = (const int*)d_in[24];
  const int* esrc = eidx;
  const int* edst = eidx + NE;

  char* wsp = (char*)d_ws;
  size_t off = 0;
  auto alloc = [&](size_t bytes) { void* p = wsp + off; off += (bytes + 255) & ~255ull; return p; };
  const size_t SZ_NH = (size_t)NN * H * 4;
  ushort_t* x_bf  = (ushort_t*)alloc((size_t)NN * H * 2);         // 4MB
  ushort_t* w_bf  = (ushort_t*)alloc((size_t)WB_TOTAL * 2);       // 2.75MB
  float* xw   = (float*)alloc(SZ_NH);                             // 8MB
  float* xloc = (float*)alloc(SZ_NH);                             // 8MB
  float* dinv = (float*)alloc((size_t)NN * 4);
  int*   deg  = (int*)  alloc((size_t)NN * 4);                    // ┐ contiguous
  int* cursor = (int*)  alloc((size_t)NN * 4);                    // │ zeroed
  int*  deg2  = (int*)  alloc((size_t)NN * 4);                    // │ together
  int* cursor2= (int*)  alloc((size_t)NN * 4);                    // ┘
  int* starts = (int*)  alloc((size_t)NN * 4);
  int* starts2= (int*)  alloc((size_t)NN * 4);
  int*   csr  = (int*)  alloc((size_t)NE * 4);                    // 0.5MB
  int*   nbr  = (int*)  alloc((size_t)2 * NE * 4);                // 1MB
  u64*   Rbuf = (u64*)  alloc((size_t)6 * NN * 16 * 8);           // 6MB (levels 0..5)
  u8*    dist = (u8*)   alloc((size_t)NN * M);                    // 8MB
  ushort_t* qkvb = (ushort_t*)alloc((size_t)NN * 768 * 2);        // 12MB
  float* h1   = (float*)alloc(SZ_NH);                             // 8MB
  ushort_t* h1_bf = (ushort_t*)alloc((size_t)NN * H * 2);         // 4MB
  float* f2   = (float*)alloc(SZ_NH);                             // 8MB
  float* h2   = (float*)alloc(SZ_NH);                             // 8MB
  float* y    = (float*)alloc(SZ_NH);                             // 8MB

  ushort_t* attno = x_bf;                  // x_bf dead after qkv gemm
  float* projo = xw;                       // xw dead after gather
  ushort_t* mid = (ushort_t*)dist;         // dist+qkvb (20MB) dead after attn
  ushort_t* y_bf = h1_bf;                  // h1_bf dead after ffn1
  float* outp = (float*)d_out;

  ushort_t* gcn_wb  = w_bf + WB_GCN;
  ushort_t* qkv_wb  = w_bf + WB_QKV;
  ushort_t* proj_wb = w_bf + WB_PROJ;
  ushort_t* ffn1_wb = w_bf + WB_FFN1;
  ushort_t* ffn2_wb = w_bf + WB_FFN2;
  ushort_t* offn1_wb= w_bf + WB_OFFN1;
  ushort_t* offn2_wb= w_bf + WB_OFFN2;

  hipMemsetAsync(deg, 0, (size_t)4 * NN * 4, stream);   // deg,cursor,deg2,cursor2

  // conversions
  k_cvt<<<(NN * H / 4 + 255) / 256, 256, 0, stream>>>(x, x_bf, NN * H / 4);
  k_cvtw<<<(WB_TOTAL + 255) / 256, 256, 0, stream>>>(gcn_w, qkv_w, proj_w, ffn1_w,
                                                     ffn2_w, offn1_w, offn2_w, w_bf);

  // --- degrees & CSRs ---
  k_deg<<<(NE + 255) / 256, 256, 0, stream>>>(edst, deg);
  k_deg2<<<(NE + 255) / 256, 256, 0, stream>>>(esrc, edst, deg2);
  k_dinv<<<NN / 256, 256, 0, stream>>>(deg, dinv);
  k_scan<<<1, 1024, 0, stream>>>(deg, starts);
  k_scan<<<1, 1024, 0, stream>>>(deg2, starts2);
  k_fill<<<(NE + 255) / 256, 256, 0, stream>>>(esrc, edst, starts, cursor, csr);
  k_fill2<<<(NE + 255) / 256, 256, 0, stream>>>(esrc, edst, starts2, cursor2, nbr);

  // --- GCN local path ---
  k_mgemm<0,0><<<dim3(H / 64, NN / 128), 256, 0, stream>>>(
      (const short*)x_bf, (const short*)gcn_wb, nullptr, xw, nullptr, H, H);
  k_gather<<<NN, 256, 0, stream>>>(csr, starts, deg, dinv, xw, gcn_b, xloc);

  // --- SPD distances (level-synchronous bitset propagation) ---
  k_rinit<<<NN * 16 / 256, 256, 0, stream>>>(Rbuf);
  for (int l = 1; l <= 5; ++l)
    k_spd<<<NN * 16 / 256, 256, 0, stream>>>(Rbuf + (size_t)(l - 1) * NN * 16,
                                             Rbuf + (size_t)l * NN * 16,
                                             starts2, deg2, nbr);
  k_dist<<<NN * 256 / 256, 256, 0, stream>>>(Rbuf, dist);

  // --- Graphormer encoder ---
  k_mgemm<0,1><<<dim3(768 / 64, NN / 128), 256, 0, stream>>>(
      (const short*)x_bf, (const short*)qkv_wb, qkv_b, nullptr, (short*)qkvb, H, 768);
  k_attn<<<dim3(M / 64, HEADS, G), 256, 0, stream>>>(qkvb, dist, bias_e, (short*)attno);
  k_mgemm<0,0><<<dim3(H / 64, NN / 128), 256, 0, stream>>>(
      (const short*)attno, (const short*)proj_wb, proj_b, projo, nullptr, H, H);
  k_ln<<<NN, 256, 0, stream>>>(x, projo, nullptr, ln1_g, ln1_b, h1, h1_bf);
  k_mgemm<1,1><<<dim3(FFND / 64, NN / 128), 256, 0, stream>>>(
      (const short*)h1_bf, (const short*)ffn1_wb, ffn1_b, nullptr, (short*)mid, H, FFND);
  k_mgemm<0,0><<<dim3(H / 64, NN / 128), 256, 0, stream>>>(
      (const short*)mid, (const short*)ffn2_wb, ffn2_b, f2, nullptr, FFND, H);
  k_ln<<<NN, 256, 0, stream>>>(h1, f2, nullptr, ln2_g, ln2_b, h2, nullptr);

  // --- GPS combine + outer FFN ---
  k_ln<<<NN, 256, 0, stream>>>(x, xloc, h2, oln1_g, oln1_b, y, y_bf);
  k_mgemm<1,1><<<dim3(FFND / 64, NN / 128), 256, 0, stream>>>(
      (const short*)y_bf, (const short*)offn1_wb, offn1_b, nullptr, (short*)mid, H, FFND);
  k_mgemm<0,0><<<dim3(H / 64, NN / 128), 256, 0, stream>>>(
      (const short*)mid, (const short*)offn2_wb, offn2_b, f2, nullptr, FFND, H);
  k_ln<<<NN, 256, 0, stream>>>(y, f2, nullptr, oln2_g, oln2_b, outp, nullptr);
}

// Round 5
// 445.415 us; speedup vs baseline: 3.9255x; 1.1503x over previous
//
#include <hip/hip_runtime.h>
#include <hip/hip_bf16.h>
#include <cstdint>

#define G 8
#define M 1024
#define H 256
#define HEADS 8
#define FFND 1024
#define NE 131072
#define NN (G*M)          // 8192
#define HD 32             // H/HEADS

typedef unsigned long long u64;
typedef uint8_t u8;
typedef unsigned short ushort_t;
typedef __attribute__((ext_vector_type(8))) short bf16x8;
typedef __attribute__((ext_vector_type(4))) float f32x4;

__device__ __forceinline__ short f2b(float v) {
  __hip_bfloat16 h = __float2bfloat16(v);
  return *reinterpret_cast<short*>(&h);
}
__device__ __forceinline__ float b2f(unsigned int u) {
  union { float f; unsigned int i; } v; v.i = u << 16; return v.f;
}

typedef __attribute__((address_space(1))) const void gvoid;
typedef __attribute__((address_space(3))) void lvoid;
__device__ __forceinline__ void gload16(const void* g, void* l) {
  __builtin_amdgcn_global_load_lds((gvoid*)g, (lvoid*)l, 16, 0, 0);
}

// ---------------- fused degree pass ----------------
__global__ void k_prep(const int* __restrict__ srcv, const int* __restrict__ dstv,
                       int* __restrict__ deg, int* __restrict__ deg2) {
  int e = blockIdx.x * 256 + threadIdx.x;
  if (e >= NE) return;
  int d = dstv[e], s = srcv[e];
  atomicAdd(&deg[d], 1);
  if (s != d) { atomicAdd(&deg2[s], 1); atomicAdd(&deg2[d], 1); }
}

// ---------------- dual prefix scan (block 0: deg->starts+dinv, block 1: deg2->starts2) ----------------
__global__ __launch_bounds__(1024) void k_scan2(const int* __restrict__ deg, const int* __restrict__ deg2,
                                                int* __restrict__ starts, int* __restrict__ starts2,
                                                float* __restrict__ dinv) {
  __shared__ int tmp[1024];
  const int* in = blockIdx.x ? deg2 : deg;
  int* outp = blockIdx.x ? starts2 : starts;
  int t = threadIdx.x;
  int base = t * 8;
  int v[8]; int s = 0;
  #pragma unroll
  for (int i = 0; i < 8; ++i) { v[i] = in[base + i]; s += v[i]; }
  if (blockIdx.x == 0) {
    #pragma unroll
    for (int i = 0; i < 8; ++i) dinv[base + i] = rsqrtf((float)(v[i] + 1));
  }
  tmp[t] = s;
  __syncthreads();
  for (int off = 1; off < 1024; off <<= 1) {
    int x = (t >= off) ? tmp[t - off] : 0;
    __syncthreads();
    tmp[t] += x;
    __syncthreads();
  }
  int ex = (t == 0) ? 0 : tmp[t - 1];
  #pragma unroll
  for (int i = 0; i < 8; ++i) { outp[base + i] = ex; ex += v[i]; }
}

// ---------------- fused CSR fills ----------------
__global__ void k_fillb(const int* __restrict__ srcv, const int* __restrict__ dstv,
                        const int* __restrict__ starts, int* __restrict__ cursor,
                        int* __restrict__ csr,
                        const int* __restrict__ starts2, int* __restrict__ cur2,
                        int* __restrict__ nbr) {
  int e = blockIdx.x * 256 + threadIdx.x;
  if (e >= NE) return;
  int d = dstv[e], s = srcv[e];
  int pos = atomicAdd(&cursor[d], 1);
  csr[starts[d] + pos] = s;
  if (s != d) {
    int p = atomicAdd(&cur2[s], 1); nbr[starts2[s] + p] = d;
    p = atomicAdd(&cur2[d], 1);     nbr[starts2[d] + p] = s;
  }
}

// ---------------- CSR gather (GCN, bf16 xw, fuses xlocal epilogue) ----------------
__global__ __launch_bounds__(256) void k_gather(const int* __restrict__ csr,
    const int* __restrict__ starts, const int* __restrict__ deg,
    const float* __restrict__ dinv, const ushort_t* __restrict__ xwb,
    const float* __restrict__ gcn_b, float* __restrict__ xloc) {
  int d = blockIdx.x, t = threadIdx.x;
  int s0 = starts[d], cnt = deg[d];
  float acc = 0.f;
  for (int j = 0; j < cnt; ++j) {
    int s = csr[s0 + j];
    acc += dinv[s] * b2f(xwb[(size_t)s * H + t]);
  }
  float di = dinv[d];
  float self = b2f(xwb[(size_t)d * H + t]);
  xloc[(size_t)d * H + t] = di * acc + di * di * self + gcn_b[t];
}

// ---------------- SPD: level-synchronous bitset propagation ----------------
template<int FIRST>
__global__ void k_spd(const u64* __restrict__ prev, u64* __restrict__ cur,
                      const int* __restrict__ starts2, const int* __restrict__ deg2,
                      const int* __restrict__ nbr) {
  int idx = blockIdx.x * 256 + threadIdx.x;       // NN*16
  int i = idx >> 4, w = idx & 15;
  u64 acc;
  if (FIRST) {
    int il = i & 1023;
    acc = (w == (il >> 6)) ? (1ull << (il & 63)) : 0ull;
  } else {
    acc = prev[idx];
  }
  int s0 = starts2[i], cnt = deg2[i];
  for (int e = 0; e < cnt; ++e) {
    int nb = nbr[s0 + e];
    if (FIRST) {
      int nl = nb & 1023;
      if ((nl >> 6) == w) acc |= 1ull << (nl & 63);
    } else {
      acc |= prev[(size_t)nb * 16 + w];
    }
  }
  cur[idx] = acc;
}

// decode: dist byte = first level whose bitset contains the bit (monotone R1..R5 at slots 0..4)
__global__ void k_dist(const u64* __restrict__ R, u8* __restrict__ dist) {
  int idx = blockIdx.x * 256 + threadIdx.x;       // NN*256 (u32 granules)
  int i = idx >> 8, c = idx & 255;
  int w = c >> 4;
  const u64* p = R + (size_t)i * 16 + w;
  u64 r1 = p[0];
  u64 r2 = p[(size_t)NN * 16];
  u64 r3 = p[(size_t)NN * 32];
  u64 r4 = p[(size_t)NN * 48];
  u64 r5 = p[(size_t)NN * 64];
  int il = i & 1023;
  unsigned int out = 0;
  #pragma unroll
  for (int j = 0; j < 4; ++j) {
    int kbit = (c & 15) * 4 + j;
    u64 msk = 1ull << kbit;
    int dd = 6 - (int)((r1 & msk) != 0) - (int)((r2 & msk) != 0) - (int)((r3 & msk) != 0)
               - (int)((r4 & msk) != 0) - (int)((r5 & msk) != 0);
    if (il == c * 4 + j) dd = 0;
    out |= (unsigned int)dd << (8 * j);
  }
  reinterpret_cast<unsigned int*>(dist)[idx] = out;
}

// ---------------- fused fp32->bf16 conversions + bias_cat ----------------
#define WB_GCN   0
#define WB_QKV   65536
#define WB_PROJ  262144
#define WB_FFN1  327680
#define WB_FFN2  589824
#define WB_OFFN1 851968
#define WB_OFFN2 1114112
#define WB_TOTAL 1376256
#define NXBLK 2048                     // NN*H/4/256
#define NWBLK 5376                     // WB_TOTAL/256

__global__ void k_cvtall(const float* __restrict__ x,
                         const float* p0, const float* p1, const float* p2,
                         const float* p3, const float* p4, const float* p5, const float* p6,
                         const float* __restrict__ qkv_b,
                         ushort_t* __restrict__ x_bf, ushort_t* __restrict__ w_bf,
                         float* __restrict__ bias_cat) {
  int bid = blockIdx.x, t = threadIdx.x;
  if (bid < NXBLK) {
    int i = bid * 256 + t;
    float4 v = reinterpret_cast<const float4*>(x)[i];
    unsigned int lo = (unsigned int)(ushort_t)f2b(v.x) | ((unsigned int)(ushort_t)f2b(v.y) << 16);
    unsigned int hi = (unsigned int)(ushort_t)f2b(v.z) | ((unsigned int)(ushort_t)f2b(v.w) << 16);
    reinterpret_cast<uint2*>(x_bf)[i] = make_uint2(lo, hi);
  } else if (bid < NXBLK + NWBLK) {
    int i = (bid - NXBLK) * 256 + t;
    const float* src; int off;
    if (i < WB_QKV)        { src = p0; off = i; }
    else if (i < WB_PROJ)  { src = p1; off = i - WB_QKV; }
    else if (i < WB_FFN1)  { src = p2; off = i - WB_PROJ; }
    else if (i < WB_FFN2)  { src = p3; off = i - WB_FFN1; }
    else if (i < WB_OFFN1) { src = p4; off = i - WB_FFN2; }
    else if (i < WB_OFFN2) { src = p5; off = i - WB_OFFN1; }
    else                   { src = p6; off = i - WB_OFFN2; }
    w_bf[i] = (ushort_t)f2b(src[off]);
  } else {
    for (int i = t; i < 1024; i += 256) bias_cat[i] = (i < 256) ? 0.f : qkv_b[i - 256];
  }
}

// ---------------- bf16 MFMA GEMM: C[NI,O] = A[NI,K] @ W[O,K]^T + bias ----------------
// BM in {64,128}, BN=64, BK=64. OMODE: 0 = f32 out, 1 = bf16 out, 2 = split (cols<256 -> Cb2 bf16 stride 256, else Cb bf16 stride 768 col-256)
template<int BM, int ACT, int OMODE>
__global__ __launch_bounds__(256) void k_mgemm(const short* __restrict__ A,
                                               const short* __restrict__ W,
                                               const float* __restrict__ bias,
                                               float* __restrict__ Cf,
                                               short* __restrict__ Cb,
                                               short* __restrict__ Cb2,
                                               int K, int O) {
  constexpr int FM = BM / 32;
  __shared__ __attribute__((aligned(16))) short As[BM * 64];
  __shared__ __attribute__((aligned(16))) short Ws[64 * 64];
  const int tid = threadIdx.x;
  const int lane = tid & 63, wbase = tid & 192;
  const int wid = tid >> 6;
  const int lg = lane >> 4, lr = lane & 15;
  const int wm = wid >> 1, wn = wid & 1;
  const int m0 = blockIdx.y * BM, n0 = blockIdx.x * 64;
  f32x4 acc[FM][2];
  #pragma unroll
  for (int i = 0; i < FM; ++i)
    #pragma unroll
    for (int j = 0; j < 2; ++j)
      acc[i][j] = (f32x4){0.f, 0.f, 0.f, 0.f};

  for (int k0 = 0; k0 < K; k0 += 64) {
    #pragma unroll
    for (int c = 0; c < BM / 32; ++c) {
      int chunk = c * 256 + tid;
      int row = chunk >> 3, ks = chunk & 7;
      int srcks = ks ^ (row & 7);
      gload16(A + (size_t)(m0 + row) * K + k0 + srcks * 8,
              (char*)As + (c * 256 + wbase) * 16);
    }
    #pragma unroll
    for (int c = 0; c < 2; ++c) {
      int chunk = c * 256 + tid;
      int row = chunk >> 3, ks = chunk & 7;
      int srcks = ks ^ (row & 7);
      gload16(W + (size_t)(n0 + row) * K + k0 + srcks * 8,
              (char*)Ws + (c * 256 + wbase) * 16);
    }
    __syncthreads();
    #pragma unroll
    for (int kk = 0; kk < 2; ++kk) {
      const int d = kk * 4 + lg;
      bf16x8 b[2];
      #pragma unroll
      for (int fn = 0; fn < 2; ++fn) {
        int r = wn * 32 + fn * 16 + lr;
        b[fn] = *reinterpret_cast<const bf16x8*>((const char*)Ws + r * 128 + ((d ^ (r & 7)) * 16));
      }
      #pragma unroll
      for (int fm = 0; fm < FM; ++fm) {
        int r = wm * (BM / 2) + fm * 16 + lr;
        bf16x8 a = *reinterpret_cast<const bf16x8*>((const char*)As + r * 128 + ((d ^ (r & 7)) * 16));
        acc[fm][0] = __builtin_amdgcn_mfma_f32_16x16x32_bf16(a, b[0], acc[fm][0], 0, 0, 0);
        acc[fm][1] = __builtin_amdgcn_mfma_f32_16x16x32_bf16(a, b[1], acc[fm][1], 0, 0, 0);
      }
    }
    __syncthreads();
  }
  #pragma unroll
  for (int fm = 0; fm < FM; ++fm)
    #pragma unroll
    for (int fn = 0; fn < 2; ++fn)
      #pragma unroll
      for (int rg = 0; rg < 4; ++rg) {
        int r = m0 + wm * (BM / 2) + fm * 16 + lg * 4 + rg;
        int cc = n0 + wn * 32 + fn * 16 + lr;
        float v = acc[fm][fn][rg] + (bias ? bias[cc] : 0.f);
        if (ACT == 1) v = 0.5f * v * (1.0f + erff(v * 0.70710678118654752f));
        if (OMODE == 0) Cf[(size_t)r * O + cc] = v;
        else if (OMODE == 1) Cb[(size_t)r * O + cc] = f2b(v);
        else {
          if (cc < 256) Cb2[(size_t)r * 256 + cc] = f2b(v);
          else          Cb[(size_t)r * 768 + cc - 256] = f2b(v);
        }
      }
}

// ---------------- MFMA flash attention with SPD bias ----------------
// Per block: (g, head, 64 q-rows). 4 waves, wave w owns q rows w*16..w*16+15.
// LDS layouts chosen for <=2-way bank conflicts (see round-5 notes).
__global__ __launch_bounds__(256) void k_attn(const ushort_t* __restrict__ qkv,
                                              const u8* __restrict__ dist,
                                              const float* __restrict__ emb,
                                              short* __restrict__ attno) {
  __shared__ __attribute__((aligned(16))) char KsB[64 * 80];      // K rows [key][d], stride 80B
  __shared__ __attribute__((aligned(16))) char VtB[32 * 128 + 64];// V^T: byte(d,key)=d*128+(d>>3)*16+((key*2)^((d&7)<<4))
  __shared__ __attribute__((aligned(16))) char PB[4][16 * 128];   // per-wave P: byte(q,key)=q*128+((key*2)^((q&7)<<4))
  __shared__ __attribute__((aligned(16))) u8 Ds[64 * 80];         // dist^T tile [key][q_local], stride 80 (dist symmetric)
  __shared__ float semb[8];
  const int g = blockIdx.z, head = blockIdx.y;
  const int q0 = blockIdx.x * 64;
  const int t = threadIdx.x, lane = t & 63, wid = t >> 6;
  const int lg = lane >> 4, lr = lane & 15;
  if (t < 7) semb[t] = emb[t];
  const size_t nodebase = (size_t)(g * M) * 768;
  const float SC = 0.17677669529663687f;   // HD^-0.5

  // Q fragment (A layout): lane holds Q[q = wid*16 + lr][d = lg*8 .. +7]
  bf16x8 qfrag = *reinterpret_cast<const bf16x8*>(
      qkv + nodebase + (size_t)(q0 + wid * 16 + lr) * 768 + head * 32 + lg * 8);

  const int srow = t >> 2, sc = t & 3;     // staging: key row, 8-elem chunk
  uint4 kr, vr, dr;
  {
    size_t kn = nodebase + (size_t)(srow) * 768 + head * 32;
    kr = *reinterpret_cast<const uint4*>(qkv + kn + 256 + sc * 8);
    vr = *reinterpret_cast<const uint4*>(qkv + kn + 512 + sc * 8);
    dr = *reinterpret_cast<const uint4*>(dist + (size_t)(g * M + srow) * M + q0 + sc * 16);
  }

  f32x4 o0 = {0.f, 0.f, 0.f, 0.f}, o1 = {0.f, 0.f, 0.f, 0.f};
  float mrun[4] = {-3e38f, -3e38f, -3e38f, -3e38f};
  float lrun[4] = {0.f, 0.f, 0.f, 0.f};
  char* pb = PB[wid];
  const int kp = srow >> 1;
  const int odd = srow & 1;
  const int d0 = sc * 8;

  for (int kt = 0; kt < 16; ++kt) {
    // ---- store staged regs ----
    *reinterpret_cast<uint4*>(KsB + srow * 80 + sc * 16) = kr;
    *reinterpret_cast<uint4*>(Ds + srow * 80 + sc * 16) = dr;
    // V^T: pair with partner holding key^1 (lane t^4), pack 2 keys per u32
    {
      uint4 pvr;
      pvr.x = (unsigned int)__shfl_xor((int)vr.x, 4);
      pvr.y = (unsigned int)__shfl_xor((int)vr.y, 4);
      pvr.z = (unsigned int)__shfl_xor((int)vr.z, 4);
      pvr.w = (unsigned int)__shfl_xor((int)vr.w, 4);
      unsigned int ev[4], ov[4];
      ev[0] = odd ? pvr.x : vr.x; ev[1] = odd ? pvr.y : vr.y;
      ev[2] = odd ? pvr.z : vr.z; ev[3] = odd ? pvr.w : vr.w;
      ov[0] = odd ? vr.x : pvr.x; ov[1] = odd ? vr.y : pvr.y;
      ov[2] = odd ? vr.z : pvr.z; ov[3] = odd ? vr.w : pvr.w;
      #pragma unroll
      for (int di = 0; di < 4; ++di) {
        int dd = odd * 4 + di;                 // even thread: d-half 0..3, odd: 4..7
        int d = d0 + dd;
        unsigned int e16 = (dd & 1) ? (ev[dd >> 1] >> 16) : (ev[dd >> 1] & 0xffff);
        unsigned int o16 = (dd & 1) ? (ov[dd >> 1] >> 16) : (ov[dd >> 1] & 0xffff);
        *reinterpret_cast<unsigned int*>(VtB + d * 128 + ((d >> 3) << 4) + ((kp << 2) ^ ((d & 7) << 4)))
            = e16 | (o16 << 16);
      }
    }
    __syncthreads();

    // ---- prefetch next tile (T14: issue before compute, consumed next iter) ----
    {
      int ktn = (kt + 1) & 15;
      size_t kn = nodebase + (size_t)(ktn * 64 + srow) * 768 + head * 32;
      kr = *reinterpret_cast<const uint4*>(qkv + kn + 256 + sc * 8);
      vr = *reinterpret_cast<const uint4*>(qkv + kn + 512 + sc * 8);
      dr = *reinterpret_cast<const uint4*>(dist + (size_t)(g * M + ktn * 64 + srow) * M + q0 + sc * 16);
    }

    // ---- scores: 4 MFMAs ----
    f32x4 s[4];
    unsigned int d4[4];
    #pragma unroll
    for (int fn = 0; fn < 4; ++fn) {
      bf16x8 b = *reinterpret_cast<const bf16x8*>(KsB + (fn * 16 + lr) * 80 + lg * 16);
      s[fn] = __builtin_amdgcn_mfma_f32_16x16x32_bf16(qfrag, b, (f32x4){0.f,0.f,0.f,0.f}, 0, 0, 0);
      d4[fn] = *reinterpret_cast<const unsigned int*>(Ds + (fn * 16 + lr) * 80 + wid * 16 + 4 * lg);
    }
    #pragma unroll
    for (int fn = 0; fn < 4; ++fn)
      #pragma unroll
      for (int rg = 0; rg < 4; ++rg)
        s[fn][rg] = s[fn][rg] * SC + semb[(d4[fn] >> (8 * rg)) & 255];

    // ---- online softmax (row spread over 16 lanes of same lg group) ----
    #pragma unroll
    for (int rg = 0; rg < 4; ++rg) {
      float v = fmaxf(fmaxf(s[0][rg], s[1][rg]), fmaxf(s[2][rg], s[3][rg]));
      v = fmaxf(v, __shfl_xor(v, 1));
      v = fmaxf(v, __shfl_xor(v, 2));
      v = fmaxf(v, __shfl_xor(v, 4));
      v = fmaxf(v, __shfl_xor(v, 8));
      float mnew = fmaxf(mrun[rg], v);
      float corr = __expf(mrun[rg] - mnew);
      mrun[rg] = mnew;
      #pragma unroll
      for (int fn = 0; fn < 4; ++fn) s[fn][rg] = __expf(s[fn][rg] - mnew);
      float rs = s[0][rg] + s[1][rg] + s[2][rg] + s[3][rg];
      rs += __shfl_xor(rs, 1);
      rs += __shfl_xor(rs, 2);
      rs += __shfl_xor(rs, 4);
      rs += __shfl_xor(rs, 8);
      lrun[rg] = lrun[rg] * corr + rs;
      o0[rg] *= corr;
      o1[rg] *= corr;
    }

    // ---- P -> per-wave LDS (bf16) ----
    #pragma unroll
    for (int fn = 0; fn < 4; ++fn)
      #pragma unroll
      for (int rg = 0; rg < 4; ++rg) {
        int qq = 4 * lg + rg, key = fn * 16 + lr;
        *reinterpret_cast<ushort_t*>(pb + qq * 128 + ((key * 2) ^ ((qq & 7) << 4))) =
            (ushort_t)f2b(s[fn][rg]);
      }

    // ---- PV: 4 MFMAs ----
    #pragma unroll
    for (int kh = 0; kh < 2; ++kh) {
      int c = kh * 4 + lg;
      int chx = (c << 4) ^ ((lr & 7) << 4);
      bf16x8 a  = *reinterpret_cast<const bf16x8*>(pb + lr * 128 + chx);
      bf16x8 b0 = *reinterpret_cast<const bf16x8*>(VtB + lr * 128 + ((lr >> 3) << 4) + chx);
      bf16x8 b1 = *reinterpret_cast<const bf16x8*>(VtB + (16 + lr) * 128 + (((16 + lr) >> 3) << 4) + chx);
      o0 = __builtin_amdgcn_mfma_f32_16x16x32_bf16(a, b0, o0, 0, 0, 0);
      o1 = __builtin_amdgcn_mfma_f32_16x16x32_bf16(a, b1, o1, 0, 0, 0);
    }
    __syncthreads();
  }

  // ---- output: O[q][d] bf16 ----
  #pragma unroll
  for (int rg = 0; rg < 4; ++rg) {
    float inv = 1.0f / lrun[rg];
    size_t qn = (size_t)(g * M + q0 + wid * 16 + 4 * lg + rg);
    attno[qn * H + head * 32 + lr]      = f2b(o0[rg] * inv);
    attno[qn * H + head * 32 + 16 + lr] = f2b(o1[rg] * inv);
  }
}

// ---------------- fused add(2|3) + LayerNorm, wave per row ----------------
__global__ __launch_bounds__(256) void k_ln(const float* __restrict__ a, const float* __restrict__ b,
                                            const float* __restrict__ c3,
                                            const float* __restrict__ gam, const float* __restrict__ bet,
                                            float* __restrict__ out, ushort_t* __restrict__ outb) {
  int wid = threadIdx.x >> 6, lane = threadIdx.x & 63;
  int row = blockIdx.x * 4 + wid;
  size_t base = (size_t)row * H + lane * 4;
  float4 v = *reinterpret_cast<const float4*>(a + base);
  float4 vb = *reinterpret_cast<const float4*>(b + base);
  v.x += vb.x; v.y += vb.y; v.z += vb.z; v.w += vb.w;
  if (c3) {
    float4 vc = *reinterpret_cast<const float4*>(c3 + base);
    v.x += vc.x; v.y += vc.y; v.z += vc.z; v.w += vc.w;
  }
  float s = v.x + v.y + v.z + v.w;
  float s2 = v.x*v.x + v.y*v.y + v.z*v.z + v.w*v.w;
  #pragma unroll
  for (int off = 1; off <= 32; off <<= 1) {
    s  += __shfl_xor(s, off);
    s2 += __shfl_xor(s2, off);
  }
  float mean = s * (1.0f / 256.0f);
  float rstd = rsqrtf(s2 * (1.0f / 256.0f) - mean * mean + 1e-5f);
  float4 gg = *reinterpret_cast<const float4*>(gam + lane * 4);
  float4 bb = *reinterpret_cast<const float4*>(bet + lane * 4);
  float4 r;
  r.x = (v.x - mean) * rstd * gg.x + bb.x;
  r.y = (v.y - mean) * rstd * gg.y + bb.y;
  r.z = (v.z - mean) * rstd * gg.z + bb.z;
  r.w = (v.w - mean) * rstd * gg.w + bb.w;
  *reinterpret_cast<float4*>(out + base) = r;
  if (outb) {
    unsigned int lo = (unsigned int)(ushort_t)f2b(r.x) | ((unsigned int)(ushort_t)f2b(r.y) << 16);
    unsigned int hi = (unsigned int)(ushort_t)f2b(r.z) | ((unsigned int)(ushort_t)f2b(r.w) << 16);
    *reinterpret_cast<uint2*>(outb + base) = make_uint2(lo, hi);
  }
}

// ---------------- launch ----------------
extern "C" void kernel_launch(void* const* d_in, const int* in_sizes, int n_in,
                              void* d_out, int out_size, void* d_ws, size_t ws_size,
                              hipStream_t stream) {
  const float* x      = (const float*)d_in[0];
  const float* gcn_w  = (const float*)d_in[1];
  const float* gcn_b  = (const float*)d_in[2];
  const float* qkv_w  = (const float*)d_in[3];
  const float* qkv_b  = (const float*)d_in[4];
  const float* proj_w = (const float*)d_in[5];
  const float* proj_b = (const float*)d_in[6];
  const float* ln1_g  = (const float*)d_in[7];
  const float* ln1_b  = (const float*)d_in[8];
  const float* ln2_g  = (const float*)d_in[9];
  const float* ln2_b  = (const float*)d_in[10];
  const float* ffn1_w = (const float*)d_in[11];
  const float* ffn1_b = (const float*)d_in[12];
  const float* ffn2_w = (const float*)d_in[13];
  const float* ffn2_b = (const float*)d_in[14];
  const float* bias_e = (const float*)d_in[15];
  const float* oln1_g = (const float*)d_in[16];
  const float* oln1_b = (const float*)d_in[17];
  const float* oln2_g = (const float*)d_in[18];
  const float* oln2_b = (const float*)d_in[19];
  const float* offn1_w= (const float*)d_in[20];
  const float* offn1_b= (const float*)d_in[21];
  const float* offn2_w= (const float*)d_in[22];
  const float* offn2_b= (const float*)d_in[23];
  const int*   eidx   = (const int*)d_in[24];
  const int* esrc = eidx;
  const int* edst = eidx + NE;

  char* wsp = (char*)d_ws;
  size_t off = 0;
  auto alloc = [&](size_t bytes) { void* p = wsp + off; off += (bytes + 255) & ~255ull; return p; };
  const size_t SZ_NH = (size_t)NN * H * 4;
  ushort_t* x_bf  = (ushort_t*)alloc((size_t)NN * H * 2);         // 4MB
  ushort_t* w_bf  = (ushort_t*)alloc((size_t)WB_TOTAL * 2);       // 2.75MB
  float* bias_cat = (float*)alloc(1024 * 4);
  ushort_t* xwb   = (ushort_t*)alloc((size_t)NN * H * 2);         // 4MB
  float* xloc = (float*)alloc(SZ_NH);                             // 8MB
  float* dinv = (float*)alloc((size_t)NN * 4);
  int*   deg  = (int*)  alloc((size_t)NN * 4);                    // ┐ contiguous
  int* cursor = (int*)  alloc((size_t)NN * 4);                    // │ zeroed
  int*  deg2  = (int*)  alloc((size_t)NN * 4);                    // │ together
  int* cursor2= (int*)  alloc((size_t)NN * 4);                    // ┘
  int* starts = (int*)  alloc((size_t)NN * 4);
  int* starts2= (int*)  alloc((size_t)NN * 4);
  int*   csr  = (int*)  alloc((size_t)NE * 4);                    // 0.5MB
  int*   nbr  = (int*)  alloc((size_t)2 * NE * 4);                // 1MB
  u64*   Rbuf = (u64*)  alloc((size_t)5 * NN * 16 * 8);           // 5MB (levels 1..5)
  u8*    dist = (u8*)   alloc((size_t)NN * M);                    // 8MB  ┐ mid alias
  ushort_t* qkvb = (ushort_t*)alloc((size_t)NN * 768 * 2);        // 12MB ┘ (20MB)
  float* h1   = (float*)alloc(SZ_NH);                             // 8MB
  ushort_t* h1_bf = (ushort_t*)alloc((size_t)NN * H * 2);         // 4MB
  float* f2   = (float*)alloc(SZ_NH);                             // 8MB
  float* h2   = (float*)alloc(SZ_NH);                             // 8MB (also projo before ln2)
  float* y    = (float*)alloc(SZ_NH);                             // 8MB

  ushort_t* attno = x_bf;                  // x_bf dead after gcn+qkv gemm
  float* projo = h2;                       // h2 written at ln2, after projo dead
  ushort_t* mid = (ushort_t*)dist;         // dist+qkvb (20MB) dead after attn; need 16MB
  ushort_t* y_bf = h1_bf;                  // h1_bf dead after ffn1
  float* outp = (float*)d_out;

  ushort_t* proj_wb = w_bf + WB_PROJ;
  ushort_t* ffn1_wb = w_bf + WB_FFN1;
  ushort_t* ffn2_wb = w_bf + WB_FFN2;
  ushort_t* offn1_wb= w_bf + WB_OFFN1;
  ushort_t* offn2_wb= w_bf + WB_OFFN2;

  hipMemsetAsync(deg, 0, (size_t)4 * NN * 4, stream);   // deg,cursor,deg2,cursor2

  // conversions (x, all weights, bias_cat)
  k_cvtall<<<NXBLK + NWBLK + 1, 256, 0, stream>>>(x, gcn_w, qkv_w, proj_w, ffn1_w,
                                                  ffn2_w, offn1_w, offn2_w, qkv_b,
                                                  x_bf, w_bf, bias_cat);

  // --- degrees & CSRs ---
  k_prep<<<NE / 256, 256, 0, stream>>>(esrc, edst, deg, deg2);
  k_scan2<<<2, 1024, 0, stream>>>(deg, deg2, starts, starts2, dinv);
  k_fillb<<<NE / 256, 256, 0, stream>>>(esrc, edst, starts, cursor, csr, starts2, cursor2, nbr);

  // --- merged GCN-xw + QKV GEMM (A = x_bf, W = gcn_w‖qkv_w, O = 1024 split) ---
  k_mgemm<128, 0, 2><<<dim3(1024 / 64, NN / 128), 256, 0, stream>>>(
      (const short*)x_bf, (const short*)w_bf, bias_cat, nullptr, (short*)qkvb, (short*)xwb, 256, 1024);
  k_gather<<<NN, 256, 0, stream>>>(csr, starts, deg, dinv, xwb, gcn_b, xloc);

  // --- SPD distances (level-synchronous bitset propagation; level 1 computed in-place) ---
  k_spd<1><<<NN * 16 / 256, 256, 0, stream>>>(nullptr, Rbuf, starts2, deg2, nbr);
  for (int l = 2; l <= 5; ++l)
    k_spd<0><<<NN * 16 / 256, 256, 0, stream>>>(Rbuf + (size_t)(l - 2) * NN * 16,
                                                Rbuf + (size_t)(l - 1) * NN * 16,
                                                starts2, deg2, nbr);
  k_dist<<<NN * 256 / 256, 256, 0, stream>>>(Rbuf, dist);

  // --- Graphormer encoder ---
  k_attn<<<dim3(M / 64, HEADS, G), 256, 0, stream>>>(qkvb, dist, bias_e, (short*)attno);
  k_mgemm<64, 0, 0><<<dim3(256 / 64, NN / 64), 256, 0, stream>>>(
      (const short*)attno, (const short*)proj_wb, proj_b, projo, nullptr, nullptr, 256, 256);
  k_ln<<<NN / 4, 256, 0, stream>>>(x, projo, nullptr, ln1_g, ln1_b, h1, h1_bf);
  k_mgemm<128, 1, 1><<<dim3(FFND / 64, NN / 128), 256, 0, stream>>>(
      (const short*)h1_bf, (const short*)ffn1_wb, ffn1_b, nullptr, (short*)mid, nullptr, 256, FFND);
  k_mgemm<64, 0, 0><<<dim3(256 / 64, NN / 64), 256, 0, stream>>>(
      (const short*)mid, (const short*)ffn2_wb, ffn2_b, f2, nullptr, nullptr, FFND, 256);
  k_ln<<<NN / 4, 256, 0, stream>>>(h1, f2, nullptr, ln2_g, ln2_b, h2, nullptr);

  // --- GPS combine + outer FFN ---
  k_ln<<<NN / 4, 256, 0, stream>>>(x, xloc, h2, oln1_g, oln1_b, y, y_bf);
  k_mgemm<128, 1, 1><<<dim3(FFND / 64, NN / 128), 256, 0, stream>>>(
      (const short*)y_bf, (const short*)offn1_wb, offn1_b, nullptr, (short*)mid, nullptr, 256, FFND);
  k_mgemm<64, 0, 0><<<dim3(256 / 64, NN / 64), 256, 0, stream>>>(
      (const short*)mid, (const short*)offn2_wb, offn2_b, f2, nullptr, nullptr, FFND, 256);
  k_ln<<<NN / 4, 256, 0, stream>>>(y, f2, nullptr, oln2_g, oln2_b, outp, nullptr);
}

// Round 6
// 389.673 us; speedup vs baseline: 4.4871x; 1.1430x over previous
//
#include <hip/hip_runtime.h>
#include <hip/hip_bf16.h>
#include <cstdint>

#define G 8
#define M 1024
#define H 256
#define HEADS 8
#define FFND 1024
#define NE 131072
#define NN (G*M)          // 8192
#define HD 32             // H/HEADS

typedef unsigned long long u64;
typedef uint8_t u8;
typedef unsigned short ushort_t;
typedef __attribute__((ext_vector_type(8))) short bf16x8;
typedef __attribute__((ext_vector_type(4))) float f32x4;

__device__ __forceinline__ short f2b(float v) {
  __hip_bfloat16 h = __float2bfloat16(v);
  return *reinterpret_cast<short*>(&h);
}
__device__ __forceinline__ float b2f(unsigned int u) {
  union { float f; unsigned int i; } v; v.i = u << 16; return v.f;
}

typedef __attribute__((address_space(1))) const void gvoid;
typedef __attribute__((address_space(3))) void lvoid;
__device__ __forceinline__ void gload16(const void* g, void* l) {
  __builtin_amdgcn_global_load_lds((gvoid*)g, (lvoid*)l, 16, 0, 0);
}

// ---------------- fused degree pass ----------------
__global__ void k_prep(const int* __restrict__ srcv, const int* __restrict__ dstv,
                       int* __restrict__ deg, int* __restrict__ deg2) {
  int e = blockIdx.x * 256 + threadIdx.x;
  if (e >= NE) return;
  int d = dstv[e], s = srcv[e];
  atomicAdd(&deg[d], 1);
  if (s != d) { atomicAdd(&deg2[s], 1); atomicAdd(&deg2[d], 1); }
}

// ---------------- dual prefix scan (block 0: deg->starts+dinv, block 1: deg2->starts2) ----------------
__global__ __launch_bounds__(1024) void k_scan2(const int* __restrict__ deg, const int* __restrict__ deg2,
                                                int* __restrict__ starts, int* __restrict__ starts2,
                                                float* __restrict__ dinv) {
  __shared__ int tmp[1024];
  const int* in = blockIdx.x ? deg2 : deg;
  int* outp = blockIdx.x ? starts2 : starts;
  int t = threadIdx.x;
  int base = t * 8;
  int v[8]; int s = 0;
  #pragma unroll
  for (int i = 0; i < 8; ++i) { v[i] = in[base + i]; s += v[i]; }
  if (blockIdx.x == 0) {
    #pragma unroll
    for (int i = 0; i < 8; ++i) dinv[base + i] = rsqrtf((float)(v[i] + 1));
  }
  tmp[t] = s;
  __syncthreads();
  for (int off = 1; off < 1024; off <<= 1) {
    int x = (t >= off) ? tmp[t - off] : 0;
    __syncthreads();
    tmp[t] += x;
    __syncthreads();
  }
  int ex = (t == 0) ? 0 : tmp[t - 1];
  #pragma unroll
  for (int i = 0; i < 8; ++i) { outp[base + i] = ex; ex += v[i]; }
}

// ---------------- fused CSR fills ----------------
__global__ void k_fillb(const int* __restrict__ srcv, const int* __restrict__ dstv,
                        const int* __restrict__ starts, int* __restrict__ cursor,
                        int* __restrict__ csr,
                        const int* __restrict__ starts2, int* __restrict__ cur2,
                        int* __restrict__ nbr) {
  int e = blockIdx.x * 256 + threadIdx.x;
  if (e >= NE) return;
  int d = dstv[e], s = srcv[e];
  int pos = atomicAdd(&cursor[d], 1);
  csr[starts[d] + pos] = s;
  if (s != d) {
    int p = atomicAdd(&cur2[s], 1); nbr[starts2[s] + p] = d;
    p = atomicAdd(&cur2[d], 1);     nbr[starts2[d] + p] = s;
  }
}

// ---------------- CSR gather (GCN, bf16 xw, fuses xlocal epilogue) ----------------
__global__ __launch_bounds__(256) void k_gather(const int* __restrict__ csr,
    const int* __restrict__ starts, const int* __restrict__ deg,
    const float* __restrict__ dinv, const ushort_t* __restrict__ xwb,
    const float* __restrict__ gcn_b, float* __restrict__ xloc) {
  int d = blockIdx.x, t = threadIdx.x;
  int s0 = starts[d], cnt = deg[d];
  float acc = 0.f;
  for (int j = 0; j < cnt; ++j) {
    int s = csr[s0 + j];
    acc += dinv[s] * b2f(xwb[(size_t)s * H + t]);
  }
  float di = dinv[d];
  float self = b2f(xwb[(size_t)d * H + t]);
  xloc[(size_t)d * H + t] = di * acc + di * di * self + gcn_b[t];
}

// ---------------- SPD: merged 5-level bitset BFS + dist decode, all in LDS ----------------
// Block = (graph, u32-word): 8*32 = 256 blocks of 1024 threads. Word w covers keys
// [w*32, w*32+32). LDS ping-pong of the per-word reachability slice; dist bytes
// recorded incrementally (newly-reached at level l -> byte l), flushed at end.
__global__ __launch_bounds__(1024) void k_spdm(const int* __restrict__ starts2,
                                               const int* __restrict__ deg2,
                                               const int* __restrict__ nbr,
                                               u8* __restrict__ dist) {
  __shared__ unsigned int Abuf[1024], Bbuf[1024];
  __shared__ u8 dtile[1024][32];
  const int g = blockIdx.x >> 5, w = blockIdx.x & 31;
  const int i = threadIdx.x;
  const int gi = (g << 10) | i;
  unsigned int self = ((i >> 5) == w) ? (1u << (i & 31)) : 0u;
  Abuf[i] = self;
  uint4 six; six.x = six.y = six.z = six.w = 0x06060606u;
  *reinterpret_cast<uint4*>(&dtile[i][0])  = six;
  *reinterpret_cast<uint4*>(&dtile[i][16]) = six;
  if (self) dtile[i][i & 31] = 0;
  const int s0 = starts2[gi], cnt = deg2[gi];
  unsigned int* prev = Abuf;
  unsigned int* cur  = Bbuf;
  unsigned int vis = self;
  __syncthreads();
  for (int l = 1; l <= 5; ++l) {
    unsigned int acc = vis;
    for (int e = 0; e < cnt; ++e)
      acc |= prev[nbr[s0 + e] & 1023];
    unsigned int newly = acc & ~vis;
    while (newly) {
      int k = __ffs(newly) - 1;
      newly &= newly - 1;
      dtile[i][k] = (u8)l;
    }
    cur[i] = acc;
    vis = acc;
    __syncthreads();
    unsigned int* tsw = prev; prev = cur; cur = tsw;
  }
  u8* drow = dist + ((size_t)gi << 10) + w * 32;
  *reinterpret_cast<uint4*>(drow)      = *reinterpret_cast<const uint4*>(&dtile[i][0]);
  *reinterpret_cast<uint4*>(drow + 16) = *reinterpret_cast<const uint4*>(&dtile[i][16]);
}

// ---------------- fused fp32->bf16 conversions + bias_cat ----------------
#define WB_GCN   0
#define WB_QKV   65536
#define WB_PROJ  262144
#define WB_FFN1  327680
#define WB_FFN2  589824
#define WB_OFFN1 851968
#define WB_OFFN2 1114112
#define WB_TOTAL 1376256
#define NXBLK 2048                     // NN*H/4/256
#define NWBLK 5376                     // WB_TOTAL/256

__global__ void k_cvtall(const float* __restrict__ x,
                         const float* p0, const float* p1, const float* p2,
                         const float* p3, const float* p4, const float* p5, const float* p6,
                         const float* __restrict__ qkv_b,
                         ushort_t* __restrict__ x_bf, ushort_t* __restrict__ w_bf,
                         float* __restrict__ bias_cat) {
  int bid = blockIdx.x, t = threadIdx.x;
  if (bid < NXBLK) {
    int i = bid * 256 + t;
    float4 v = reinterpret_cast<const float4*>(x)[i];
    unsigned int lo = (unsigned int)(ushort_t)f2b(v.x) | ((unsigned int)(ushort_t)f2b(v.y) << 16);
    unsigned int hi = (unsigned int)(ushort_t)f2b(v.z) | ((unsigned int)(ushort_t)f2b(v.w) << 16);
    reinterpret_cast<uint2*>(x_bf)[i] = make_uint2(lo, hi);
  } else if (bid < NXBLK + NWBLK) {
    int i = (bid - NXBLK) * 256 + t;
    const float* src; int off;
    if (i < WB_QKV)        { src = p0; off = i; }
    else if (i < WB_PROJ)  { src = p1; off = i - WB_QKV; }
    else if (i < WB_FFN1)  { src = p2; off = i - WB_PROJ; }
    else if (i < WB_FFN2)  { src = p3; off = i - WB_FFN1; }
    else if (i < WB_OFFN1) { src = p4; off = i - WB_FFN2; }
    else if (i < WB_OFFN2) { src = p5; off = i - WB_OFFN1; }
    else                   { src = p6; off = i - WB_OFFN2; }
    w_bf[i] = (ushort_t)f2b(src[off]);
  } else {
    for (int i = t; i < 1024; i += 256) bias_cat[i] = (i < 256) ? 0.f : qkv_b[i - 256];
  }
}

// ---------------- bf16 MFMA GEMM: C[NI,O] = A[NI,K] @ W[O,K]^T + bias ----------------
// BM in {64,128}, BN=64, BK=64. OMODE: 0 = f32 out, 1 = bf16 out, 2 = split (cols<256 -> Cb2 bf16 stride 256, else Cb bf16 stride 768 col-256)
template<int BM, int ACT, int OMODE>
__global__ __launch_bounds__(256) void k_mgemm(const short* __restrict__ A,
                                               const short* __restrict__ W,
                                               const float* __restrict__ bias,
                                               float* __restrict__ Cf,
                                               short* __restrict__ Cb,
                                               short* __restrict__ Cb2,
                                               int K, int O) {
  constexpr int FM = BM / 32;
  __shared__ __attribute__((aligned(16))) short As[BM * 64];
  __shared__ __attribute__((aligned(16))) short Ws[64 * 64];
  const int tid = threadIdx.x;
  const int lane = tid & 63, wbase = tid & 192;
  const int wid = tid >> 6;
  const int lg = lane >> 4, lr = lane & 15;
  const int wm = wid >> 1, wn = wid & 1;
  const int m0 = blockIdx.y * BM, n0 = blockIdx.x * 64;
  f32x4 acc[FM][2];
  #pragma unroll
  for (int i = 0; i < FM; ++i)
    #pragma unroll
    for (int j = 0; j < 2; ++j)
      acc[i][j] = (f32x4){0.f, 0.f, 0.f, 0.f};

  for (int k0 = 0; k0 < K; k0 += 64) {
    #pragma unroll
    for (int c = 0; c < BM / 32; ++c) {
      int chunk = c * 256 + tid;
      int row = chunk >> 3, ks = chunk & 7;
      int srcks = ks ^ (row & 7);
      gload16(A + (size_t)(m0 + row) * K + k0 + srcks * 8,
              (char*)As + (c * 256 + wbase) * 16);
    }
    #pragma unroll
    for (int c = 0; c < 2; ++c) {
      int chunk = c * 256 + tid;
      int row = chunk >> 3, ks = chunk & 7;
      int srcks = ks ^ (row & 7);
      gload16(W + (size_t)(n0 + row) * K + k0 + srcks * 8,
              (char*)Ws + (c * 256 + wbase) * 16);
    }
    __syncthreads();
    #pragma unroll
    for (int kk = 0; kk < 2; ++kk) {
      const int d = kk * 4 + lg;
      bf16x8 b[2];
      #pragma unroll
      for (int fn = 0; fn < 2; ++fn) {
        int r = wn * 32 + fn * 16 + lr;
        b[fn] = *reinterpret_cast<const bf16x8*>((const char*)Ws + r * 128 + ((d ^ (r & 7)) * 16));
      }
      #pragma unroll
      for (int fm = 0; fm < FM; ++fm) {
        int r = wm * (BM / 2) + fm * 16 + lr;
        bf16x8 a = *reinterpret_cast<const bf16x8*>((const char*)As + r * 128 + ((d ^ (r & 7)) * 16));
        acc[fm][0] = __builtin_amdgcn_mfma_f32_16x16x32_bf16(a, b[0], acc[fm][0], 0, 0, 0);
        acc[fm][1] = __builtin_amdgcn_mfma_f32_16x16x32_bf16(a, b[1], acc[fm][1], 0, 0, 0);
      }
    }
    __syncthreads();
  }
  #pragma unroll
  for (int fm = 0; fm < FM; ++fm)
    #pragma unroll
    for (int fn = 0; fn < 2; ++fn)
      #pragma unroll
      for (int rg = 0; rg < 4; ++rg) {
        int r = m0 + wm * (BM / 2) + fm * 16 + lg * 4 + rg;
        int cc = n0 + wn * 32 + fn * 16 + lr;
        float v = acc[fm][fn][rg] + (bias ? bias[cc] : 0.f);
        if (ACT == 1) v = 0.5f * v * (1.0f + erff(v * 0.70710678118654752f));
        if (OMODE == 0) Cf[(size_t)r * O + cc] = v;
        else if (OMODE == 1) Cb[(size_t)r * O + cc] = f2b(v);
        else {
          if (cc < 256) Cb2[(size_t)r * 256 + cc] = f2b(v);
          else          Cb[(size_t)r * 768 + cc - 256] = f2b(v);
        }
      }
}

// ---------------- MFMA flash attention with SPD bias ----------------
// Per block: (g, head, 64 q-rows). 4 waves, wave w owns q rows w*16..w*16+15.
// No online max: inputs bounded (|s| << 80), p = exp2(s*C1 + bias*log2e) is
// f32-safe; l reduced once after the K loop.
__global__ __launch_bounds__(256) void k_attn(const ushort_t* __restrict__ qkv,
                                              const u8* __restrict__ dist,
                                              const float* __restrict__ emb,
                                              short* __restrict__ attno) {
  __shared__ __attribute__((aligned(16))) char KsB[64 * 80];      // K rows [key][d], stride 80B
  __shared__ __attribute__((aligned(16))) char VtB[32 * 128 + 64];// V^T: byte(d,key)=d*128+(d>>3)*16+((key*2)^((d&7)<<4))
  __shared__ __attribute__((aligned(16))) char PB[4][16 * 128];   // per-wave P: byte(q,key)=q*128+((key*2)^((q&7)<<4))
  __shared__ __attribute__((aligned(16))) u8 Ds[64 * 80];         // dist^T tile [key][q_local], stride 80 (dist symmetric)
  __shared__ float semb[8];
  const int g = blockIdx.z, head = blockIdx.y;
  const int q0 = blockIdx.x * 64;
  const int t = threadIdx.x, lane = t & 63, wid = t >> 6;
  const int lg = lane >> 4, lr = lane & 15;
  if (t < 7) semb[t] = emb[t] * 1.44269504088896341f;
  const size_t nodebase = (size_t)(g * M) * 768;
  const float C1 = 0.17677669529663687f * 1.44269504088896341f;  // HD^-0.5 * log2(e)

  // Q fragment (A layout): lane holds Q[q = wid*16 + lr][d = lg*8 .. +7]
  bf16x8 qfrag = *reinterpret_cast<const bf16x8*>(
      qkv + nodebase + (size_t)(q0 + wid * 16 + lr) * 768 + head * 32 + lg * 8);

  const int srow = t >> 2, sc = t & 3;     // staging: key row, 8-elem chunk
  uint4 kr, vr, dr;
  {
    size_t kn = nodebase + (size_t)(srow) * 768 + head * 32;
    kr = *reinterpret_cast<const uint4*>(qkv + kn + 256 + sc * 8);
    vr = *reinterpret_cast<const uint4*>(qkv + kn + 512 + sc * 8);
    dr = *reinterpret_cast<const uint4*>(dist + (size_t)(g * M + srow) * M + q0 + sc * 16);
  }

  f32x4 o0 = {0.f, 0.f, 0.f, 0.f}, o1 = {0.f, 0.f, 0.f, 0.f};
  float lpart[4] = {0.f, 0.f, 0.f, 0.f};
  char* pb = PB[wid];
  const int kp = srow >> 1;
  const int odd = srow & 1;
  const int d0 = sc * 8;

  for (int kt = 0; kt < 16; ++kt) {
    // ---- store staged regs ----
    *reinterpret_cast<uint4*>(KsB + srow * 80 + sc * 16) = kr;
    *reinterpret_cast<uint4*>(Ds + srow * 80 + sc * 16) = dr;
    // V^T: pair with partner holding key^1 (lane t^4), pack 2 keys per u32
    {
      uint4 pvr;
      pvr.x = (unsigned int)__shfl_xor((int)vr.x, 4);
      pvr.y = (unsigned int)__shfl_xor((int)vr.y, 4);
      pvr.z = (unsigned int)__shfl_xor((int)vr.z, 4);
      pvr.w = (unsigned int)__shfl_xor((int)vr.w, 4);
      unsigned int ev[4], ov[4];
      ev[0] = odd ? pvr.x : vr.x; ev[1] = odd ? pvr.y : vr.y;
      ev[2] = odd ? pvr.z : vr.z; ev[3] = odd ? pvr.w : vr.w;
      ov[0] = odd ? vr.x : pvr.x; ov[1] = odd ? vr.y : pvr.y;
      ov[2] = odd ? vr.z : pvr.z; ov[3] = odd ? vr.w : pvr.w;
      #pragma unroll
      for (int di = 0; di < 4; ++di) {
        int dd = odd * 4 + di;                 // even thread: d-half 0..3, odd: 4..7
        int d = d0 + dd;
        unsigned int e16 = (dd & 1) ? (ev[dd >> 1] >> 16) : (ev[dd >> 1] & 0xffff);
        unsigned int o16 = (dd & 1) ? (ov[dd >> 1] >> 16) : (ov[dd >> 1] & 0xffff);
        *reinterpret_cast<unsigned int*>(VtB + d * 128 + ((d >> 3) << 4) + ((kp << 2) ^ ((d & 7) << 4)))
            = e16 | (o16 << 16);
      }
    }
    __syncthreads();

    // ---- prefetch next tile (T14: issue before compute, consumed next iter) ----
    {
      int ktn = (kt + 1) & 15;
      size_t kn = nodebase + (size_t)(ktn * 64 + srow) * 768 + head * 32;
      kr = *reinterpret_cast<const uint4*>(qkv + kn + 256 + sc * 8);
      vr = *reinterpret_cast<const uint4*>(qkv + kn + 512 + sc * 8);
      dr = *reinterpret_cast<const uint4*>(dist + (size_t)(g * M + ktn * 64 + srow) * M + q0 + sc * 16);
    }

    // ---- scores: 4 MFMAs ----
    f32x4 s[4];
    unsigned int d4[4];
    #pragma unroll
    for (int fn = 0; fn < 4; ++fn) {
      bf16x8 b = *reinterpret_cast<const bf16x8*>(KsB + (fn * 16 + lr) * 80 + lg * 16);
      s[fn] = __builtin_amdgcn_mfma_f32_16x16x32_bf16(qfrag, b, (f32x4){0.f,0.f,0.f,0.f}, 0, 0, 0);
      d4[fn] = *reinterpret_cast<const unsigned int*>(Ds + (fn * 16 + lr) * 80 + wid * 16 + 4 * lg);
    }
    // p = exp2(s*C1 + bias_log2e) — no max subtraction (bounded inputs)
    #pragma unroll
    for (int fn = 0; fn < 4; ++fn)
      #pragma unroll
      for (int rg = 0; rg < 4; ++rg)
        s[fn][rg] = exp2f(s[fn][rg] * C1 + semb[(d4[fn] >> (8 * rg)) & 255]);
    #pragma unroll
    for (int rg = 0; rg < 4; ++rg)
      lpart[rg] += (s[0][rg] + s[1][rg]) + (s[2][rg] + s[3][rg]);

    // ---- P -> per-wave LDS (bf16) ----
    #pragma unroll
    for (int fn = 0; fn < 4; ++fn)
      #pragma unroll
      for (int rg = 0; rg < 4; ++rg) {
        int qq = 4 * lg + rg, key = fn * 16 + lr;
        *reinterpret_cast<ushort_t*>(pb + qq * 128 + ((key * 2) ^ ((qq & 7) << 4))) =
            (ushort_t)f2b(s[fn][rg]);
      }

    // ---- PV: 4 MFMAs ----
    #pragma unroll
    for (int kh = 0; kh < 2; ++kh) {
      int c = kh * 4 + lg;
      int chx = (c << 4) ^ ((lr & 7) << 4);
      bf16x8 a  = *reinterpret_cast<const bf16x8*>(pb + lr * 128 + chx);
      bf16x8 b0 = *reinterpret_cast<const bf16x8*>(VtB + lr * 128 + ((lr >> 3) << 4) + chx);
      bf16x8 b1 = *reinterpret_cast<const bf16x8*>(VtB + (16 + lr) * 128 + (((16 + lr) >> 3) << 4) + chx);
      o0 = __builtin_amdgcn_mfma_f32_16x16x32_bf16(a, b0, o0, 0, 0, 0);
      o1 = __builtin_amdgcn_mfma_f32_16x16x32_bf16(a, b1, o1, 0, 0, 0);
    }
    __syncthreads();
  }

  // ---- final l reduce (across the 16 lr lanes) + output ----
  #pragma unroll
  for (int rg = 0; rg < 4; ++rg) {
    float l = lpart[rg];
    l += __shfl_xor(l, 1);
    l += __shfl_xor(l, 2);
    l += __shfl_xor(l, 4);
    l += __shfl_xor(l, 8);
    float inv = 1.0f / l;
    size_t qn = (size_t)(g * M + q0 + wid * 16 + 4 * lg + rg);
    attno[qn * H + head * 32 + lr]      = f2b(o0[rg] * inv);
    attno[qn * H + head * 32 + 16 + lr] = f2b(o1[rg] * inv);
  }
}

// ---------------- fused add(2|3) + LayerNorm, wave per row ----------------
__global__ __launch_bounds__(256) void k_ln(const float* __restrict__ a, const float* __restrict__ b,
                                            const float* __restrict__ c3,
                                            const float* __restrict__ gam, const float* __restrict__ bet,
                                            float* __restrict__ out, ushort_t* __restrict__ outb) {
  int wid = threadIdx.x >> 6, lane = threadIdx.x & 63;
  int row = blockIdx.x * 4 + wid;
  size_t base = (size_t)row * H + lane * 4;
  float4 v = *reinterpret_cast<const float4*>(a + base);
  float4 vb = *reinterpret_cast<const float4*>(b + base);
  v.x += vb.x; v.y += vb.y; v.z += vb.z; v.w += vb.w;
  if (c3) {
    float4 vc = *reinterpret_cast<const float4*>(c3 + base);
    v.x += vc.x; v.y += vc.y; v.z += vc.z; v.w += vc.w;
  }
  float s = v.x + v.y + v.z + v.w;
  float s2 = v.x*v.x + v.y*v.y + v.z*v.z + v.w*v.w;
  #pragma unroll
  for (int off = 1; off <= 32; off <<= 1) {
    s  += __shfl_xor(s, off);
    s2 += __shfl_xor(s2, off);
  }
  float mean = s * (1.0f / 256.0f);
  float rstd = rsqrtf(s2 * (1.0f / 256.0f) - mean * mean + 1e-5f);
  float4 gg = *reinterpret_cast<const float4*>(gam + lane * 4);
  float4 bb = *reinterpret_cast<const float4*>(bet + lane * 4);
  float4 r;
  r.x = (v.x - mean) * rstd * gg.x + bb.x;
  r.y = (v.y - mean) * rstd * gg.y + bb.y;
  r.z = (v.z - mean) * rstd * gg.z + bb.z;
  r.w = (v.w - mean) * rstd * gg.w + bb.w;
  *reinterpret_cast<float4*>(out + base) = r;
  if (outb) {
    unsigned int lo = (unsigned int)(ushort_t)f2b(r.x) | ((unsigned int)(ushort_t)f2b(r.y) << 16);
    unsigned int hi = (unsigned int)(ushort_t)f2b(r.z) | ((unsigned int)(ushort_t)f2b(r.w) << 16);
    *reinterpret_cast<uint2*>(outb + base) = make_uint2(lo, hi);
  }
}

// ---------------- launch ----------------
extern "C" void kernel_launch(void* const* d_in, const int* in_sizes, int n_in,
                              void* d_out, int out_size, void* d_ws, size_t ws_size,
                              hipStream_t stream) {
  const float* x      = (const float*)d_in[0];
  const float* gcn_w  = (const float*)d_in[1];
  const float* gcn_b  = (const float*)d_in[2];
  const float* qkv_w  = (const float*)d_in[3];
  const float* qkv_b  = (const float*)d_in[4];
  const float* proj_w = (const float*)d_in[5];
  const float* proj_b = (const float*)d_in[6];
  const float* ln1_g  = (const float*)d_in[7];
  const float* ln1_b  = (const float*)d_in[8];
  const float* ln2_g  = (const float*)d_in[9];
  const float* ln2_b  = (const float*)d_in[10];
  const float* ffn1_w = (const float*)d_in[11];
  const float* ffn1_b = (const float*)d_in[12];
  const float* ffn2_w = (const float*)d_in[13];
  const float* ffn2_b = (const float*)d_in[14];
  const float* bias_e = (const float*)d_in[15];
  const float* oln1_g = (const float*)d_in[16];
  const float* oln1_b = (const float*)d_in[17];
  const float* oln2_g = (const float*)d_in[18];
  const float* oln2_b = (const float*)d_in[19];
  const float* offn1_w= (const float*)d_in[20];
  const float* offn1_b= (const float*)d_in[21];
  const float* offn2_w= (const float*)d_in[22];
  const float* offn2_b= (const float*)d_in[23];
  const int*   eidx   = (const int*)d_in[24];
  const int* esrc = eidx;
  const int* edst = eidx + NE;

  char* wsp = (char*)d_ws;
  size_t off = 0;
  auto alloc = [&](size_t bytes) { void* p = wsp + off; off += (bytes + 255) & ~255ull; return p; };
  const size_t SZ_NH = (size_t)NN * H * 4;
  ushort_t* x_bf  = (ushort_t*)alloc((size_t)NN * H * 2);         // 4MB
  ushort_t* w_bf  = (ushort_t*)alloc((size_t)WB_TOTAL * 2);       // 2.75MB
  float* bias_cat = (float*)alloc(1024 * 4);
  ushort_t* xwb   = (ushort_t*)alloc((size_t)NN * H * 2);         // 4MB
  float* xloc = (float*)alloc(SZ_NH);                             // 8MB
  float* dinv = (float*)alloc((size_t)NN * 4);
  int*   deg  = (int*)  alloc((size_t)NN * 4);                    // ┐ contiguous
  int* cursor = (int*)  alloc((size_t)NN * 4);                    // │ zeroed
  int*  deg2  = (int*)  alloc((size_t)NN * 4);                    // │ together
  int* cursor2= (int*)  alloc((size_t)NN * 4);                    // ┘
  int* starts = (int*)  alloc((size_t)NN * 4);
  int* starts2= (int*)  alloc((size_t)NN * 4);
  int*   csr  = (int*)  alloc((size_t)NE * 4);                    // 0.5MB
  int*   nbr  = (int*)  alloc((size_t)2 * NE * 4);                // 1MB
  u8*    dist = (u8*)   alloc((size_t)NN * M);                    // 8MB  ┐ mid alias
  ushort_t* qkvb = (ushort_t*)alloc((size_t)NN * 768 * 2);        // 12MB ┘ (20MB)
  float* h1   = (float*)alloc(SZ_NH);                             // 8MB
  ushort_t* h1_bf = (ushort_t*)alloc((size_t)NN * H * 2);         // 4MB
  float* f2   = (float*)alloc(SZ_NH);                             // 8MB
  float* h2   = (float*)alloc(SZ_NH);                             // 8MB (also projo before ln2)
  float* y    = (float*)alloc(SZ_NH);                             // 8MB

  ushort_t* attno = x_bf;                  // x_bf dead after gcn+qkv gemm
  float* projo = h2;                       // h2 written at ln2, after projo dead
  ushort_t* mid = (ushort_t*)dist;         // dist+qkvb (20MB) dead after attn; need 16MB
  ushort_t* y_bf = h1_bf;                  // h1_bf dead after ffn1
  float* outp = (float*)d_out;

  ushort_t* proj_wb = w_bf + WB_PROJ;
  ushort_t* ffn1_wb = w_bf + WB_FFN1;
  ushort_t* ffn2_wb = w_bf + WB_FFN2;
  ushort_t* offn1_wb= w_bf + WB_OFFN1;
  ushort_t* offn2_wb= w_bf + WB_OFFN2;

  hipMemsetAsync(deg, 0, (size_t)4 * NN * 4, stream);   // deg,cursor,deg2,cursor2

  // conversions (x, all weights, bias_cat)
  k_cvtall<<<NXBLK + NWBLK + 1, 256, 0, stream>>>(x, gcn_w, qkv_w, proj_w, ffn1_w,
                                                  ffn2_w, offn1_w, offn2_w, qkv_b,
                                                  x_bf, w_bf, bias_cat);

  // --- degrees & CSRs ---
  k_prep<<<NE / 256, 256, 0, stream>>>(esrc, edst, deg, deg2);
  k_scan2<<<2, 1024, 0, stream>>>(deg, deg2, starts, starts2, dinv);
  k_fillb<<<NE / 256, 256, 0, stream>>>(esrc, edst, starts, cursor, csr, starts2, cursor2, nbr);

  // --- merged GCN-xw + QKV GEMM (A = x_bf, W = gcn_w‖qkv_w, O = 1024 split) ---
  k_mgemm<128, 0, 2><<<dim3(1024 / 64, NN / 128), 256, 0, stream>>>(
      (const short*)x_bf, (const short*)w_bf, bias_cat, nullptr, (short*)qkvb, (short*)xwb, 256, 1024);
  k_gather<<<NN, 256, 0, stream>>>(csr, starts, deg, dinv, xwb, gcn_b, xloc);

  // --- SPD distances: single merged kernel (5 levels + decode in LDS) ---
  k_spdm<<<G * 32, 1024, 0, stream>>>(starts2, deg2, nbr, dist);

  // --- Graphormer encoder ---
  k_attn<<<dim3(M / 64, HEADS, G), 256, 0, stream>>>(qkvb, dist, bias_e, (short*)attno);
  k_mgemm<64, 0, 0><<<dim3(256 / 64, NN / 64), 256, 0, stream>>>(
      (const short*)attno, (const short*)proj_wb, proj_b, projo, nullptr, nullptr, 256, 256);
  k_ln<<<NN / 4, 256, 0, stream>>>(x, projo, nullptr, ln1_g, ln1_b, h1, h1_bf);
  k_mgemm<128, 1, 1><<<dim3(FFND / 64, NN / 128), 256, 0, stream>>>(
      (const short*)h1_bf, (const short*)ffn1_wb, ffn1_b, nullptr, (short*)mid, nullptr, 256, FFND);
  k_mgemm<64, 0, 0><<<dim3(256 / 64, NN / 64), 256, 0, stream>>>(
      (const short*)mid, (const short*)ffn2_wb, ffn2_b, f2, nullptr, nullptr, FFND, 256);
  k_ln<<<NN / 4, 256, 0, stream>>>(h1, f2, nullptr, ln2_g, ln2_b, h2, nullptr);

  // --- GPS combine + outer FFN ---
  k_ln<<<NN / 4, 256, 0, stream>>>(x, xloc, h2, oln1_g, oln1_b, y, y_bf);
  k_mgemm<128, 1, 1><<<dim3(FFND / 64, NN / 128), 256, 0, stream>>>(
      (const short*)y_bf, (const short*)offn1_wb, offn1_b, nullptr, (short*)mid, nullptr, 256, FFND);
  k_mgemm<64, 0, 0><<<dim3(256 / 64, NN / 64), 256, 0, stream>>>(
      (const short*)mid, (const short*)offn2_wb, offn2_b, f2, nullptr, nullptr, FFND, 256);
  k_ln<<<NN / 4, 256, 0, stream>>>(y, f2, nullptr, oln2_g, oln2_b, outp, nullptr);
}

// Round 7
// 374.640 us; speedup vs baseline: 4.6671x; 1.0401x over previous
//
#include <hip/hip_runtime.h>
#include <hip/hip_bf16.h>
#include <cstdint>

#define G 8
#define M 1024
#define H 256
#define HEADS 8
#define FFND 1024
#define NE 131072
#define NN (G*M)          // 8192
#define HD 32             // H/HEADS

typedef unsigned long long u64;
typedef uint8_t u8;
typedef unsigned short ushort_t;
typedef __attribute__((ext_vector_type(8))) short bf16x8;
typedef __attribute__((ext_vector_type(4))) float f32x4;

__device__ __forceinline__ short f2b(float v) {
  __hip_bfloat16 h = __float2bfloat16(v);
  return *reinterpret_cast<short*>(&h);
}
__device__ __forceinline__ float b2f(unsigned int u) {
  union { float f; unsigned int i; } v; v.i = u << 16; return v.f;
}

typedef __attribute__((address_space(1))) const void gvoid;
typedef __attribute__((address_space(3))) void lvoid;
__device__ __forceinline__ void gload16(const void* g, void* l) {
  __builtin_amdgcn_global_load_lds((gvoid*)g, (lvoid*)l, 16, 0, 0);
}

// ---------------- fused degree pass ----------------
__global__ void k_prep(const int* __restrict__ srcv, const int* __restrict__ dstv,
                       int* __restrict__ deg, int* __restrict__ deg2) {
  int e = blockIdx.x * 256 + threadIdx.x;
  if (e >= NE) return;
  int d = dstv[e], s = srcv[e];
  atomicAdd(&deg[d], 1);
  if (s != d) { atomicAdd(&deg2[s], 1); atomicAdd(&deg2[d], 1); }
}

// ---------------- dual prefix scan ----------------
__global__ __launch_bounds__(1024) void k_scan2(const int* __restrict__ deg, const int* __restrict__ deg2,
                                                int* __restrict__ starts, int* __restrict__ starts2,
                                                float* __restrict__ dinv) {
  __shared__ int tmp[1024];
  const int* in = blockIdx.x ? deg2 : deg;
  int* outp = blockIdx.x ? starts2 : starts;
  int t = threadIdx.x;
  int base = t * 8;
  int v[8]; int s = 0;
  #pragma unroll
  for (int i = 0; i < 8; ++i) { v[i] = in[base + i]; s += v[i]; }
  if (blockIdx.x == 0) {
    #pragma unroll
    for (int i = 0; i < 8; ++i) dinv[base + i] = rsqrtf((float)(v[i] + 1));
  }
  tmp[t] = s;
  __syncthreads();
  for (int off = 1; off < 1024; off <<= 1) {
    int x = (t >= off) ? tmp[t - off] : 0;
    __syncthreads();
    tmp[t] += x;
    __syncthreads();
  }
  int ex = (t == 0) ? 0 : tmp[t - 1];
  #pragma unroll
  for (int i = 0; i < 8; ++i) { outp[base + i] = ex; ex += v[i]; }
}

// ---------------- fused CSR fills ----------------
__global__ void k_fillb(const int* __restrict__ srcv, const int* __restrict__ dstv,
                        const int* __restrict__ starts, int* __restrict__ cursor,
                        int* __restrict__ csr,
                        const int* __restrict__ starts2, int* __restrict__ cur2,
                        int* __restrict__ nbr) {
  int e = blockIdx.x * 256 + threadIdx.x;
  if (e >= NE) return;
  int d = dstv[e], s = srcv[e];
  int pos = atomicAdd(&cursor[d], 1);
  csr[starts[d] + pos] = s;
  if (s != d) {
    int p = atomicAdd(&cur2[s], 1); nbr[starts2[s] + p] = d;
    p = atomicAdd(&cur2[d], 1);     nbr[starts2[d] + p] = s;
  }
}

// ---------------- CSR gather (GCN) ----------------
__global__ __launch_bounds__(256) void k_gather(const int* __restrict__ csr,
    const int* __restrict__ starts, const int* __restrict__ deg,
    const float* __restrict__ dinv, const ushort_t* __restrict__ xwb,
    const float* __restrict__ gcn_b, float* __restrict__ xloc) {
  int d = blockIdx.x, t = threadIdx.x;
  int s0 = starts[d], cnt = deg[d];
  float acc = 0.f;
  for (int j = 0; j < cnt; ++j) {
    int s = csr[s0 + j];
    acc += dinv[s] * b2f(xwb[(size_t)s * H + t]);
  }
  float di = dinv[d];
  float self = b2f(xwb[(size_t)d * H + t]);
  xloc[(size_t)d * H + t] = di * acc + di * di * self + gcn_b[t];
}

// ---------------- SPD: merged 5-level bitset BFS + dist decode in LDS ----------------
__global__ __launch_bounds__(1024) void k_spdm(const int* __restrict__ starts2,
                                               const int* __restrict__ deg2,
                                               const int* __restrict__ nbr,
                                               u8* __restrict__ dist) {
  __shared__ unsigned int Abuf[1024], Bbuf[1024];
  __shared__ u8 dtile[1024][32];
  const int g = blockIdx.x >> 5, w = blockIdx.x & 31;
  const int i = threadIdx.x;
  const int gi = (g << 10) | i;
  unsigned int self = ((i >> 5) == w) ? (1u << (i & 31)) : 0u;
  Abuf[i] = self;
  uint4 six; six.x = six.y = six.z = six.w = 0x06060606u;
  *reinterpret_cast<uint4*>(&dtile[i][0])  = six;
  *reinterpret_cast<uint4*>(&dtile[i][16]) = six;
  if (self) dtile[i][i & 31] = 0;
  const int s0 = starts2[gi], cnt = deg2[gi];
  unsigned int* prev = Abuf;
  unsigned int* cur  = Bbuf;
  unsigned int vis = self;
  __syncthreads();
  for (int l = 1; l <= 5; ++l) {
    unsigned int acc = vis;
    for (int e = 0; e < cnt; ++e)
      acc |= prev[nbr[s0 + e] & 1023];
    unsigned int newly = acc & ~vis;
    while (newly) {
      int k = __ffs(newly) - 1;
      newly &= newly - 1;
      dtile[i][k] = (u8)l;
    }
    cur[i] = acc;
    vis = acc;
    __syncthreads();
    unsigned int* tsw = prev; prev = cur; cur = tsw;
  }
  u8* drow = dist + ((size_t)gi << 10) + w * 32;
  *reinterpret_cast<uint4*>(drow)      = *reinterpret_cast<const uint4*>(&dtile[i][0]);
  *reinterpret_cast<uint4*>(drow + 16) = *reinterpret_cast<const uint4*>(&dtile[i][16]);
}

// ---------------- fused fp32->bf16 conversions + bias_cat ----------------
#define WB_GCN   0
#define WB_QKV   65536
#define WB_PROJ  262144
#define WB_FFN1  327680
#define WB_FFN2  589824
#define WB_OFFN1 851968
#define WB_OFFN2 1114112
#define WB_TOTAL 1376256
#define NXBLK 2048
#define NWBLK 5376

__global__ void k_cvtall(const float* __restrict__ x,
                         const float* p0, const float* p1, const float* p2,
                         const float* p3, const float* p4, const float* p5, const float* p6,
                         const float* __restrict__ qkv_b,
                         ushort_t* __restrict__ x_bf, ushort_t* __restrict__ w_bf,
                         float* __restrict__ bias_cat) {
  int bid = blockIdx.x, t = threadIdx.x;
  if (bid < NXBLK) {
    int i = bid * 256 + t;
    float4 v = reinterpret_cast<const float4*>(x)[i];
    unsigned int lo = (unsigned int)(ushort_t)f2b(v.x) | ((unsigned int)(ushort_t)f2b(v.y) << 16);
    unsigned int hi = (unsigned int)(ushort_t)f2b(v.z) | ((unsigned int)(ushort_t)f2b(v.w) << 16);
    reinterpret_cast<uint2*>(x_bf)[i] = make_uint2(lo, hi);
  } else if (bid < NXBLK + NWBLK) {
    int i = (bid - NXBLK) * 256 + t;
    const float* src; int off;
    if (i < WB_QKV)        { src = p0; off = i; }
    else if (i < WB_PROJ)  { src = p1; off = i - WB_QKV; }
    else if (i < WB_FFN1)  { src = p2; off = i - WB_PROJ; }
    else if (i < WB_FFN2)  { src = p3; off = i - WB_FFN1; }
    else if (i < WB_OFFN1) { src = p4; off = i - WB_FFN2; }
    else if (i < WB_OFFN2) { src = p5; off = i - WB_OFFN1; }
    else                   { src = p6; off = i - WB_OFFN2; }
    w_bf[i] = (ushort_t)f2b(src[off]);
  } else {
    for (int i = t; i < 1024; i += 256) bias_cat[i] = (i < 256) ? 0.f : qkv_b[i - 256];
  }
}

// ---------------- bf16 MFMA GEMM (BM x 64 tiles) ----------------
// OMODE: 1 = bf16 out, 2 = split (cols<256 -> Cb2 stride 256, else Cb stride 768 col-256)
template<int BM, int ACT, int OMODE>
__global__ __launch_bounds__(256) void k_mgemm(const short* __restrict__ A,
                                               const short* __restrict__ W,
                                               const float* __restrict__ bias,
                                               short* __restrict__ Cb,
                                               short* __restrict__ Cb2,
                                               int K, int O) {
  constexpr int FM = BM / 32;
  __shared__ __attribute__((aligned(16))) short As[BM * 64];
  __shared__ __attribute__((aligned(16))) short Ws[64 * 64];
  const int tid = threadIdx.x;
  const int lane = tid & 63, wbase = tid & 192;
  const int wid = tid >> 6;
  const int lg = lane >> 4, lr = lane & 15;
  const int wm = wid >> 1, wn = wid & 1;
  const int m0 = blockIdx.y * BM, n0 = blockIdx.x * 64;
  f32x4 acc[FM][2];
  #pragma unroll
  for (int i = 0; i < FM; ++i)
    #pragma unroll
    for (int j = 0; j < 2; ++j)
      acc[i][j] = (f32x4){0.f, 0.f, 0.f, 0.f};

  for (int k0 = 0; k0 < K; k0 += 64) {
    #pragma unroll
    for (int c = 0; c < BM / 32; ++c) {
      int chunk = c * 256 + tid;
      int row = chunk >> 3, ks = chunk & 7;
      int srcks = ks ^ (row & 7);
      gload16(A + (size_t)(m0 + row) * K + k0 + srcks * 8,
              (char*)As + (c * 256 + wbase) * 16);
    }
    #pragma unroll
    for (int c = 0; c < 2; ++c) {
      int chunk = c * 256 + tid;
      int row = chunk >> 3, ks = chunk & 7;
      int srcks = ks ^ (row & 7);
      gload16(W + (size_t)(n0 + row) * K + k0 + srcks * 8,
              (char*)Ws + (c * 256 + wbase) * 16);
    }
    __syncthreads();
    #pragma unroll
    for (int kk = 0; kk < 2; ++kk) {
      const int d = kk * 4 + lg;
      bf16x8 b[2];
      #pragma unroll
      for (int fn = 0; fn < 2; ++fn) {
        int r = wn * 32 + fn * 16 + lr;
        b[fn] = *reinterpret_cast<const bf16x8*>((const char*)Ws + r * 128 + ((d ^ (r & 7)) * 16));
      }
      #pragma unroll
      for (int fm = 0; fm < FM; ++fm) {
        int r = wm * (BM / 2) + fm * 16 + lr;
        bf16x8 a = *reinterpret_cast<const bf16x8*>((const char*)As + r * 128 + ((d ^ (r & 7)) * 16));
        acc[fm][0] = __builtin_amdgcn_mfma_f32_16x16x32_bf16(a, b[0], acc[fm][0], 0, 0, 0);
        acc[fm][1] = __builtin_amdgcn_mfma_f32_16x16x32_bf16(a, b[1], acc[fm][1], 0, 0, 0);
      }
    }
    __syncthreads();
  }
  #pragma unroll
  for (int fm = 0; fm < FM; ++fm)
    #pragma unroll
    for (int fn = 0; fn < 2; ++fn)
      #pragma unroll
      for (int rg = 0; rg < 4; ++rg) {
        int r = m0 + wm * (BM / 2) + fm * 16 + lg * 4 + rg;
        int cc = n0 + wn * 32 + fn * 16 + lr;
        float v = acc[fm][fn][rg] + (bias ? bias[cc] : 0.f);
        if (ACT == 1) v = 0.5f * v * (1.0f + erff(v * 0.70710678118654752f));
        if (OMODE == 1) Cb[(size_t)r * O + cc] = f2b(v);
        else {
          if (cc < 256) Cb2[(size_t)r * 256 + cc] = f2b(v);
          else          Cb[(size_t)r * 768 + cc - 256] = f2b(v);
        }
      }
}

// ---------------- GEMM (O=256 full row) + residual + LayerNorm fused ----------------
// BM=32, BN=256, grid NN/32=256. 4 waves: wave owns cols wid*64..+63 (4 col frags, 2 row frags).
template<int KK, int OUTB>
__global__ __launch_bounds__(256) void k_gemmln(const short* __restrict__ A,
                                                const short* __restrict__ W,
                                                const float* __restrict__ bias,
                                                const float* __restrict__ res1,
                                                const float* __restrict__ gam,
                                                const float* __restrict__ bet,
                                                float* __restrict__ outf,
                                                ushort_t* __restrict__ outb) {
  __shared__ __attribute__((aligned(16))) short As[32 * 64];
  __shared__ __attribute__((aligned(16))) short Ws[256 * 64];
  __shared__ float redS[4][32], redQ[4][32];
  const int tid = threadIdx.x, lane = tid & 63, wid = tid >> 6;
  const int wbase = tid & 192;
  const int lg = lane >> 4, lr = lane & 15;
  const int m0 = blockIdx.x * 32;
  f32x4 acc[2][4];
  #pragma unroll
  for (int i = 0; i < 2; ++i)
    #pragma unroll
    for (int j = 0; j < 4; ++j)
      acc[i][j] = (f32x4){0.f, 0.f, 0.f, 0.f};

  for (int k0 = 0; k0 < KK; k0 += 64) {
    {  // A tile 32x64: 256 chunks, 1 per thread
      int row = tid >> 3, ks = tid & 7, srcks = ks ^ (row & 7);
      gload16(A + (size_t)(m0 + row) * KK + k0 + srcks * 8,
              (char*)As + wbase * 16);
    }
    #pragma unroll
    for (int c = 0; c < 8; ++c) {  // W tile 256x64: 2048 chunks
      int chunk = c * 256 + tid;
      int row = chunk >> 3, ks = chunk & 7;
      int srcks = ks ^ (row & 7);
      gload16(W + (size_t)row * KK + k0 + srcks * 8,
              (char*)Ws + (c * 256 + wbase) * 16);
    }
    __syncthreads();
    #pragma unroll
    for (int kk = 0; kk < 2; ++kk) {
      const int d = kk * 4 + lg;
      bf16x8 a[2];
      #pragma unroll
      for (int fr = 0; fr < 2; ++fr) {
        int r = fr * 16 + lr;
        a[fr] = *reinterpret_cast<const bf16x8*>((const char*)As + r * 128 + ((d ^ (r & 7)) * 16));
      }
      #pragma unroll
      for (int fc = 0; fc < 4; ++fc) {
        int r = wid * 64 + fc * 16 + lr;
        bf16x8 b = *reinterpret_cast<const bf16x8*>((const char*)Ws + r * 128 + ((d ^ (r & 7)) * 16));
        acc[0][fc] = __builtin_amdgcn_mfma_f32_16x16x32_bf16(a[0], b, acc[0][fc], 0, 0, 0);
        acc[1][fc] = __builtin_amdgcn_mfma_f32_16x16x32_bf16(a[1], b, acc[1][fc], 0, 0, 0);
      }
    }
    __syncthreads();
  }

  // epilogue: bias + residual, row stats, LN, write
  float vs[2][4][4];
  float ps[2][4], pq[2][4];
  #pragma unroll
  for (int fr = 0; fr < 2; ++fr)
    #pragma unroll
    for (int rg = 0; rg < 4; ++rg) { ps[fr][rg] = 0.f; pq[fr][rg] = 0.f; }
  #pragma unroll
  for (int fc = 0; fc < 4; ++fc) {
    int col = wid * 64 + fc * 16 + lr;
    float bv = bias[col];
    #pragma unroll
    for (int fr = 0; fr < 2; ++fr)
      #pragma unroll
      for (int rg = 0; rg < 4; ++rg) {
        int row = m0 + fr * 16 + 4 * lg + rg;
        float v = acc[fr][fc][rg] + bv + res1[(size_t)row * 256 + col];
        vs[fr][fc][rg] = v;
        ps[fr][rg] += v; pq[fr][rg] += v * v;
      }
  }
  #pragma unroll
  for (int fr = 0; fr < 2; ++fr)
    #pragma unroll
    for (int rg = 0; rg < 4; ++rg) {
      float s = ps[fr][rg], q = pq[fr][rg];
      s += __shfl_xor(s, 1); q += __shfl_xor(q, 1);
      s += __shfl_xor(s, 2); q += __shfl_xor(q, 2);
      s += __shfl_xor(s, 4); q += __shfl_xor(q, 4);
      s += __shfl_xor(s, 8); q += __shfl_xor(q, 8);
      ps[fr][rg] = s; pq[fr][rg] = q;
    }
  if (lr == 0) {
    #pragma unroll
    for (int fr = 0; fr < 2; ++fr)
      #pragma unroll
      for (int rg = 0; rg < 4; ++rg) {
        redS[wid][fr * 16 + 4 * lg + rg] = ps[fr][rg];
        redQ[wid][fr * 16 + 4 * lg + rg] = pq[fr][rg];
      }
  }
  __syncthreads();
  #pragma unroll
  for (int fr = 0; fr < 2; ++fr)
    #pragma unroll
    for (int rg = 0; rg < 4; ++rg) {
      int rl = fr * 16 + 4 * lg + rg;
      float S = redS[0][rl] + redS[1][rl] + redS[2][rl] + redS[3][rl];
      float Q = redQ[0][rl] + redQ[1][rl] + redQ[2][rl] + redQ[3][rl];
      float mean = S * (1.0f / 256.0f);
      float rstd = rsqrtf(Q * (1.0f / 256.0f) - mean * mean + 1e-5f);
      #pragma unroll
      for (int fc = 0; fc < 4; ++fc) {
        int col = wid * 64 + fc * 16 + lr;
        float v = (vs[fr][fc][rg] - mean) * rstd * gam[col] + bet[col];
        size_t o = (size_t)(m0 + rl) * 256 + col;
        outf[o] = v;
        if (OUTB) outb[o] = (ushort_t)f2b(v);
      }
    }
}

// ---------------- MFMA flash attention with SPD bias ----------------
// Dense key-pair packed Ks/Ds: row8 = key>>1 (128B rows), slot = chunk ^ (row8&7).
// Stores are lane-contiguous (conflict-free); reads 2-way max.
__global__ __launch_bounds__(256) void k_attn(const ushort_t* __restrict__ qkv,
                                              const u8* __restrict__ dist,
                                              const float* __restrict__ emb,
                                              short* __restrict__ attno) {
  __shared__ __attribute__((aligned(16))) char KsB[32 * 128];     // K packed: [key>>1][8 slots x16B]
  __shared__ __attribute__((aligned(16))) char VtB[32 * 128 + 64];// V^T: byte(d,key)=d*128+(d>>3)*16+((key*2)^((d&7)<<4))
  __shared__ __attribute__((aligned(16))) char PB[4][16 * 128];   // per-wave P: byte(q,key)=q*128+((key*2)^((q&7)<<4))
  __shared__ __attribute__((aligned(16))) u8 Ds[32 * 128];        // dist^T packed like Ks (dist symmetric)
  __shared__ float semb[8];
  const int g = blockIdx.z, head = blockIdx.y;
  const int q0 = blockIdx.x * 64;
  const int t = threadIdx.x, lane = t & 63, wid = t >> 6;
  const int lg = lane >> 4, lr = lane & 15;
  if (t < 7) semb[t] = emb[t] * 1.44269504088896341f;
  const size_t nodebase = (size_t)(g * M) * 768;
  const float C1 = 0.17677669529663687f * 1.44269504088896341f;  // HD^-0.5 * log2(e)

  bf16x8 qfrag = *reinterpret_cast<const bf16x8*>(
      qkv + nodebase + (size_t)(q0 + wid * 16 + lr) * 768 + head * 32 + lg * 8);

  const int srow = t >> 2, sc = t & 3;
  const int prow8 = t >> 3, pslot = (t & 7) ^ (prow8 & 7);   // packed store indices
  uint4 kr, vr, dr;
  {
    size_t kn = nodebase + (size_t)(srow) * 768 + head * 32;
    kr = *reinterpret_cast<const uint4*>(qkv + kn + 256 + sc * 8);
    vr = *reinterpret_cast<const uint4*>(qkv + kn + 512 + sc * 8);
    dr = *reinterpret_cast<const uint4*>(dist + (size_t)(g * M + srow) * M + q0 + sc * 16);
  }

  f32x4 o0 = {0.f, 0.f, 0.f, 0.f}, o1 = {0.f, 0.f, 0.f, 0.f};
  float lpart[4] = {0.f, 0.f, 0.f, 0.f};
  char* pb = PB[wid];
  const int kp = srow >> 1;
  const int odd = srow & 1;
  const int d0 = sc * 8;
  // precomputed read indices (per fn)
  int r8f[4], slK[4], slD[4];
  #pragma unroll
  for (int fn = 0; fn < 4; ++fn) {
    r8f[fn] = fn * 8 + (lr >> 1);
    slK[fn] = (((lr & 1) << 2) | lg) ^ (r8f[fn] & 7);
    slD[fn] = (((lr & 1) << 2) | wid) ^ (r8f[fn] & 7);
  }

  for (int kt = 0; kt < 16; ++kt) {
    // ---- store staged regs (lane-contiguous packed layout) ----
    *reinterpret_cast<uint4*>(KsB + prow8 * 128 + pslot * 16) = kr;
    *reinterpret_cast<uint4*>(Ds + prow8 * 128 + pslot * 16) = dr;
    // V^T: pair with partner holding key^1 (lane t^4), pack 2 keys per u32
    {
      uint4 pvr;
      pvr.x = (unsigned int)__shfl_xor((int)vr.x, 4);
      pvr.y = (unsigned int)__shfl_xor((int)vr.y, 4);
      pvr.z = (unsigned int)__shfl_xor((int)vr.z, 4);
      pvr.w = (unsigned int)__shfl_xor((int)vr.w, 4);
      unsigned int ev[4], ov[4];
      ev[0] = odd ? pvr.x : vr.x; ev[1] = odd ? pvr.y : vr.y;
      ev[2] = odd ? pvr.z : vr.z; ev[3] = odd ? pvr.w : vr.w;
      ov[0] = odd ? vr.x : pvr.x; ov[1] = odd ? vr.y : pvr.y;
      ov[2] = odd ? vr.z : pvr.z; ov[3] = odd ? vr.w : pvr.w;
      #pragma unroll
      for (int di = 0; di < 4; ++di) {
        int dd = odd * 4 + di;
        int d = d0 + dd;
        unsigned int e16 = (dd & 1) ? (ev[dd >> 1] >> 16) : (ev[dd >> 1] & 0xffff);
        unsigned int o16 = (dd & 1) ? (ov[dd >> 1] >> 16) : (ov[dd >> 1] & 0xffff);
        *reinterpret_cast<unsigned int*>(VtB + d * 128 + ((d >> 3) << 4) + ((kp << 2) ^ ((d & 7) << 4)))
            = e16 | (o16 << 16);
      }
    }
    __syncthreads();

    // ---- prefetch next tile ----
    {
      int ktn = (kt + 1) & 15;
      size_t kn = nodebase + (size_t)(ktn * 64 + srow) * 768 + head * 32;
      kr = *reinterpret_cast<const uint4*>(qkv + kn + 256 + sc * 8);
      vr = *reinterpret_cast<const uint4*>(qkv + kn + 512 + sc * 8);
      dr = *reinterpret_cast<const uint4*>(dist + (size_t)(g * M + ktn * 64 + srow) * M + q0 + sc * 16);
    }

    // ---- scores: 4 MFMAs ----
    f32x4 s[4];
    unsigned int d4[4];
    #pragma unroll
    for (int fn = 0; fn < 4; ++fn) {
      bf16x8 b = *reinterpret_cast<const bf16x8*>(KsB + r8f[fn] * 128 + slK[fn] * 16);
      s[fn] = __builtin_amdgcn_mfma_f32_16x16x32_bf16(qfrag, b, (f32x4){0.f,0.f,0.f,0.f}, 0, 0, 0);
      d4[fn] = *reinterpret_cast<const unsigned int*>(Ds + r8f[fn] * 128 + slD[fn] * 16 + 4 * lg);
    }
    #pragma unroll
    for (int fn = 0; fn < 4; ++fn)
      #pragma unroll
      for (int rg = 0; rg < 4; ++rg)
        s[fn][rg] = exp2f(s[fn][rg] * C1 + semb[(d4[fn] >> (8 * rg)) & 255]);
    #pragma unroll
    for (int rg = 0; rg < 4; ++rg)
      lpart[rg] += (s[0][rg] + s[1][rg]) + (s[2][rg] + s[3][rg]);

    // ---- P -> per-wave LDS (bf16) ----
    #pragma unroll
    for (int fn = 0; fn < 4; ++fn)
      #pragma unroll
      for (int rg = 0; rg < 4; ++rg) {
        int qq = 4 * lg + rg, key = fn * 16 + lr;
        *reinterpret_cast<ushort_t*>(pb + qq * 128 + ((key * 2) ^ ((qq & 7) << 4))) =
            (ushort_t)f2b(s[fn][rg]);
      }

    // ---- PV: 4 MFMAs ----
    #pragma unroll
    for (int kh = 0; kh < 2; ++kh) {
      int c = kh * 4 + lg;
      int chx = (c << 4) ^ ((lr & 7) << 4);
      bf16x8 a  = *reinterpret_cast<const bf16x8*>(pb + lr * 128 + chx);
      bf16x8 b0 = *reinterpret_cast<const bf16x8*>(VtB + lr * 128 + ((lr >> 3) << 4) + chx);
      bf16x8 b1 = *reinterpret_cast<const bf16x8*>(VtB + (16 + lr) * 128 + (((16 + lr) >> 3) << 4) + chx);
      o0 = __builtin_amdgcn_mfma_f32_16x16x32_bf16(a, b0, o0, 0, 0, 0);
      o1 = __builtin_amdgcn_mfma_f32_16x16x32_bf16(a, b1, o1, 0, 0, 0);
    }
    __syncthreads();
  }

  // ---- final l reduce + output ----
  #pragma unroll
  for (int rg = 0; rg < 4; ++rg) {
    float l = lpart[rg];
    l += __shfl_xor(l, 1);
    l += __shfl_xor(l, 2);
    l += __shfl_xor(l, 4);
    l += __shfl_xor(l, 8);
    float inv = 1.0f / l;
    size_t qn = (size_t)(g * M + q0 + wid * 16 + 4 * lg + rg);
    attno[qn * H + head * 32 + lr]      = f2b(o0[rg] * inv);
    attno[qn * H + head * 32 + 16 + lr] = f2b(o1[rg] * inv);
  }
}

// ---------------- fused add3 + LayerNorm, wave per row (oln1) ----------------
__global__ __launch_bounds__(256) void k_ln(const float* __restrict__ a, const float* __restrict__ b,
                                            const float* __restrict__ c3,
                                            const float* __restrict__ gam, const float* __restrict__ bet,
                                            float* __restrict__ out, ushort_t* __restrict__ outb) {
  int wid = threadIdx.x >> 6, lane = threadIdx.x & 63;
  int row = blockIdx.x * 4 + wid;
  size_t base = (size_t)row * H + lane * 4;
  float4 v = *reinterpret_cast<const float4*>(a + base);
  float4 vb = *reinterpret_cast<const float4*>(b + base);
  v.x += vb.x; v.y += vb.y; v.z += vb.z; v.w += vb.w;
  if (c3) {
    float4 vc = *reinterpret_cast<const float4*>(c3 + base);
    v.x += vc.x; v.y += vc.y; v.z += vc.z; v.w += vc.w;
  }
  float s = v.x + v.y + v.z + v.w;
  float s2 = v.x*v.x + v.y*v.y + v.z*v.z + v.w*v.w;
  #pragma unroll
  for (int off = 1; off <= 32; off <<= 1) {
    s  += __shfl_xor(s, off);
    s2 += __shfl_xor(s2, off);
  }
  float mean = s * (1.0f / 256.0f);
  float rstd = rsqrtf(s2 * (1.0f / 256.0f) - mean * mean + 1e-5f);
  float4 gg = *reinterpret_cast<const float4*>(gam + lane * 4);
  float4 bb = *reinterpret_cast<const float4*>(bet + lane * 4);
  float4 r;
  r.x = (v.x - mean) * rstd * gg.x + bb.x;
  r.y = (v.y - mean) * rstd * gg.y + bb.y;
  r.z = (v.z - mean) * rstd * gg.z + bb.z;
  r.w = (v.w - mean) * rstd * gg.w + bb.w;
  *reinterpret_cast<float4*>(out + base) = r;
  if (outb) {
    unsigned int lo = (unsigned int)(ushort_t)f2b(r.x) | ((unsigned int)(ushort_t)f2b(r.y) << 16);
    unsigned int hi = (unsigned int)(ushort_t)f2b(r.z) | ((unsigned int)(ushort_t)f2b(r.w) << 16);
    *reinterpret_cast<uint2*>(outb + base) = make_uint2(lo, hi);
  }
}

// ---------------- launch ----------------
extern "C" void kernel_launch(void* const* d_in, const int* in_sizes, int n_in,
                              void* d_out, int out_size, void* d_ws, size_t ws_size,
                              hipStream_t stream) {
  const float* x      = (const float*)d_in[0];
  const float* gcn_w  = (const float*)d_in[1];
  const float* gcn_b  = (const float*)d_in[2];
  const float* qkv_w  = (const float*)d_in[3];
  const float* qkv_b  = (const float*)d_in[4];
  const float* proj_w = (const float*)d_in[5];
  const float* proj_b = (const float*)d_in[6];
  const float* ln1_g  = (const float*)d_in[7];
  const float* ln1_b  = (const float*)d_in[8];
  const float* ln2_g  = (const float*)d_in[9];
  const float* ln2_b  = (const float*)d_in[10];
  const float* ffn1_w = (const float*)d_in[11];
  const float* ffn1_b = (const float*)d_in[12];
  const float* ffn2_w = (const float*)d_in[13];
  const float* ffn2_b = (const float*)d_in[14];
  const float* bias_e = (const float*)d_in[15];
  const float* oln1_g = (const float*)d_in[16];
  const float* oln1_b = (const float*)d_in[17];
  const float* oln2_g = (const float*)d_in[18];
  const float* oln2_b = (const float*)d_in[19];
  const float* offn1_w= (const float*)d_in[20];
  const float* offn1_b= (const float*)d_in[21];
  const float* offn2_w= (const float*)d_in[22];
  const float* offn2_b= (const float*)d_in[23];
  const int*   eidx   = (const int*)d_in[24];
  const int* esrc = eidx;
  const int* edst = eidx + NE;

  char* wsp = (char*)d_ws;
  size_t off = 0;
  auto alloc = [&](size_t bytes) { void* p = wsp + off; off += (bytes + 255) & ~255ull; return p; };
  const size_t SZ_NH = (size_t)NN * H * 4;
  ushort_t* x_bf  = (ushort_t*)alloc((size_t)NN * H * 2);         // 4MB
  ushort_t* w_bf  = (ushort_t*)alloc((size_t)WB_TOTAL * 2);       // 2.75MB
  float* bias_cat = (float*)alloc(1024 * 4);
  ushort_t* xwb   = (ushort_t*)alloc((size_t)NN * H * 2);         // 4MB
  float* xloc = (float*)alloc(SZ_NH);                             // 8MB
  float* dinv = (float*)alloc((size_t)NN * 4);
  int*   deg  = (int*)  alloc((size_t)NN * 4);                    // zeroed together
  int* cursor = (int*)  alloc((size_t)NN * 4);
  int*  deg2  = (int*)  alloc((size_t)NN * 4);
  int* cursor2= (int*)  alloc((size_t)NN * 4);
  int* starts = (int*)  alloc((size_t)NN * 4);
  int* starts2= (int*)  alloc((size_t)NN * 4);
  int*   csr  = (int*)  alloc((size_t)NE * 4);                    // 0.5MB
  int*   nbr  = (int*)  alloc((size_t)2 * NE * 4);                // 1MB
  u8*    dist = (u8*)   alloc((size_t)NN * M);                    // 8MB  ┐ mid alias
  ushort_t* qkvb = (ushort_t*)alloc((size_t)NN * 768 * 2);        // 12MB ┘
  float* h1   = (float*)alloc(SZ_NH);                             // 8MB
  ushort_t* h1_bf = (ushort_t*)alloc((size_t)NN * H * 2);         // 4MB
  float* h2   = (float*)alloc(SZ_NH);                             // 8MB
  float* y    = (float*)alloc(SZ_NH);                             // 8MB

  ushort_t* attno = x_bf;                  // x_bf dead after merged gemm
  ushort_t* mid = (ushort_t*)dist;         // dist+qkvb (20MB) dead after attn; need 16MB
  ushort_t* y_bf = h1_bf;                  // h1_bf dead after ffn1
  float* outp = (float*)d_out;

  ushort_t* proj_wb = w_bf + WB_PROJ;
  ushort_t* ffn1_wb = w_bf + WB_FFN1;
  ushort_t* ffn2_wb = w_bf + WB_FFN2;
  ushort_t* offn1_wb= w_bf + WB_OFFN1;
  ushort_t* offn2_wb= w_bf + WB_OFFN2;

  hipMemsetAsync(deg, 0, (size_t)4 * NN * 4, stream);

  k_cvtall<<<NXBLK + NWBLK + 1, 256, 0, stream>>>(x, gcn_w, qkv_w, proj_w, ffn1_w,
                                                  ffn2_w, offn1_w, offn2_w, qkv_b,
                                                  x_bf, w_bf, bias_cat);

  // --- degrees & CSRs ---
  k_prep<<<NE / 256, 256, 0, stream>>>(esrc, edst, deg, deg2);
  k_scan2<<<2, 1024, 0, stream>>>(deg, deg2, starts, starts2, dinv);
  k_fillb<<<NE / 256, 256, 0, stream>>>(esrc, edst, starts, cursor, csr, starts2, cursor2, nbr);

  // --- merged GCN-xw + QKV GEMM ---
  k_mgemm<128, 0, 2><<<dim3(1024 / 64, NN / 128), 256, 0, stream>>>(
      (const short*)x_bf, (const short*)w_bf, bias_cat, (short*)qkvb, (short*)xwb, 256, 1024);
  k_gather<<<NN, 256, 0, stream>>>(csr, starts, deg, dinv, xwb, gcn_b, xloc);

  // --- SPD distances ---
  k_spdm<<<G * 32, 1024, 0, stream>>>(starts2, deg2, nbr, dist);

  // --- Graphormer encoder ---
  k_attn<<<dim3(M / 64, HEADS, G), 256, 0, stream>>>(qkvb, dist, bias_e, (short*)attno);
  k_gemmln<256, 1><<<NN / 32, 256, 0, stream>>>(
      (const short*)attno, (const short*)proj_wb, proj_b, x, ln1_g, ln1_b, h1, h1_bf);
  k_mgemm<128, 1, 1><<<dim3(FFND / 64, NN / 128), 256, 0, stream>>>(
      (const short*)h1_bf, (const short*)ffn1_wb, ffn1_b, (short*)mid, nullptr, 256, FFND);
  k_gemmln<1024, 0><<<NN / 32, 256, 0, stream>>>(
      (const short*)mid, (const short*)ffn2_wb, ffn2_b, h1, ln2_g, ln2_b, h2, nullptr);

  // --- GPS combine + outer FFN ---
  k_ln<<<NN / 4, 256, 0, stream>>>(x, xloc, h2, oln1_g, oln1_b, y, y_bf);
  k_mgemm<128, 1, 1><<<dim3(FFND / 64, NN / 128), 256, 0, stream>>>(
      (const short*)y_bf, (const short*)offn1_wb, offn1_b, (short*)mid, nullptr, 256, FFND);
  k_gemmln<1024, 0><<<NN / 32, 256, 0, stream>>>(
      (const short*)mid, (const short*)offn2_wb, offn2_b, y, oln2_g, oln2_b, outp, nullptr);
}

// Round 8
// 361.168 us; speedup vs baseline: 4.8412x; 1.0373x over previous
//
#include <hip/hip_runtime.h>
#include <hip/hip_bf16.h>
#include <cstdint>

#define G 8
#define M 1024
#define H 256
#define HEADS 8
#define FFND 1024
#define NE 131072
#define NN (G*M)          // 8192
#define HD 32             // H/HEADS

typedef unsigned long long u64;
typedef uint8_t u8;
typedef unsigned short ushort_t;
typedef __attribute__((ext_vector_type(8))) short bf16x8;
typedef __attribute__((ext_vector_type(4))) float f32x4;

__device__ __forceinline__ short f2b(float v) {
  __hip_bfloat16 h = __float2bfloat16(v);
  return *reinterpret_cast<short*>(&h);
}
__device__ __forceinline__ float b2f(unsigned int u) {
  union { float f; unsigned int i; } v; v.i = u << 16; return v.f;
}

typedef __attribute__((address_space(1))) const void gvoid;
typedef __attribute__((address_space(3))) void lvoid;
__device__ __forceinline__ void gload16(const void* g, void* l) {
  __builtin_amdgcn_global_load_lds((gvoid*)g, (lvoid*)l, 16, 0, 0);
}

// ---------------- fused degree pass ----------------
__global__ void k_prep(const int* __restrict__ srcv, const int* __restrict__ dstv,
                       int* __restrict__ deg, int* __restrict__ deg2) {
  int e = blockIdx.x * 256 + threadIdx.x;
  if (e >= NE) return;
  int d = dstv[e], s = srcv[e];
  atomicAdd(&deg[d], 1);
  if (s != d) { atomicAdd(&deg2[s], 1); atomicAdd(&deg2[d], 1); }
}

// ---------------- dual prefix scan ----------------
__global__ __launch_bounds__(1024) void k_scan2(const int* __restrict__ deg, const int* __restrict__ deg2,
                                                int* __restrict__ starts, int* __restrict__ starts2,
                                                float* __restrict__ dinv) {
  __shared__ int tmp[1024];
  const int* in = blockIdx.x ? deg2 : deg;
  int* outp = blockIdx.x ? starts2 : starts;
  int t = threadIdx.x;
  int base = t * 8;
  int v[8]; int s = 0;
  #pragma unroll
  for (int i = 0; i < 8; ++i) { v[i] = in[base + i]; s += v[i]; }
  if (blockIdx.x == 0) {
    #pragma unroll
    for (int i = 0; i < 8; ++i) dinv[base + i] = rsqrtf((float)(v[i] + 1));
  }
  tmp[t] = s;
  __syncthreads();
  for (int off = 1; off < 1024; off <<= 1) {
    int x = (t >= off) ? tmp[t - off] : 0;
    __syncthreads();
    tmp[t] += x;
    __syncthreads();
  }
  int ex = (t == 0) ? 0 : tmp[t - 1];
  #pragma unroll
  for (int i = 0; i < 8; ++i) { outp[base + i] = ex; ex += v[i]; }
}

// ---------------- fused CSR fills ----------------
__global__ void k_fillb(const int* __restrict__ srcv, const int* __restrict__ dstv,
                        const int* __restrict__ starts, int* __restrict__ cursor,
                        int* __restrict__ csr,
                        const int* __restrict__ starts2, int* __restrict__ cur2,
                        int* __restrict__ nbr) {
  int e = blockIdx.x * 256 + threadIdx.x;
  if (e >= NE) return;
  int d = dstv[e], s = srcv[e];
  int pos = atomicAdd(&cursor[d], 1);
  csr[starts[d] + pos] = s;
  if (s != d) {
    int p = atomicAdd(&cur2[s], 1); nbr[starts2[s] + p] = d;
    p = atomicAdd(&cur2[d], 1);     nbr[starts2[d] + p] = s;
  }
}

// ---------------- CSR gather (GCN) ----------------
__global__ __launch_bounds__(256) void k_gather(const int* __restrict__ csr,
    const int* __restrict__ starts, const int* __restrict__ deg,
    const float* __restrict__ dinv, const ushort_t* __restrict__ xwb,
    const float* __restrict__ gcn_b, float* __restrict__ xloc) {
  int d = blockIdx.x, t = threadIdx.x;
  int s0 = starts[d], cnt = deg[d];
  float acc = 0.f;
  for (int j = 0; j < cnt; ++j) {
    int s = csr[s0 + j];
    acc += dinv[s] * b2f(xwb[(size_t)s * H + t]);
  }
  float di = dinv[d];
  float self = b2f(xwb[(size_t)d * H + t]);
  xloc[(size_t)d * H + t] = di * acc + di * di * self + gcn_b[t];
}

// ---------------- SPD: merged 5-level bitset BFS + dist decode in LDS ----------------
__global__ __launch_bounds__(1024) void k_spdm(const int* __restrict__ starts2,
                                               const int* __restrict__ deg2,
                                               const int* __restrict__ nbr,
                                               u8* __restrict__ dist) {
  __shared__ unsigned int Abuf[1024], Bbuf[1024];
  __shared__ u8 dtile[1024][32];
  const int g = blockIdx.x >> 5, w = blockIdx.x & 31;
  const int i = threadIdx.x;
  const int gi = (g << 10) | i;
  unsigned int self = ((i >> 5) == w) ? (1u << (i & 31)) : 0u;
  Abuf[i] = self;
  uint4 six; six.x = six.y = six.z = six.w = 0x06060606u;
  *reinterpret_cast<uint4*>(&dtile[i][0])  = six;
  *reinterpret_cast<uint4*>(&dtile[i][16]) = six;
  if (self) dtile[i][i & 31] = 0;
  const int s0 = starts2[gi], cnt = deg2[gi];
  unsigned int* prev = Abuf;
  unsigned int* cur  = Bbuf;
  unsigned int vis = self;
  __syncthreads();
  for (int l = 1; l <= 5; ++l) {
    unsigned int acc = vis;
    for (int e = 0; e < cnt; ++e)
      acc |= prev[nbr[s0 + e] & 1023];
    unsigned int newly = acc & ~vis;
    while (newly) {
      int k = __ffs(newly) - 1;
      newly &= newly - 1;
      dtile[i][k] = (u8)l;
    }
    cur[i] = acc;
    vis = acc;
    __syncthreads();
    unsigned int* tsw = prev; prev = cur; cur = tsw;
  }
  u8* drow = dist + ((size_t)gi << 10) + w * 32;
  *reinterpret_cast<uint4*>(drow)      = *reinterpret_cast<const uint4*>(&dtile[i][0]);
  *reinterpret_cast<uint4*>(drow + 16) = *reinterpret_cast<const uint4*>(&dtile[i][16]);
}

// ---------------- fused fp32->bf16 conversions + bias_cat ----------------
#define WB_GCN   0
#define WB_QKV   65536
#define WB_PROJ  262144
#define WB_FFN1  327680
#define WB_FFN2  589824
#define WB_OFFN1 851968
#define WB_OFFN2 1114112
#define WB_TOTAL 1376256
#define NXBLK 2048
#define NWBLK 5376

__global__ void k_cvtall(const float* __restrict__ x,
                         const float* p0, const float* p1, const float* p2,
                         const float* p3, const float* p4, const float* p5, const float* p6,
                         const float* __restrict__ qkv_b,
                         ushort_t* __restrict__ x_bf, ushort_t* __restrict__ w_bf,
                         float* __restrict__ bias_cat) {
  int bid = blockIdx.x, t = threadIdx.x;
  if (bid < NXBLK) {
    int i = bid * 256 + t;
    float4 v = reinterpret_cast<const float4*>(x)[i];
    unsigned int lo = (unsigned int)(ushort_t)f2b(v.x) | ((unsigned int)(ushort_t)f2b(v.y) << 16);
    unsigned int hi = (unsigned int)(ushort_t)f2b(v.z) | ((unsigned int)(ushort_t)f2b(v.w) << 16);
    reinterpret_cast<uint2*>(x_bf)[i] = make_uint2(lo, hi);
  } else if (bid < NXBLK + NWBLK) {
    int i = (bid - NXBLK) * 256 + t;
    const float* src; int off;
    if (i < WB_QKV)        { src = p0; off = i; }
    else if (i < WB_PROJ)  { src = p1; off = i - WB_QKV; }
    else if (i < WB_FFN1)  { src = p2; off = i - WB_PROJ; }
    else if (i < WB_FFN2)  { src = p3; off = i - WB_FFN1; }
    else if (i < WB_OFFN1) { src = p4; off = i - WB_FFN2; }
    else if (i < WB_OFFN2) { src = p5; off = i - WB_OFFN1; }
    else                   { src = p6; off = i - WB_OFFN2; }
    w_bf[i] = (ushort_t)f2b(src[off]);
  } else {
    for (int i = t; i < 1024; i += 256) bias_cat[i] = (i < 256) ? 0.f : qkv_b[i - 256];
  }
}

// ---------------- bf16 MFMA GEMM (BM x 64 tiles) ----------------
template<int BM, int ACT, int OMODE>
__global__ __launch_bounds__(256) void k_mgemm(const short* __restrict__ A,
                                               const short* __restrict__ W,
                                               const float* __restrict__ bias,
                                               short* __restrict__ Cb,
                                               short* __restrict__ Cb2,
                                               int K, int O) {
  constexpr int FM = BM / 32;
  __shared__ __attribute__((aligned(16))) short As[BM * 64];
  __shared__ __attribute__((aligned(16))) short Ws[64 * 64];
  const int tid = threadIdx.x;
  const int lane = tid & 63, wbase = tid & 192;
  const int wid = tid >> 6;
  const int lg = lane >> 4, lr = lane & 15;
  const int wm = wid >> 1, wn = wid & 1;
  const int m0 = blockIdx.y * BM, n0 = blockIdx.x * 64;
  f32x4 acc[FM][2];
  #pragma unroll
  for (int i = 0; i < FM; ++i)
    #pragma unroll
    for (int j = 0; j < 2; ++j)
      acc[i][j] = (f32x4){0.f, 0.f, 0.f, 0.f};

  for (int k0 = 0; k0 < K; k0 += 64) {
    #pragma unroll
    for (int c = 0; c < BM / 32; ++c) {
      int chunk = c * 256 + tid;
      int row = chunk >> 3, ks = chunk & 7;
      int srcks = ks ^ (row & 7);
      gload16(A + (size_t)(m0 + row) * K + k0 + srcks * 8,
              (char*)As + (c * 256 + wbase) * 16);
    }
    #pragma unroll
    for (int c = 0; c < 2; ++c) {
      int chunk = c * 256 + tid;
      int row = chunk >> 3, ks = chunk & 7;
      int srcks = ks ^ (row & 7);
      gload16(W + (size_t)(n0 + row) * K + k0 + srcks * 8,
              (char*)Ws + (c * 256 + wbase) * 16);
    }
    __syncthreads();
    #pragma unroll
    for (int kk = 0; kk < 2; ++kk) {
      const int d = kk * 4 + lg;
      bf16x8 b[2];
      #pragma unroll
      for (int fn = 0; fn < 2; ++fn) {
        int r = wn * 32 + fn * 16 + lr;
        b[fn] = *reinterpret_cast<const bf16x8*>((const char*)Ws + r * 128 + ((d ^ (r & 7)) * 16));
      }
      #pragma unroll
      for (int fm = 0; fm < FM; ++fm) {
        int r = wm * (BM / 2) + fm * 16 + lr;
        bf16x8 a = *reinterpret_cast<const bf16x8*>((const char*)As + r * 128 + ((d ^ (r & 7)) * 16));
        acc[fm][0] = __builtin_amdgcn_mfma_f32_16x16x32_bf16(a, b[0], acc[fm][0], 0, 0, 0);
        acc[fm][1] = __builtin_amdgcn_mfma_f32_16x16x32_bf16(a, b[1], acc[fm][1], 0, 0, 0);
      }
    }
    __syncthreads();
  }
  #pragma unroll
  for (int fm = 0; fm < FM; ++fm)
    #pragma unroll
    for (int fn = 0; fn < 2; ++fn)
      #pragma unroll
      for (int rg = 0; rg < 4; ++rg) {
        int r = m0 + wm * (BM / 2) + fm * 16 + lg * 4 + rg;
        int cc = n0 + wn * 32 + fn * 16 + lr;
        float v = acc[fm][fn][rg] + (bias ? bias[cc] : 0.f);
        if (ACT == 1) v = 0.5f * v * (1.0f + erff(v * 0.70710678118654752f));
        if (OMODE == 1) Cb[(size_t)r * O + cc] = f2b(v);
        else {
          if (cc < 256) Cb2[(size_t)r * 256 + cc] = f2b(v);
          else          Cb[(size_t)r * 768 + cc - 256] = f2b(v);
        }
      }
}

// ---------------- GEMM (O=256) + residual + LN (+opt second residual LN) ----------------
// 512 threads, 8 waves: kh = wid>>2 selects K-half (double-buffered LDS), cw = wid&3
// selects 64-col group. After K loop, high half's acc added via LDS exchange; epilogue
// on waves 0-3. LN2: out = LN2(res2a + res2b + LN1(res1 + gemm)).
template<int KK, int OUTB, int LN2>
__global__ __launch_bounds__(512) void k_gemmln(const short* __restrict__ A,
                                                const short* __restrict__ W,
                                                const float* __restrict__ bias,
                                                const float* __restrict__ res1,
                                                const float* __restrict__ gam,
                                                const float* __restrict__ bet,
                                                const float* __restrict__ res2a,
                                                const float* __restrict__ res2b,
                                                const float* __restrict__ gam2,
                                                const float* __restrict__ bet2,
                                                float* __restrict__ outf,
                                                ushort_t* __restrict__ outb) {
  __shared__ __attribute__((aligned(16))) short As[2][32 * 64];
  __shared__ __attribute__((aligned(16))) short Ws[2][256 * 64];
  __shared__ float redS[4][32], redQ[4][32];
  const int tid = threadIdx.x, lane = tid & 63;
  const int hg = tid >> 8, ht = tid & 255;          // K-half group, index within
  const int cw = (tid >> 6) & 3;                    // col group (epilogue: wid 0-3)
  const int lg = lane >> 4, lr = lane & 15;
  const int m0 = blockIdx.x * 32;
  f32x4 acc[2][4];
  #pragma unroll
  for (int i = 0; i < 2; ++i)
    #pragma unroll
    for (int j = 0; j < 4; ++j)
      acc[i][j] = (f32x4){0.f, 0.f, 0.f, 0.f};

  for (int st = 0; st < KK / 128; ++st) {
    const int k0 = hg * (KK / 2) + st * 64;
    {  // A tile 32x64: 256 chunks per half, 1/thread
      int row = ht >> 3, ks = ht & 7, srcks = ks ^ (row & 7);
      gload16(A + (size_t)(m0 + row) * KK + k0 + srcks * 8,
              (char*)As[hg] + (ht & 192) * 16);
    }
    #pragma unroll
    for (int c = 0; c < 8; ++c) {  // W tile 256x64: 2048 chunks per half, 8/thread
      int chunk = c * 256 + ht;
      int row = chunk >> 3, ks = chunk & 7;
      int srcks = ks ^ (row & 7);
      gload16(W + (size_t)row * KK + k0 + srcks * 8,
              (char*)Ws[hg] + (c * 256 + (ht & 192)) * 16);
    }
    __syncthreads();
    #pragma unroll
    for (int kk = 0; kk < 2; ++kk) {
      const int d = kk * 4 + lg;
      bf16x8 a[2];
      #pragma unroll
      for (int fr = 0; fr < 2; ++fr) {
        int r = fr * 16 + lr;
        a[fr] = *reinterpret_cast<const bf16x8*>((const char*)As[hg] + r * 128 + ((d ^ (r & 7)) * 16));
      }
      #pragma unroll
      for (int fc = 0; fc < 4; ++fc) {
        int r = cw * 64 + fc * 16 + lr;
        bf16x8 b = *reinterpret_cast<const bf16x8*>((const char*)Ws[hg] + r * 128 + ((d ^ (r & 7)) * 16));
        acc[0][fc] = __builtin_amdgcn_mfma_f32_16x16x32_bf16(a[0], b, acc[0][fc], 0, 0, 0);
        acc[1][fc] = __builtin_amdgcn_mfma_f32_16x16x32_bf16(a[1], b, acc[1][fc], 0, 0, 0);
      }
    }
    __syncthreads();
  }

  // ---- combine K-halves via LDS (stride-33 floats: conflict-free) ----
  float* xch = reinterpret_cast<float*>(&Ws[0][0]);
  if (hg == 1) {
    float* p = xch + ht * 33;
    #pragma unroll
    for (int fr = 0; fr < 2; ++fr)
      #pragma unroll
      for (int fc = 0; fc < 4; ++fc)
        #pragma unroll
        for (int rg = 0; rg < 4; ++rg)
          p[(fr * 4 + fc) * 4 + rg] = acc[fr][fc][rg];
  }
  __syncthreads();

  float vs[2][4][4];
  float mean1[2][4], rstd1[2][4];
  if (hg == 0) {
    float* p = xch + ht * 33;
    float ps[2][4], pq[2][4];
    #pragma unroll
    for (int fr = 0; fr < 2; ++fr)
      #pragma unroll
      for (int rg = 0; rg < 4; ++rg) { ps[fr][rg] = 0.f; pq[fr][rg] = 0.f; }
    #pragma unroll
    for (int fc = 0; fc < 4; ++fc) {
      int col = cw * 64 + fc * 16 + lr;
      float bv = bias[col];
      #pragma unroll
      for (int fr = 0; fr < 2; ++fr)
        #pragma unroll
        for (int rg = 0; rg < 4; ++rg) {
          int row = m0 + fr * 16 + 4 * lg + rg;
          float v = acc[fr][fc][rg] + p[(fr * 4 + fc) * 4 + rg] + bv
                  + res1[(size_t)row * 256 + col];
          vs[fr][fc][rg] = v;
          ps[fr][rg] += v; pq[fr][rg] += v * v;
        }
    }
    #pragma unroll
    for (int fr = 0; fr < 2; ++fr)
      #pragma unroll
      for (int rg = 0; rg < 4; ++rg) {
        float s = ps[fr][rg], q = pq[fr][rg];
        s += __shfl_xor(s, 1); q += __shfl_xor(q, 1);
        s += __shfl_xor(s, 2); q += __shfl_xor(q, 2);
        s += __shfl_xor(s, 4); q += __shfl_xor(q, 4);
        s += __shfl_xor(s, 8); q += __shfl_xor(q, 8);
        if (lr == 0) {
          redS[cw][fr * 16 + 4 * lg + rg] = s;
          redQ[cw][fr * 16 + 4 * lg + rg] = q;
        }
      }
  }
  __syncthreads();
  if (hg == 0) {
    #pragma unroll
    for (int fr = 0; fr < 2; ++fr)
      #pragma unroll
      for (int rg = 0; rg < 4; ++rg) {
        int rl = fr * 16 + 4 * lg + rg;
        float S = redS[0][rl] + redS[1][rl] + redS[2][rl] + redS[3][rl];
        float Q = redQ[0][rl] + redQ[1][rl] + redQ[2][rl] + redQ[3][rl];
        float mn = S * (1.0f / 256.0f);
        mean1[fr][rg] = mn;
        rstd1[fr][rg] = rsqrtf(Q * (1.0f / 256.0f) - mn * mn + 1e-5f);
      }
  }

  if (LN2) {
    // second stage: vs2 = res2a + res2b + LN1val; new stats; LN2 params
    __syncthreads();                       // all hg0 done reading redS
    if (hg == 0) {
      float ps[2][4], pq[2][4];
      #pragma unroll
      for (int fr = 0; fr < 2; ++fr)
        #pragma unroll
        for (int rg = 0; rg < 4; ++rg) { ps[fr][rg] = 0.f; pq[fr][rg] = 0.f; }
      #pragma unroll
      for (int fc = 0; fc < 4; ++fc) {
        int col = cw * 64 + fc * 16 + lr;
        float g1 = gam[col], b1 = bet[col];
        #pragma unroll
        for (int fr = 0; fr < 2; ++fr)
          #pragma unroll
          for (int rg = 0; rg < 4; ++rg) {
            int row = m0 + fr * 16 + 4 * lg + rg;
            float v1n = (vs[fr][fc][rg] - mean1[fr][rg]) * rstd1[fr][rg] * g1 + b1;
            float v = v1n + res2a[(size_t)row * 256 + col] + res2b[(size_t)row * 256 + col];
            vs[fr][fc][rg] = v;
            ps[fr][rg] += v; pq[fr][rg] += v * v;
          }
      }
      #pragma unroll
      for (int fr = 0; fr < 2; ++fr)
        #pragma unroll
        for (int rg = 0; rg < 4; ++rg) {
          float s = ps[fr][rg], q = pq[fr][rg];
          s += __shfl_xor(s, 1); q += __shfl_xor(q, 1);
          s += __shfl_xor(s, 2); q += __shfl_xor(q, 2);
          s += __shfl_xor(s, 4); q += __shfl_xor(q, 4);
          s += __shfl_xor(s, 8); q += __shfl_xor(q, 8);
          if (lr == 0) {
            redS[cw][fr * 16 + 4 * lg + rg] = s;
            redQ[cw][fr * 16 + 4 * lg + rg] = q;
          }
        }
    }
    __syncthreads();
    if (hg == 0) {
      #pragma unroll
      for (int fr = 0; fr < 2; ++fr)
        #pragma unroll
        for (int rg = 0; rg < 4; ++rg) {
          int rl = fr * 16 + 4 * lg + rg;
          float S = redS[0][rl] + redS[1][rl] + redS[2][rl] + redS[3][rl];
          float Q = redQ[0][rl] + redQ[1][rl] + redQ[2][rl] + redQ[3][rl];
          float mn = S * (1.0f / 256.0f);
          mean1[fr][rg] = mn;
          rstd1[fr][rg] = rsqrtf(Q * (1.0f / 256.0f) - mn * mn + 1e-5f);
        }
    }
  }

  if (hg == 0) {
    const float* gma = LN2 ? gam2 : gam;
    const float* bta = LN2 ? bet2 : bet;
    #pragma unroll
    for (int fr = 0; fr < 2; ++fr)
      #pragma unroll
      for (int rg = 0; rg < 4; ++rg) {
        int rl = fr * 16 + 4 * lg + rg;
        #pragma unroll
        for (int fc = 0; fc < 4; ++fc) {
          int col = cw * 64 + fc * 16 + lr;
          float v = (vs[fr][fc][rg] - mean1[fr][rg]) * rstd1[fr][rg] * gma[col] + bta[col];
          size_t o = (size_t)(m0 + rl) * 256 + col;
          outf[o] = v;
          if (OUTB) outb[o] = (ushort_t)f2b(v);
        }
      }
  }
}

// ---------------- MFMA flash attention, 2-way K-split, f32 partials ----------------
__global__ __launch_bounds__(256) void k_attn(const ushort_t* __restrict__ qkv,
                                              const u8* __restrict__ dist,
                                              const float* __restrict__ emb,
                                              float* __restrict__ po0,
                                              float* __restrict__ po1,
                                              float* __restrict__ pl) {
  __shared__ __attribute__((aligned(16))) char KsB[32 * 128];
  __shared__ __attribute__((aligned(16))) char VtB[32 * 128 + 64];
  __shared__ __attribute__((aligned(16))) char PB[4][16 * 128];
  __shared__ __attribute__((aligned(16))) u8 Ds[32 * 128];
  __shared__ float semb[8];
  const int g = blockIdx.z, head = blockIdx.y;
  const int sp = blockIdx.x >> 4, qblk = blockIdx.x & 15;
  const int q0 = qblk * 64;
  const int kt0 = sp * 8;
  const int t = threadIdx.x, lane = t & 63, wid = t >> 6;
  const int lg = lane >> 4, lr = lane & 15;
  if (t < 7) semb[t] = emb[t] * 1.44269504088896341f;
  const size_t nodebase = (size_t)(g * M) * 768;
  const float C1 = 0.17677669529663687f * 1.44269504088896341f;

  bf16x8 qfrag = *reinterpret_cast<const bf16x8*>(
      qkv + nodebase + (size_t)(q0 + wid * 16 + lr) * 768 + head * 32 + lg * 8);

  const int srow = t >> 2, sc = t & 3;
  const int prow8 = t >> 3, pslot = (t & 7) ^ (prow8 & 7);
  uint4 kr, vr, dr;
  {
    size_t kn = nodebase + (size_t)(kt0 * 64 + srow) * 768 + head * 32;
    kr = *reinterpret_cast<const uint4*>(qkv + kn + 256 + sc * 8);
    vr = *reinterpret_cast<const uint4*>(qkv + kn + 512 + sc * 8);
    dr = *reinterpret_cast<const uint4*>(dist + (size_t)(g * M + kt0 * 64 + srow) * M + q0 + sc * 16);
  }

  f32x4 o0 = {0.f, 0.f, 0.f, 0.f}, o1 = {0.f, 0.f, 0.f, 0.f};
  float lpart[4] = {0.f, 0.f, 0.f, 0.f};
  char* pb = PB[wid];
  const int kp = srow >> 1;
  const int odd = srow & 1;
  const int d0 = sc * 8;
  int r8f[4], slK[4], slD[4];
  #pragma unroll
  for (int fn = 0; fn < 4; ++fn) {
    r8f[fn] = fn * 8 + (lr >> 1);
    slK[fn] = (((lr & 1) << 2) | lg) ^ (r8f[fn] & 7);
    slD[fn] = (((lr & 1) << 2) | wid) ^ (r8f[fn] & 7);
  }

  for (int kt = kt0; kt < kt0 + 8; ++kt) {
    *reinterpret_cast<uint4*>(KsB + prow8 * 128 + pslot * 16) = kr;
    *reinterpret_cast<uint4*>(Ds + prow8 * 128 + pslot * 16) = dr;
    {
      uint4 pvr;
      pvr.x = (unsigned int)__shfl_xor((int)vr.x, 4);
      pvr.y = (unsigned int)__shfl_xor((int)vr.y, 4);
      pvr.z = (unsigned int)__shfl_xor((int)vr.z, 4);
      pvr.w = (unsigned int)__shfl_xor((int)vr.w, 4);
      unsigned int ev[4], ov[4];
      ev[0] = odd ? pvr.x : vr.x; ev[1] = odd ? pvr.y : vr.y;
      ev[2] = odd ? pvr.z : vr.z; ev[3] = odd ? pvr.w : vr.w;
      ov[0] = odd ? vr.x : pvr.x; ov[1] = odd ? vr.y : pvr.y;
      ov[2] = odd ? vr.z : pvr.z; ov[3] = odd ? vr.w : pvr.w;
      #pragma unroll
      for (int di = 0; di < 4; ++di) {
        int dd = odd * 4 + di;
        int d = d0 + dd;
        unsigned int e16 = (dd & 1) ? (ev[dd >> 1] >> 16) : (ev[dd >> 1] & 0xffff);
        unsigned int o16 = (dd & 1) ? (ov[dd >> 1] >> 16) : (ov[dd >> 1] & 0xffff);
        *reinterpret_cast<unsigned int*>(VtB + d * 128 + ((d >> 3) << 4) + ((kp << 2) ^ ((d & 7) << 4)))
            = e16 | (o16 << 16);
      }
    }
    __syncthreads();

    {
      int ktn = (kt + 1) & 15;
      size_t kn = nodebase + (size_t)(ktn * 64 + srow) * 768 + head * 32;
      kr = *reinterpret_cast<const uint4*>(qkv + kn + 256 + sc * 8);
      vr = *reinterpret_cast<const uint4*>(qkv + kn + 512 + sc * 8);
      dr = *reinterpret_cast<const uint4*>(dist + (size_t)(g * M + ktn * 64 + srow) * M + q0 + sc * 16);
    }

    f32x4 s[4];
    unsigned int d4[4];
    #pragma unroll
    for (int fn = 0; fn < 4; ++fn) {
      bf16x8 b = *reinterpret_cast<const bf16x8*>(KsB + r8f[fn] * 128 + slK[fn] * 16);
      s[fn] = __builtin_amdgcn_mfma_f32_16x16x32_bf16(qfrag, b, (f32x4){0.f,0.f,0.f,0.f}, 0, 0, 0);
      d4[fn] = *reinterpret_cast<const unsigned int*>(Ds + r8f[fn] * 128 + slD[fn] * 16 + 4 * lg);
    }
    #pragma unroll
    for (int fn = 0; fn < 4; ++fn)
      #pragma unroll
      for (int rg = 0; rg < 4; ++rg)
        s[fn][rg] = exp2f(s[fn][rg] * C1 + semb[(d4[fn] >> (8 * rg)) & 255]);
    #pragma unroll
    for (int rg = 0; rg < 4; ++rg)
      lpart[rg] += (s[0][rg] + s[1][rg]) + (s[2][rg] + s[3][rg]);

    #pragma unroll
    for (int fn = 0; fn < 4; ++fn)
      #pragma unroll
      for (int rg = 0; rg < 4; ++rg) {
        int qq = 4 * lg + rg, key = fn * 16 + lr;
        *reinterpret_cast<ushort_t*>(pb + qq * 128 + ((key * 2) ^ ((qq & 7) << 4))) =
            (ushort_t)f2b(s[fn][rg]);
      }

    #pragma unroll
    for (int kh = 0; kh < 2; ++kh) {
      int c = kh * 4 + lg;
      int chx = (c << 4) ^ ((lr & 7) << 4);
      bf16x8 a  = *reinterpret_cast<const bf16x8*>(pb + lr * 128 + chx);
      bf16x8 b0 = *reinterpret_cast<const bf16x8*>(VtB + lr * 128 + ((lr >> 3) << 4) + chx);
      bf16x8 b1 = *reinterpret_cast<const bf16x8*>(VtB + (16 + lr) * 128 + (((16 + lr) >> 3) << 4) + chx);
      o0 = __builtin_amdgcn_mfma_f32_16x16x32_bf16(a, b0, o0, 0, 0, 0);
      o1 = __builtin_amdgcn_mfma_f32_16x16x32_bf16(a, b1, o1, 0, 0, 0);
    }
    __syncthreads();
  }

  float* po = sp ? po1 : po0;
  #pragma unroll
  for (int rg = 0; rg < 4; ++rg) {
    float l = lpart[rg];
    l += __shfl_xor(l, 1);
    l += __shfl_xor(l, 2);
    l += __shfl_xor(l, 4);
    l += __shfl_xor(l, 8);
    int q = q0 + wid * 16 + 4 * lg + rg;
    size_t qn = (size_t)(g * M + q);
    po[qn * H + head * 32 + lr]      = o0[rg];
    po[qn * H + head * 32 + 16 + lr] = o1[rg];
    if (lr == 0)
      pl[(sp << 16) + ((g * HEADS + head) << 10) + q] = l;
  }
}

// ---------------- combine attention partials -> bf16 ----------------
__global__ __launch_bounds__(256) void k_acomb(const float* __restrict__ po0,
                                               const float* __restrict__ po1,
                                               const float* __restrict__ pl,
                                               ushort_t* __restrict__ attno) {
  int i4 = blockIdx.x * 256 + threadIdx.x;      // float4 index over NN*H/4
  int idx = i4 * 4;
  int q = idx >> 8;                              // g*M + ql
  int col = idx & 255;
  int head = col >> 5;
  int g = q >> 10, ql = q & 1023;
  int li = ((g * HEADS + head) << 10) + ql;
  float inv = 1.0f / (pl[li] + pl[65536 + li]);
  float4 a = reinterpret_cast<const float4*>(po0)[i4];
  float4 b = reinterpret_cast<const float4*>(po1)[i4];
  unsigned int lo = (unsigned int)(ushort_t)f2b((a.x + b.x) * inv)
                  | ((unsigned int)(ushort_t)f2b((a.y + b.y) * inv) << 16);
  unsigned int hi = (unsigned int)(ushort_t)f2b((a.z + b.z) * inv)
                  | ((unsigned int)(ushort_t)f2b((a.w + b.w) * inv) << 16);
  reinterpret_cast<uint2*>(attno)[i4] = make_uint2(lo, hi);
}

// ---------------- launch ----------------
extern "C" void kernel_launch(void* const* d_in, const int* in_sizes, int n_in,
                              void* d_out, int out_size, void* d_ws, size_t ws_size,
                              hipStream_t stream) {
  const float* x      = (const float*)d_in[0];
  const float* gcn_w  = (const float*)d_in[1];
  const float* gcn_b  = (const float*)d_in[2];
  const float* qkv_w  = (const float*)d_in[3];
  const float* qkv_b  = (const float*)d_in[4];
  const float* proj_w = (const float*)d_in[5];
  const float* proj_b = (const float*)d_in[6];
  const float* ln1_g  = (const float*)d_in[7];
  const float* ln1_b  = (const float*)d_in[8];
  const float* ln2_g  = (const float*)d_in[9];
  const float* ln2_b  = (const float*)d_in[10];
  const float* ffn1_w = (const float*)d_in[11];
  const float* ffn1_b = (const float*)d_in[12];
  const float* ffn2_w = (const float*)d_in[13];
  const float* ffn2_b = (const float*)d_in[14];
  const float* bias_e = (const float*)d_in[15];
  const float* oln1_g = (const float*)d_in[16];
  const float* oln1_b = (const float*)d_in[17];
  const float* oln2_g = (const float*)d_in[18];
  const float* oln2_b = (const float*)d_in[19];
  const float* offn1_w= (const float*)d_in[20];
  const float* offn1_b= (const float*)d_in[21];
  const float* offn2_w= (const float*)d_in[22];
  const float* offn2_b= (const float*)d_in[23];
  const int*   eidx   = (const int*)d_in[24];
  const int* esrc = eidx;
  const int* edst = eidx + NE;

  char* wsp = (char*)d_ws;
  size_t off = 0;
  auto alloc = [&](size_t bytes) { void* p = wsp + off; off += (bytes + 255) & ~255ull; return p; };
  const size_t SZ_NH = (size_t)NN * H * 4;
  ushort_t* x_bf  = (ushort_t*)alloc((size_t)NN * H * 2);         // 4MB
  ushort_t* w_bf  = (ushort_t*)alloc((size_t)WB_TOTAL * 2);       // 2.75MB
  float* bias_cat = (float*)alloc(1024 * 4);
  ushort_t* xwb   = (ushort_t*)alloc((size_t)NN * H * 2);         // 4MB
  float* xloc = (float*)alloc(SZ_NH);                             // 8MB
  float* dinv = (float*)alloc((size_t)NN * 4);
  int*   deg  = (int*)  alloc((size_t)NN * 4);                    // zeroed together
  int* cursor = (int*)  alloc((size_t)NN * 4);
  int*  deg2  = (int*)  alloc((size_t)NN * 4);
  int* cursor2= (int*)  alloc((size_t)NN * 4);
  int* starts = (int*)  alloc((size_t)NN * 4);
  int* starts2= (int*)  alloc((size_t)NN * 4);
  int*   csr  = (int*)  alloc((size_t)NE * 4);                    // 0.5MB
  int*   nbr  = (int*)  alloc((size_t)2 * NE * 4);                // 1MB
  u8*    dist = (u8*)   alloc((size_t)NN * M);                    // 8MB  ┐ mid alias
  ushort_t* qkvb = (ushort_t*)alloc((size_t)NN * 768 * 2);        // 12MB ┘
  float* h1   = (float*)alloc(SZ_NH);                             // 8MB (po0 during attn)
  ushort_t* h1_bf = (ushort_t*)alloc((size_t)NN * H * 2);         // 4MB
  float* y    = (float*)alloc(SZ_NH);                             // 8MB (po1 during attn)
  float* pl   = (float*)alloc((size_t)2 * 65536 * 4);             // 0.5MB

  ushort_t* attno = x_bf;                  // x_bf dead after merged gemm
  ushort_t* mid = (ushort_t*)dist;         // dist+qkvb (20MB) dead after attn
  ushort_t* y_bf = h1_bf;                  // h1_bf dead after ffn1
  float* po0 = h1;                         // h1 written by gemmln#1 (after acomb)
  float* po1 = y;                          // y written by gemmln#2 (after acomb)
  float* outp = (float*)d_out;

  ushort_t* proj_wb = w_bf + WB_PROJ;
  ushort_t* ffn1_wb = w_bf + WB_FFN1;
  ushort_t* ffn2_wb = w_bf + WB_FFN2;
  ushort_t* offn1_wb= w_bf + WB_OFFN1;
  ushort_t* offn2_wb= w_bf + WB_OFFN2;

  hipMemsetAsync(deg, 0, (size_t)4 * NN * 4, stream);

  k_cvtall<<<NXBLK + NWBLK + 1, 256, 0, stream>>>(x, gcn_w, qkv_w, proj_w, ffn1_w,
                                                  ffn2_w, offn1_w, offn2_w, qkv_b,
                                                  x_bf, w_bf, bias_cat);

  // --- degrees & CSRs ---
  k_prep<<<NE / 256, 256, 0, stream>>>(esrc, edst, deg, deg2);
  k_scan2<<<2, 1024, 0, stream>>>(deg, deg2, starts, starts2, dinv);
  k_fillb<<<NE / 256, 256, 0, stream>>>(esrc, edst, starts, cursor, csr, starts2, cursor2, nbr);

  // --- merged GCN-xw + QKV GEMM ---
  k_mgemm<128, 0, 2><<<dim3(1024 / 64, NN / 128), 256, 0, stream>>>(
      (const short*)x_bf, (const short*)w_bf, bias_cat, (short*)qkvb, (short*)xwb, 256, 1024);
  k_gather<<<NN, 256, 0, stream>>>(csr, starts, deg, dinv, xwb, gcn_b, xloc);

  // --- SPD distances ---
  k_spdm<<<G * 32, 1024, 0, stream>>>(starts2, deg2, nbr, dist);

  // --- attention (2-way K-split) + combine ---
  k_attn<<<dim3(32, HEADS, G), 256, 0, stream>>>(qkvb, dist, bias_e, po0, po1, pl);
  k_acomb<<<NN * H / 4 / 256, 256, 0, stream>>>(po0, po1, pl, attno);

  // --- proj + ln1 ---
  k_gemmln<256, 1, 0><<<NN / 32, 512, 0, stream>>>(
      (const short*)attno, (const short*)proj_wb, proj_b, x, ln1_g, ln1_b,
      nullptr, nullptr, nullptr, nullptr, h1, h1_bf);
  // --- ffn1 ---
  k_mgemm<128, 1, 1><<<dim3(FFND / 64, NN / 128), 256, 0, stream>>>(
      (const short*)h1_bf, (const short*)ffn1_wb, ffn1_b, (short*)mid, nullptr, 256, FFND);
  // --- ffn2 + ln2 + oln1 (fused double-LN) -> y ---
  k_gemmln<1024, 1, 1><<<NN / 32, 512, 0, stream>>>(
      (const short*)mid, (const short*)ffn2_wb, ffn2_b, h1, ln2_g, ln2_b,
      x, xloc, oln1_g, oln1_b, y, y_bf);
  // --- offn1 ---
  k_mgemm<128, 1, 1><<<dim3(FFND / 64, NN / 128), 256, 0, stream>>>(
      (const short*)y_bf, (const short*)offn1_wb, offn1_b, (short*)mid, nullptr, 256, FFND);
  // --- offn2 + oln2 -> out ---
  k_gemmln<1024, 0, 0><<<NN / 32, 512, 0, stream>>>(
      (const short*)mid, (const short*)offn2_wb, offn2_b, y, oln2_g, oln2_b,
      nullptr, nullptr, nullptr, nullptr, outp, nullptr);
}

// Round 10
// 337.475 us; speedup vs baseline: 5.1811x; 1.0702x over previous
//
#include <hip/hip_runtime.h>
#include <hip/hip_bf16.h>
#include <cstdint>

#define G 8
#define M 1024
#define H 256
#define HEADS 8
#define FFND 1024
#define NE 131072
#define NN (G*M)          // 8192
#define HD 32             // H/HEADS

typedef unsigned long long u64;
typedef uint8_t u8;
typedef unsigned short ushort_t;
typedef __attribute__((ext_vector_type(8))) short bf16x8;
typedef __attribute__((ext_vector_type(4))) float f32x4;

__device__ __forceinline__ short f2b(float v) {
  __hip_bfloat16 h = __float2bfloat16(v);
  return *reinterpret_cast<short*>(&h);
}
__device__ __forceinline__ float b2f(unsigned int u) {
  union { float f; unsigned int i; } v; v.i = u << 16; return v.f;
}

typedef __attribute__((address_space(1))) const void gvoid;
typedef __attribute__((address_space(3))) void lvoid;
__device__ __forceinline__ void gload16(const void* g, void* l) {
  __builtin_amdgcn_global_load_lds((gvoid*)g, (lvoid*)l, 16, 0, 0);
}

// ---------------- dual prefix scan ----------------
__global__ __launch_bounds__(1024) void k_scan2(const int* __restrict__ deg, const int* __restrict__ deg2,
                                                int* __restrict__ starts, int* __restrict__ starts2,
                                                float* __restrict__ dinv) {
  __shared__ int tmp[1024];
  const int* in = blockIdx.x ? deg2 : deg;
  int* outp = blockIdx.x ? starts2 : starts;
  int t = threadIdx.x;
  int base = t * 8;
  int v[8]; int s = 0;
  #pragma unroll
  for (int i = 0; i < 8; ++i) { v[i] = in[base + i]; s += v[i]; }
  if (blockIdx.x == 0) {
    #pragma unroll
    for (int i = 0; i < 8; ++i) dinv[base + i] = rsqrtf((float)(v[i] + 1));
  }
  tmp[t] = s;
  __syncthreads();
  for (int off = 1; off < 1024; off <<= 1) {
    int x = (t >= off) ? tmp[t - off] : 0;
    __syncthreads();
    tmp[t] += x;
    __syncthreads();
  }
  int ex = (t == 0) ? 0 : tmp[t - 1];
  #pragma unroll
  for (int i = 0; i < 8; ++i) { outp[base + i] = ex; ex += v[i]; }
}

// ---------------- fused CSR fills ----------------
__global__ void k_fillb(const int* __restrict__ srcv, const int* __restrict__ dstv,
                        const int* __restrict__ starts, int* __restrict__ cursor,
                        int* __restrict__ csr,
                        const int* __restrict__ starts2, int* __restrict__ cur2,
                        int* __restrict__ nbr) {
  int e = blockIdx.x * 256 + threadIdx.x;
  if (e >= NE) return;
  int d = dstv[e], s = srcv[e];
  int pos = atomicAdd(&cursor[d], 1);
  csr[starts[d] + pos] = s;
  if (s != d) {
    int p = atomicAdd(&cur2[s], 1); nbr[starts2[s] + p] = d;
    p = atomicAdd(&cur2[d], 1);     nbr[starts2[d] + p] = s;
  }
}

// ---------------- CSR gather (GCN) ----------------
__global__ __launch_bounds__(256) void k_gather(const int* __restrict__ csr,
    const int* __restrict__ starts, const int* __restrict__ deg,
    const float* __restrict__ dinv, const ushort_t* __restrict__ xwb,
    const float* __restrict__ gcn_b, float* __restrict__ xloc) {
  int d = blockIdx.x, t = threadIdx.x;
  int s0 = starts[d], cnt = deg[d];
  float acc = 0.f;
  #pragma unroll 4
  for (int j = 0; j < cnt; ++j) {
    int s = csr[s0 + j];
    acc += dinv[s] * b2f(xwb[(size_t)s * H + t]);
  }
  float di = dinv[d];
  float self = b2f(xwb[(size_t)d * H + t]);
  xloc[(size_t)d * H + t] = di * acc + di * di * self + gcn_b[t];
}

// ---------------- SPD: merged 5-level bitset BFS + dist decode in LDS ----------------
__global__ __launch_bounds__(1024) void k_spdm(const int* __restrict__ starts2,
                                               const int* __restrict__ deg2,
                                               const int* __restrict__ nbr,
                                               u8* __restrict__ dist) {
  __shared__ unsigned int Abuf[1024], Bbuf[1024];
  __shared__ u8 dtile[1024][32];
  const int g = blockIdx.x >> 5, w = blockIdx.x & 31;
  const int i = threadIdx.x;
  const int gi = (g << 10) | i;
  unsigned int self = ((i >> 5) == w) ? (1u << (i & 31)) : 0u;
  Abuf[i] = self;
  uint4 six; six.x = six.y = six.z = six.w = 0x06060606u;
  *reinterpret_cast<uint4*>(&dtile[i][0])  = six;
  *reinterpret_cast<uint4*>(&dtile[i][16]) = six;
  if (self) dtile[i][i & 31] = 0;
  const int s0 = starts2[gi], cnt = deg2[gi];
  unsigned int* prev = Abuf;
  unsigned int* cur  = Bbuf;
  unsigned int vis = self;
  __syncthreads();
  for (int l = 1; l <= 5; ++l) {
    unsigned int acc = vis;
    #pragma unroll 4
    for (int e = 0; e < cnt; ++e)
      acc |= prev[nbr[s0 + e] & 1023];
    unsigned int newly = acc & ~vis;
    while (newly) {
      int k = __ffs(newly) - 1;
      newly &= newly - 1;
      dtile[i][k] = (u8)l;
    }
    cur[i] = acc;
    vis = acc;
    __syncthreads();
    unsigned int* tsw = prev; prev = cur; cur = tsw;
  }
  u8* drow = dist + ((size_t)gi << 10) + w * 32;
  *reinterpret_cast<uint4*>(drow)      = *reinterpret_cast<const uint4*>(&dtile[i][0]);
  *reinterpret_cast<uint4*>(drow + 16) = *reinterpret_cast<const uint4*>(&dtile[i][16]);
}

// ---------------- fused fp32->bf16 conversions + bias_cat + degree prep ----------------
#define WB_GCN   0
#define WB_QKV   65536
#define WB_PROJ  262144
#define WB_FFN1  327680
#define WB_FFN2  589824
#define WB_OFFN1 851968
#define WB_OFFN2 1114112
#define WB_TOTAL 1376256
#define NXBLK 2048
#define NWBLK 5376
#define NEBLK 512

__global__ void k_cvtall(const float* __restrict__ x,
                         const float* p0, const float* p1, const float* p2,
                         const float* p3, const float* p4, const float* p5, const float* p6,
                         const float* __restrict__ qkv_b,
                         ushort_t* __restrict__ x_bf, ushort_t* __restrict__ w_bf,
                         float* __restrict__ bias_cat,
                         const int* __restrict__ srcv, const int* __restrict__ dstv,
                         int* __restrict__ deg, int* __restrict__ deg2) {
  int bid = blockIdx.x, t = threadIdx.x;
  if (bid < NXBLK) {
    int i = bid * 256 + t;
    float4 v = reinterpret_cast<const float4*>(x)[i];
    unsigned int lo = (unsigned int)(ushort_t)f2b(v.x) | ((unsigned int)(ushort_t)f2b(v.y) << 16);
    unsigned int hi = (unsigned int)(ushort_t)f2b(v.z) | ((unsigned int)(ushort_t)f2b(v.w) << 16);
    reinterpret_cast<uint2*>(x_bf)[i] = make_uint2(lo, hi);
  } else if (bid < NXBLK + NWBLK) {
    int i = (bid - NXBLK) * 256 + t;
    const float* src; int off;
    if (i < WB_QKV)        { src = p0; off = i; }
    else if (i < WB_PROJ)  { src = p1; off = i - WB_QKV; }
    else if (i < WB_FFN1)  { src = p2; off = i - WB_PROJ; }
    else if (i < WB_FFN2)  { src = p3; off = i - WB_FFN1; }
    else if (i < WB_OFFN1) { src = p4; off = i - WB_FFN2; }
    else if (i < WB_OFFN2) { src = p5; off = i - WB_OFFN1; }
    else                   { src = p6; off = i - WB_OFFN2; }
    w_bf[i] = (ushort_t)f2b(src[off]);
  } else if (bid == NXBLK + NWBLK) {
    for (int i = t; i < 1024; i += 256) bias_cat[i] = (i < 256) ? 0.f : qkv_b[i - 256];
  } else {
    int e = (bid - NXBLK - NWBLK - 1) * 256 + t;
    int d = dstv[e], s = srcv[e];
    atomicAdd(&deg[d], 1);
    if (s != d) { atomicAdd(&deg2[s], 1); atomicAdd(&deg2[d], 1); }
  }
}

// ---------------- bf16 MFMA GEMM (BM x 64 tiles) ----------------
// OMODE 1: bf16 out stride O. OMODE 2 (merged gcn+qkv, O=1024):
//   cc<256 -> xwb stride 256; 256<=cc<768 -> qkvb stride 768 (col cc-256);
//   cc>=768 -> V transposed: vT[g*256 + (cc-768)][node], 4-row u64 packs.
template<int BM, int ACT, int OMODE>
__global__ __launch_bounds__(256) void k_mgemm(const short* __restrict__ A,
                                               const short* __restrict__ W,
                                               const float* __restrict__ bias,
                                               short* __restrict__ Cb,
                                               short* __restrict__ Cb2,
                                               ushort_t* __restrict__ vTp,
                                               int K, int O) {
  constexpr int FM = BM / 32;
  __shared__ __attribute__((aligned(16))) short As[BM * 64];
  __shared__ __attribute__((aligned(16))) short Ws[64 * 64];
  const int tid = threadIdx.x;
  const int lane = tid & 63, wbase = tid & 192;
  const int wid = tid >> 6;
  const int lg = lane >> 4, lr = lane & 15;
  const int wm = wid >> 1, wn = wid & 1;
  const int m0 = blockIdx.y * BM, n0 = blockIdx.x * 64;
  f32x4 acc[FM][2];
  #pragma unroll
  for (int i = 0; i < FM; ++i)
    #pragma unroll
    for (int j = 0; j < 2; ++j)
      acc[i][j] = (f32x4){0.f, 0.f, 0.f, 0.f};

  for (int k0 = 0; k0 < K; k0 += 64) {
    #pragma unroll
    for (int c = 0; c < BM / 32; ++c) {
      int chunk = c * 256 + tid;
      int row = chunk >> 3, ks = chunk & 7;
      int srcks = ks ^ (row & 7);
      gload16(A + (size_t)(m0 + row) * K + k0 + srcks * 8,
              (char*)As + (c * 256 + wbase) * 16);
    }
    #pragma unroll
    for (int c = 0; c < 2; ++c) {
      int chunk = c * 256 + tid;
      int row = chunk >> 3, ks = chunk & 7;
      int srcks = ks ^ (row & 7);
      gload16(W + (size_t)(n0 + row) * K + k0 + srcks * 8,
              (char*)Ws + (c * 256 + wbase) * 16);
    }
    __syncthreads();
    #pragma unroll
    for (int kk = 0; kk < 2; ++kk) {
      const int d = kk * 4 + lg;
      bf16x8 b[2];
      #pragma unroll
      for (int fn = 0; fn < 2; ++fn) {
        int r = wn * 32 + fn * 16 + lr;
        b[fn] = *reinterpret_cast<const bf16x8*>((const char*)Ws + r * 128 + ((d ^ (r & 7)) * 16));
      }
      #pragma unroll
      for (int fm = 0; fm < FM; ++fm) {
        int r = wm * (BM / 2) + fm * 16 + lr;
        bf16x8 a = *reinterpret_cast<const bf16x8*>((const char*)As + r * 128 + ((d ^ (r & 7)) * 16));
        acc[fm][0] = __builtin_amdgcn_mfma_f32_16x16x32_bf16(a, b[0], acc[fm][0], 0, 0, 0);
        acc[fm][1] = __builtin_amdgcn_mfma_f32_16x16x32_bf16(a, b[1], acc[fm][1], 0, 0, 0);
      }
    }
    __syncthreads();
  }
  #pragma unroll
  for (int fm = 0; fm < FM; ++fm)
    #pragma unroll
    for (int fn = 0; fn < 2; ++fn) {
      int cc = n0 + wn * 32 + fn * 16 + lr;
      float bv = bias ? bias[cc] : 0.f;
      float tv[4];
      #pragma unroll
      for (int rg = 0; rg < 4; ++rg) {
        float v = acc[fm][fn][rg] + bv;
        if (ACT == 1) v = 0.5f * v * (1.0f + erff(v * 0.70710678118654752f));
        tv[rg] = v;
      }
      int r0 = m0 + wm * (BM / 2) + fm * 16 + lg * 4;
      if (OMODE == 1) {
        #pragma unroll
        for (int rg = 0; rg < 4; ++rg)
          Cb[(size_t)(r0 + rg) * O + cc] = f2b(tv[rg]);
      } else {
        if (cc < 256) {
          #pragma unroll
          for (int rg = 0; rg < 4; ++rg)
            Cb2[(size_t)(r0 + rg) * 256 + cc] = f2b(tv[rg]);
        } else if (cc < 768) {
          #pragma unroll
          for (int rg = 0; rg < 4; ++rg)
            Cb[(size_t)(r0 + rg) * 768 + cc - 256] = f2b(tv[rg]);
        } else {
          u64 pk = 0;
          #pragma unroll
          for (int rg = 0; rg < 4; ++rg)
            pk |= (u64)(ushort_t)f2b(tv[rg]) << (16 * rg);
          int gg = r0 >> 10, ql = r0 & 1023;
          *reinterpret_cast<u64*>(vTp + (((size_t)(gg * 256 + cc - 768)) << 10) + ql) = pk;
        }
      }
    }
}

// ---------------- GEMM (O=256) + residual + LN (+opt second residual LN) ----------------
template<int KK, int OUTB, int LN2>
__global__ __launch_bounds__(512) void k_gemmln(const short* __restrict__ A,
                                                const short* __restrict__ W,
                                                const float* __restrict__ bias,
                                                const float* __restrict__ res1,
                                                const float* __restrict__ gam,
                                                const float* __restrict__ bet,
                                                const float* __restrict__ res2a,
                                                const float* __restrict__ res2b,
                                                const float* __restrict__ gam2,
                                                const float* __restrict__ bet2,
                                                float* __restrict__ outf,
                                                ushort_t* __restrict__ outb) {
  __shared__ __attribute__((aligned(16))) short As[2][32 * 64];
  __shared__ __attribute__((aligned(16))) short Ws[2][256 * 64];
  __shared__ float redS[4][32], redQ[4][32];
  const int tid = threadIdx.x, lane = tid & 63;
  const int hg = tid >> 8, ht = tid & 255;
  const int cw = (tid >> 6) & 3;
  const int lg = lane >> 4, lr = lane & 15;
  const int m0 = blockIdx.x * 32;
  f32x4 acc[2][4];
  #pragma unroll
  for (int i = 0; i < 2; ++i)
    #pragma unroll
    for (int j = 0; j < 4; ++j)
      acc[i][j] = (f32x4){0.f, 0.f, 0.f, 0.f};

  for (int st = 0; st < KK / 128; ++st) {
    const int k0 = hg * (KK / 2) + st * 64;
    {
      int row = ht >> 3, ks = ht & 7, srcks = ks ^ (row & 7);
      gload16(A + (size_t)(m0 + row) * KK + k0 + srcks * 8,
              (char*)As[hg] + (ht & 192) * 16);
    }
    #pragma unroll
    for (int c = 0; c < 8; ++c) {
      int chunk = c * 256 + ht;
      int row = chunk >> 3, ks = chunk & 7;
      int srcks = ks ^ (row & 7);
      gload16(W + (size_t)row * KK + k0 + srcks * 8,
              (char*)Ws[hg] + (c * 256 + (ht & 192)) * 16);
    }
    __syncthreads();
    #pragma unroll
    for (int kk = 0; kk < 2; ++kk) {
      const int d = kk * 4 + lg;
      bf16x8 a[2];
      #pragma unroll
      for (int fr = 0; fr < 2; ++fr) {
        int r = fr * 16 + lr;
        a[fr] = *reinterpret_cast<const bf16x8*>((const char*)As[hg] + r * 128 + ((d ^ (r & 7)) * 16));
      }
      #pragma unroll
      for (int fc = 0; fc < 4; ++fc) {
        int r = cw * 64 + fc * 16 + lr;
        bf16x8 b = *reinterpret_cast<const bf16x8*>((const char*)Ws[hg] + r * 128 + ((d ^ (r & 7)) * 16));
        acc[0][fc] = __builtin_amdgcn_mfma_f32_16x16x32_bf16(a[0], b, acc[0][fc], 0, 0, 0);
        acc[1][fc] = __builtin_amdgcn_mfma_f32_16x16x32_bf16(a[1], b, acc[1][fc], 0, 0, 0);
      }
    }
    __syncthreads();
  }

  float* xch = reinterpret_cast<float*>(&Ws[0][0]);
  if (hg == 1) {
    float* p = xch + ht * 33;
    #pragma unroll
    for (int fr = 0; fr < 2; ++fr)
      #pragma unroll
      for (int fc = 0; fc < 4; ++fc)
        #pragma unroll
        for (int rg = 0; rg < 4; ++rg)
          p[(fr * 4 + fc) * 4 + rg] = acc[fr][fc][rg];
  }
  __syncthreads();

  float vs[2][4][4];
  float mean1[2][4], rstd1[2][4];
  if (hg == 0) {
    float* p = xch + ht * 33;
    float ps[2][4], pq[2][4];
    #pragma unroll
    for (int fr = 0; fr < 2; ++fr)
      #pragma unroll
      for (int rg = 0; rg < 4; ++rg) { ps[fr][rg] = 0.f; pq[fr][rg] = 0.f; }
    #pragma unroll
    for (int fc = 0; fc < 4; ++fc) {
      int col = cw * 64 + fc * 16 + lr;
      float bv = bias[col];
      #pragma unroll
      for (int fr = 0; fr < 2; ++fr)
        #pragma unroll
        for (int rg = 0; rg < 4; ++rg) {
          int row = m0 + fr * 16 + 4 * lg + rg;
          float v = acc[fr][fc][rg] + p[(fr * 4 + fc) * 4 + rg] + bv
                  + res1[(size_t)row * 256 + col];
          vs[fr][fc][rg] = v;
          ps[fr][rg] += v; pq[fr][rg] += v * v;
        }
    }
    #pragma unroll
    for (int fr = 0; fr < 2; ++fr)
      #pragma unroll
      for (int rg = 0; rg < 4; ++rg) {
        float s = ps[fr][rg], q = pq[fr][rg];
        s += __shfl_xor(s, 1); q += __shfl_xor(q, 1);
        s += __shfl_xor(s, 2); q += __shfl_xor(q, 2);
        s += __shfl_xor(s, 4); q += __shfl_xor(q, 4);
        s += __shfl_xor(s, 8); q += __shfl_xor(q, 8);
        if (lr == 0) {
          redS[cw][fr * 16 + 4 * lg + rg] = s;
          redQ[cw][fr * 16 + 4 * lg + rg] = q;
        }
      }
  }
  __syncthreads();
  if (hg == 0) {
    #pragma unroll
    for (int fr = 0; fr < 2; ++fr)
      #pragma unroll
      for (int rg = 0; rg < 4; ++rg) {
        int rl = fr * 16 + 4 * lg + rg;
        float S = redS[0][rl] + redS[1][rl] + redS[2][rl] + redS[3][rl];
        float Q = redQ[0][rl] + redQ[1][rl] + redQ[2][rl] + redQ[3][rl];
        float mn = S * (1.0f / 256.0f);
        mean1[fr][rg] = mn;
        rstd1[fr][rg] = rsqrtf(Q * (1.0f / 256.0f) - mn * mn + 1e-5f);
      }
  }

  if (LN2) {
    __syncthreads();
    if (hg == 0) {
      float ps[2][4], pq[2][4];
      #pragma unroll
      for (int fr = 0; fr < 2; ++fr)
        #pragma unroll
        for (int rg = 0; rg < 4; ++rg) { ps[fr][rg] = 0.f; pq[fr][rg] = 0.f; }
      #pragma unroll
      for (int fc = 0; fc < 4; ++fc) {
        int col = cw * 64 + fc * 16 + lr;
        float g1 = gam[col], b1 = bet[col];
        #pragma unroll
        for (int fr = 0; fr < 2; ++fr)
          #pragma unroll
          for (int rg = 0; rg < 4; ++rg) {
            int row = m0 + fr * 16 + 4 * lg + rg;
            float v1n = (vs[fr][fc][rg] - mean1[fr][rg]) * rstd1[fr][rg] * g1 + b1;
            float v = v1n + res2a[(size_t)row * 256 + col] + res2b[(size_t)row * 256 + col];
            vs[fr][fc][rg] = v;
            ps[fr][rg] += v; pq[fr][rg] += v * v;
          }
      }
      #pragma unroll
      for (int fr = 0; fr < 2; ++fr)
        #pragma unroll
        for (int rg = 0; rg < 4; ++rg) {
          float s = ps[fr][rg], q = pq[fr][rg];
          s += __shfl_xor(s, 1); q += __shfl_xor(q, 1);
          s += __shfl_xor(s, 2); q += __shfl_xor(q, 2);
          s += __shfl_xor(s, 4); q += __shfl_xor(q, 4);
          s += __shfl_xor(s, 8); q += __shfl_xor(q, 8);
          if (lr == 0) {
            redS[cw][fr * 16 + 4 * lg + rg] = s;
            redQ[cw][fr * 16 + 4 * lg + rg] = q;
          }
        }
    }
    __syncthreads();
    if (hg == 0) {
      #pragma unroll
      for (int fr = 0; fr < 2; ++fr)
        #pragma unroll
        for (int rg = 0; rg < 4; ++rg) {
          int rl = fr * 16 + 4 * lg + rg;
          float S = redS[0][rl] + redS[1][rl] + redS[2][rl] + redS[3][rl];
          float Q = redQ[0][rl] + redQ[1][rl] + redQ[2][rl] + redQ[3][rl];
          float mn = S * (1.0f / 256.0f);
          mean1[fr][rg] = mn;
          rstd1[fr][rg] = rsqrtf(Q * (1.0f / 256.0f) - mn * mn + 1e-5f);
        }
    }
  }

  if (hg == 0) {
    const float* gma = LN2 ? gam2 : gam;
    const float* bta = LN2 ? bet2 : bet;
    #pragma unroll
    for (int fr = 0; fr < 2; ++fr)
      #pragma unroll
      for (int rg = 0; rg < 4; ++rg) {
        int rl = fr * 16 + 4 * lg + rg;
        #pragma unroll
        for (int fc = 0; fc < 4; ++fc) {
          int col = cw * 64 + fc * 16 + lr;
          float v = (vs[fr][fc][rg] - mean1[fr][rg]) * rstd1[fr][rg] * gma[col] + bta[col];
          size_t o = (size_t)(m0 + rl) * 256 + col;
          outf[o] = v;
          if (OUTB) outb[o] = (ushort_t)f2b(v);
        }
      }
  }
}

// ---------------- MFMA flash attention, 2-way K-split, pre-transposed V ----------------
__global__ __launch_bounds__(256) void k_attn(const ushort_t* __restrict__ qkv,
                                              const ushort_t* __restrict__ vT,
                                              const u8* __restrict__ dist,
                                              const float* __restrict__ emb,
                                              float* __restrict__ po0,
                                              float* __restrict__ po1,
                                              float* __restrict__ pl) {
  __shared__ __attribute__((aligned(16))) char KsB[32 * 128];   // K packed key-pairs
  __shared__ __attribute__((aligned(16))) char VtB[32 * 128];   // V^T rows [d][8 slots x16B], slot^=(d&7)
  __shared__ __attribute__((aligned(16))) char PB[4][16 * 128];
  __shared__ __attribute__((aligned(16))) u8 Ds[32 * 128];
  __shared__ float semb[8];
  const int g = blockIdx.z, head = blockIdx.y;
  const int sp = blockIdx.x >> 4, qblk = blockIdx.x & 15;
  const int q0 = qblk * 64;
  const int kt0 = sp * 8;
  const int t = threadIdx.x, lane = t & 63, wid = t >> 6;
  const int lg = lane >> 4, lr = lane & 15;
  if (t < 7) semb[t] = emb[t] * 1.44269504088896341f;
  const size_t nodebase = (size_t)(g * M) * 768;
  const size_t vtbase = ((size_t)(g * 256 + head * 32)) << 10;
  const float C1 = 0.17677669529663687f * 1.44269504088896341f;

  bf16x8 qfrag = *reinterpret_cast<const bf16x8*>(
      qkv + nodebase + (size_t)(q0 + wid * 16 + lr) * 768 + head * 32 + lg * 8);

  const int srow = t >> 2, sc = t & 3;            // K/D staging
  const int vrow = t >> 3, vc = t & 7;            // V staging (32 rows x 8 chunks)
  const int prow8 = t >> 3, pslot = (t & 7) ^ (prow8 & 7);
  const int vslot = vc ^ (vrow & 7);
  uint4 kr, vr, dr;
  {
    size_t kn = nodebase + (size_t)(kt0 * 64 + srow) * 768 + head * 32;
    kr = *reinterpret_cast<const uint4*>(qkv + kn + 256 + sc * 8);
    vr = *reinterpret_cast<const uint4*>(vT + vtbase + ((size_t)vrow << 10) + kt0 * 64 + vc * 8);
    dr = *reinterpret_cast<const uint4*>(dist + (size_t)(g * M + kt0 * 64 + srow) * M + q0 + sc * 16);
  }

  f32x4 o0 = {0.f, 0.f, 0.f, 0.f}, o1 = {0.f, 0.f, 0.f, 0.f};
  float lpart[4] = {0.f, 0.f, 0.f, 0.f};
  char* pb = PB[wid];
  int r8f[4], slK[4], slD[4];
  #pragma unroll
  for (int fn = 0; fn < 4; ++fn) {
    r8f[fn] = fn * 8 + (lr >> 1);
    slK[fn] = (((lr & 1) << 2) | lg) ^ (r8f[fn] & 7);
    slD[fn] = (((lr & 1) << 2) | wid) ^ (r8f[fn] & 7);
  }

  for (int kt = kt0; kt < kt0 + 8; ++kt) {
    *reinterpret_cast<uint4*>(KsB + prow8 * 128 + pslot * 16) = kr;
    *reinterpret_cast<uint4*>(Ds + prow8 * 128 + pslot * 16) = dr;
    *reinterpret_cast<uint4*>(VtB + vrow * 128 + vslot * 16) = vr;
    __syncthreads();

    {
      int ktn = (kt + 1) & 15;
      size_t kn = nodebase + (size_t)(ktn * 64 + srow) * 768 + head * 32;
      kr = *reinterpret_cast<const uint4*>(qkv + kn + 256 + sc * 8);
      vr = *reinterpret_cast<const uint4*>(vT + vtbase + ((size_t)vrow << 10) + ktn * 64 + vc * 8);
      dr = *reinterpret_cast<const uint4*>(dist + (size_t)(g * M + ktn * 64 + srow) * M + q0 + sc * 16);
    }

    f32x4 s[4];
    unsigned int d4[4];
    #pragma unroll
    for (int fn = 0; fn < 4; ++fn) {
      bf16x8 b = *reinterpret_cast<const bf16x8*>(KsB + r8f[fn] * 128 + slK[fn] * 16);
      s[fn] = __builtin_amdgcn_mfma_f32_16x16x32_bf16(qfrag, b, (f32x4){0.f,0.f,0.f,0.f}, 0, 0, 0);
      d4[fn] = *reinterpret_cast<const unsigned int*>(Ds + r8f[fn] * 128 + slD[fn] * 16 + 4 * lg);
    }
    #pragma unroll
    for (int fn = 0; fn < 4; ++fn)
      #pragma unroll
      for (int rg = 0; rg < 4; ++rg)
        s[fn][rg] = exp2f(s[fn][rg] * C1 + semb[(d4[fn] >> (8 * rg)) & 255]);
    #pragma unroll
    for (int rg = 0; rg < 4; ++rg)
      lpart[rg] += (s[0][rg] + s[1][rg]) + (s[2][rg] + s[3][rg]);

    #pragma unroll
    for (int fn = 0; fn < 4; ++fn)
      #pragma unroll
      for (int rg = 0; rg < 4; ++rg) {
        int qq = 4 * lg + rg, key = fn * 16 + lr;
        *reinterpret_cast<ushort_t*>(pb + qq * 128 + ((key * 2) ^ ((qq & 7) << 4))) =
            (ushort_t)f2b(s[fn][rg]);
      }

    #pragma unroll
    for (int kh = 0; kh < 2; ++kh) {
      int c = kh * 4 + lg;
      int chx = ((c ^ (lr & 7)) << 4);
      bf16x8 a  = *reinterpret_cast<const bf16x8*>(pb + lr * 128 + chx);
      bf16x8 b0 = *reinterpret_cast<const bf16x8*>(VtB + lr * 128 + chx);
      bf16x8 b1 = *reinterpret_cast<const bf16x8*>(VtB + (16 + lr) * 128 + chx);
      o0 = __builtin_amdgcn_mfma_f32_16x16x32_bf16(a, b0, o0, 0, 0, 0);
      o1 = __builtin_amdgcn_mfma_f32_16x16x32_bf16(a, b1, o1, 0, 0, 0);
    }
    __syncthreads();
  }

  float* po = sp ? po1 : po0;
  #pragma unroll
  for (int rg = 0; rg < 4; ++rg) {
    float l = lpart[rg];
    l += __shfl_xor(l, 1);
    l += __shfl_xor(l, 2);
    l += __shfl_xor(l, 4);
    l += __shfl_xor(l, 8);
    int q = q0 + wid * 16 + 4 * lg + rg;
    size_t qn = (size_t)(g * M + q);
    po[qn * H + head * 32 + lr]      = o0[rg];
    po[qn * H + head * 32 + 16 + lr] = o1[rg];
    if (lr == 0)
      pl[(sp << 16) + ((g * HEADS + head) << 10) + q] = l;
  }
}

// ---------------- combine attention partials -> bf16 ----------------
__global__ __launch_bounds__(256) void k_acomb(const float* __restrict__ po0,
                                               const float* __restrict__ po1,
                                               const float* __restrict__ pl,
                                               ushort_t* __restrict__ attno) {
  int i4 = blockIdx.x * 256 + threadIdx.x;
  int idx = i4 * 4;
  int q = idx >> 8;
  int col = idx & 255;
  int head = col >> 5;
  int g = q >> 10, ql = q & 1023;
  int li = ((g * HEADS + head) << 10) + ql;
  float inv = 1.0f / (pl[li] + pl[65536 + li]);
  float4 a = reinterpret_cast<const float4*>(po0)[i4];
  float4 b = reinterpret_cast<const float4*>(po1)[i4];
  unsigned int lo = (unsigned int)(ushort_t)f2b((a.x + b.x) * inv)
                  | ((unsigned int)(ushort_t)f2b((a.y + b.y) * inv) << 16);
  unsigned int hi = (unsigned int)(ushort_t)f2b((a.z + b.z) * inv)
                  | ((unsigned int)(ushort_t)f2b((a.w + b.w) * inv) << 16);
  reinterpret_cast<uint2*>(attno)[i4] = make_uint2(lo, hi);
}

// ---------------- launch ----------------
extern "C" void kernel_launch(void* const* d_in, const int* in_sizes, int n_in,
                              void* d_out, int out_size, void* d_ws, size_t ws_size,
                              hipStream_t stream) {
  const float* x      = (const float*)d_in[0];
  const float* gcn_w  = (const float*)d_in[1];
  const float* gcn_b  = (const float*)d_in[2];
  const float* qkv_w  = (const float*)d_in[3];
  const float* qkv_b  = (const float*)d_in[4];
  const float* proj_w = (const float*)d_in[5];
  const float* proj_b = (const float*)d_in[6];
  const float* ln1_g  = (const float*)d_in[7];
  const float* ln1_b  = (const float*)d_in[8];
  const float* ln2_g  = (const float*)d_in[9];
  const float* ln2_b  = (const float*)d_in[10];
  const float* ffn1_w = (const float*)d_in[11];
  const float* ffn1_b = (const float*)d_in[12];
  const float* ffn2_w = (const float*)d_in[13];
  const float* ffn2_b = (const float*)d_in[14];
  const float* bias_e = (const float*)d_in[15];
  const float* oln1_g = (const float*)d_in[16];
  const float* oln1_b = (const float*)d_in[17];
  const float* oln2_g = (const float*)d_in[18];
  const float* oln2_b = (const float*)d_in[19];
  const float* offn1_w= (const float*)d_in[20];
  const float* offn1_b= (const float*)d_in[21];
  const float* offn2_w= (const float*)d_in[22];
  const float* offn2_b= (const float*)d_in[23];
  const int*   eidx   = (const int*)d_in[24];
  const int* esrc = eidx;
  const int* edst = eidx + NE;

  char* wsp = (char*)d_ws;
  size_t off = 0;
  auto alloc = [&](size_t bytes) { void* p = wsp + off; off += (bytes + 255) & ~255ull; return p; };
  const size_t SZ_NH = (size_t)NN * H * 4;
  ushort_t* x_bf  = (ushort_t*)alloc((size_t)NN * H * 2);         // 4MB
  ushort_t* w_bf  = (ushort_t*)alloc((size_t)WB_TOTAL * 2);       // 2.75MB
  float* bias_cat = (float*)alloc(1024 * 4);
  ushort_t* xwb   = (ushort_t*)alloc((size_t)NN * H * 2);         // 4MB
  ushort_t* vT    = (ushort_t*)alloc((size_t)NN * 256 * 2);       // 4MB (V transposed)
  float* xloc = (float*)alloc(SZ_NH);                             // 8MB
  float* dinv = (float*)alloc((size_t)NN * 4);
  int*   deg  = (int*)  alloc((size_t)NN * 4);                    // zeroed together
  int* cursor = (int*)  alloc((size_t)NN * 4);
  int*  deg2  = (int*)  alloc((size_t)NN * 4);
  int* cursor2= (int*)  alloc((size_t)NN * 4);
  int* starts = (int*)  alloc((size_t)NN * 4);
  int* starts2= (int*)  alloc((size_t)NN * 4);
  int*   csr  = (int*)  alloc((size_t)NE * 4);                    // 0.5MB
  int*   nbr  = (int*)  alloc((size_t)2 * NE * 4);                // 1MB
  u8*    dist = (u8*)   alloc((size_t)NN * M);                    // 8MB  ┐ mid alias
  ushort_t* qkvb = (ushort_t*)alloc((size_t)NN * 768 * 2);        // 12MB ┘
  float* h1   = (float*)alloc(SZ_NH);                             // 8MB (po0 during attn)
  ushort_t* h1_bf = (ushort_t*)alloc((size_t)NN * H * 2);         // 4MB
  float* y    = (float*)alloc(SZ_NH);                             // 8MB (po1 during attn)
  float* pl   = (float*)alloc((size_t)2 * 65536 * 4);             // 0.5MB

  ushort_t* attno = x_bf;
  ushort_t* mid = (ushort_t*)dist;
  ushort_t* y_bf = h1_bf;
  float* po0 = h1;
  float* po1 = y;
  float* outp = (float*)d_out;

  ushort_t* proj_wb = w_bf + WB_PROJ;
  ushort_t* ffn1_wb = w_bf + WB_FFN1;
  ushort_t* ffn2_wb = w_bf + WB_FFN2;
  ushort_t* offn1_wb= w_bf + WB_OFFN1;
  ushort_t* offn2_wb= w_bf + WB_OFFN2;

  hipMemsetAsync(deg, 0, (size_t)4 * NN * 4, stream);

  // conversions + bias_cat + degree prep (fused)
  k_cvtall<<<NXBLK + NWBLK + 1 + NEBLK, 256, 0, stream>>>(
      x, gcn_w, qkv_w, proj_w, ffn1_w, ffn2_w, offn1_w, offn2_w, qkv_b,
      x_bf, w_bf, bias_cat, esrc, edst, deg, deg2);

  k_scan2<<<2, 1024, 0, stream>>>(deg, deg2, starts, starts2, dinv);
  k_fillb<<<NE / 256, 256, 0, stream>>>(esrc, edst, starts, cursor, csr, starts2, cursor2, nbr);

  // --- merged GCN-xw + QKV GEMM (V written transposed to vT) ---
  k_mgemm<128, 0, 2><<<dim3(1024 / 64, NN / 128), 256, 0, stream>>>(
      (const short*)x_bf, (const short*)w_bf, bias_cat, (short*)qkvb, (short*)xwb, vT, 256, 1024);
  k_gather<<<NN, 256, 0, stream>>>(csr, starts, deg, dinv, xwb, gcn_b, xloc);

  // --- SPD distances ---
  k_spdm<<<G * 32, 1024, 0, stream>>>(starts2, deg2, nbr, dist);

  // --- attention (2-way K-split) + combine ---
  k_attn<<<dim3(32, HEADS, G), 256, 0, stream>>>(qkvb, vT, dist, bias_e, po0, po1, pl);
  k_acomb<<<NN * H / 4 / 256, 256, 0, stream>>>(po0, po1, pl, attno);

  // --- proj + ln1 ---
  k_gemmln<256, 1, 0><<<NN / 32, 512, 0, stream>>>(
      (const short*)attno, (const short*)proj_wb, proj_b, x, ln1_g, ln1_b,
      nullptr, nullptr, nullptr, nullptr, h1, h1_bf);
  // --- ffn1 ---
  k_mgemm<128, 1, 1><<<dim3(FFND / 64, NN / 128), 256, 0, stream>>>(
      (const short*)h1_bf, (const short*)ffn1_wb, ffn1_b, (short*)mid, nullptr, nullptr, 256, FFND);
  // --- ffn2 + ln2 + oln1 (fused double-LN) -> y ---
  k_gemmln<1024, 1, 1><<<NN / 32, 512, 0, stream>>>(
      (const short*)mid, (const short*)ffn2_wb, ffn2_b, h1, ln2_g, ln2_b,
      x, xloc, oln1_g, oln1_b, y, y_bf);
  // --- offn1 ---
  k_mgemm<128, 1, 1><<<dim3(FFND / 64, NN / 128), 256, 0, stream>>>(
      (const short*)y_bf, (const short*)offn1_wb, offn1_b, (short*)mid, nullptr, nullptr, 256, FFND);
  // --- offn2 + oln2 -> out ---
  k_gemmln<1024, 0, 0><<<NN / 32, 512, 0, stream>>>(
      (const short*)mid, (const short*)offn2_wb, offn2_b, y, oln2_g, oln2_b,
      nullptr, nullptr, nullptr, nullptr, outp, nullptr);
}